// Round 4
// baseline (949.426 us; speedup 1.0000x reference)
//
#include <hip/hip_runtime.h>

#define NN 50000
#define DD 128
#define EE 800000
#define TT 400000
#define KM 32
#define UU 320  // uints per 640-col bf16 row
#define ROWB 12500           // NN/4
#define MB 782               // ceil(NN/64)
#define EDGE_BLKS 3125       // EE/256
#define HB2 782              // ceil(EE/1024)
#define HBT 391              // ceil(TT/1024)
#define SCAN_TILE 2048
#define SCAN_NB ((NN + SCAN_TILE - 1) / SCAN_TILE)  // 25

static constexpr float INV_SQRT_D = 0.08838834764831845f; // 1/sqrt(128)
static constexpr float INV_D = 1.f / 128.f;

typedef __attribute__((ext_vector_type(8))) short bf16x8;
typedef __attribute__((ext_vector_type(4))) float f32x4;
typedef unsigned short ushort_t;

__device__ __forceinline__ float softplus_f(float x) {
  return (x > 20.f) ? x : log1pf(__expf(x));
}

// exact rewrite of tanh-gelu: 0.5x(1+tanh(z)) == x * sigmoid(2z)
__device__ __forceinline__ float gelu_fast(float x) {
  float p = fmaf(0.044715f * x * x, x, x);
  float e = __expf(-1.5957691216057308f * p);
  return x * __builtin_amdgcn_rcpf(1.f + e);
}

__device__ __forceinline__ float wredsum(float v) {
#pragma unroll
  for (int m = 32; m; m >>= 1) v += __shfl_xor(v, m, 64);
  return v;
}

__device__ __forceinline__ float redsum16(float v) {
#pragma unroll
  for (int m = 1; m < 16; m <<= 1) v += __shfl_xor(v, m, 64);
  return v;
}

__device__ __forceinline__ float blo(unsigned w) { return __uint_as_float(w << 16); }
__device__ __forceinline__ float bhi(unsigned w) { return __uint_as_float(w & 0xffff0000u); }
__device__ __forceinline__ unsigned pack_bf16(float a, float b) {
  unsigned ua = __float_as_uint(a); ua += 0x7fff + ((ua >> 16) & 1);
  unsigned ub = __float_as_uint(b); ub += 0x7fff + ((ub >> 16) & 1);
  return (ua >> 16) | (ub & 0xffff0000u);
}
__device__ __forceinline__ ushort_t bf16_1(float x) {
  unsigned u = __float_as_uint(x); u += 0x7fff + ((u >> 16) & 1);
  return (ushort_t)(u >> 16);
}
__device__ __forceinline__ void unp8(uint4 w, float* f) {
  f[0] = blo(w.x); f[1] = bhi(w.x); f[2] = blo(w.y); f[3] = bhi(w.y);
  f[4] = blo(w.z); f[5] = bhi(w.z); f[6] = blo(w.w); f[7] = bhi(w.w);
}
__device__ __forceinline__ uint4 pk8(const float* f) {
  uint4 r;
  r.x = pack_bf16(f[0], f[1]); r.y = pack_bf16(f[2], f[3]);
  r.z = pack_bf16(f[4], f[5]); r.w = pack_bf16(f[6], f[7]);
  return r;
}

// params: [0]=b2 [1]=b3 [2]=bm [3]=cw2 [4]=cw3 [5]=cwm [6]=-sp2/b2 [7]=-sp3/b3 [8]=-spm/bm
__global__ void params_k(const float* l2, const float* l3, const float* lm,
                         const float* b2, const float* b3, const float* bm,
                         float* __restrict__ P) {
  if (threadIdx.x != 0) return;
  float B2 = fminf(softplus_f(b2[0]), 5.f);
  float B3 = fminf(softplus_f(b3[0]), 5.f);
  float Bm = fminf(softplus_f(bm[0]), 5.f);
  float S2 = softplus_f(l2[0]);
  float S3 = softplus_f(l3[0]);
  float Sm = softplus_f(lm[0]);
  P[0] = B2; P[1] = B3; P[2] = Bm;
  P[3] = -S2 * INV_SQRT_D; P[4] = -S3 * INV_D; P[5] = -Sm * INV_SQRT_D;
  P[6] = -S2 / B2; P[7] = -S3 / B3; P[8] = -Sm / Bm;
}

// ---------------- LayerNorm forward -> bf16 G ----------------
__global__ __launch_bounds__(256) void ln_fwd(const float* __restrict__ X,
                                              const float* __restrict__ gamma,
                                              const float* __restrict__ beta,
                                              unsigned* __restrict__ Gb,
                                              float* __restrict__ meanv,
                                              float* __restrict__ rstdv) {
  int row = blockIdx.x * 4 + (threadIdx.x >> 6);
  if (row >= NN) return;
  int l = threadIdx.x & 63;
  float2 x2 = *(const float2*)(X + row * DD + 2 * l);
  float mu = wredsum(x2.x + x2.y) * (1.f / DD);
  float d0 = x2.x - mu, d1 = x2.y - mu;
  float var = wredsum(d0 * d0 + d1 * d1) * (1.f / DD);
  float rstd = rsqrtf(var + 1e-5f);
  float2 g2 = *(const float2*)(gamma + 2 * l);
  float2 b2 = *(const float2*)(beta + 2 * l);
  float o0 = d0 * rstd * g2.x + b2.x;
  float o1 = d1 * rstd * g2.y + b2.y;
  Gb[(size_t)row * 64 + l] = pack_bf16(o0, o1);
  if (l == 0) { meanv[row] = mu; rstdv[row] = rstd; }
}

// ---------------- weight conversion ----------------
__global__ __launch_bounds__(256) void w_conv(const float* W0, const float* W1, const float* W2,
                                              const float* W3, const float* W4,
                                              ushort_t* __restrict__ Wt,
                                              ushort_t* __restrict__ Wc) {
  int idx = blockIdx.x * 256 + threadIdx.x;
  if (idx >= 640 * 128) return;
  const float* Ws[5] = {W0, W1, W2, W3, W4};
  int n = idx >> 7, k = idx & 127;
  Wt[idx] = bf16_1(Ws[n >> 7][(size_t)k * 128 + (n & 127)]);
  int k2 = idx >> 7, n2 = idx & 127;
  Wc[(size_t)n2 * 640 + k2] = bf16_1(Ws[k2 >> 7][(size_t)n2 * 128 + (k2 & 127)]);
}

// ---------------- fwd MFMA GEMM body ----------------
__device__ void mfma_fwd_body(int bxr, int by, const ushort_t* __restrict__ Gb,
                              const ushort_t* __restrict__ Wt,
                              ushort_t* __restrict__ QK, int M) {
  __shared__ ushort_t sB[64][136];
  int tid = threadIdx.x;
  int nb = by * 64;
  for (int idx = tid; idx < 64 * 16; idx += 256) {
    int r = idx >> 4, c8 = idx & 15;
    *(bf16x8*)&sB[r][c8 * 8] = *(const bf16x8*)(Wt + (size_t)(nb + r) * 128 + c8 * 8);
  }
  __syncthreads();
  int w = tid >> 6, l = tid & 63, quad = l >> 4, j = l & 15;
  int row0 = bxr * 64 + w * 16;
  int arow = row0 + j; if (arow >= M) arow = M - 1;
  const bf16x8* ap = (const bf16x8*)(Gb + (size_t)arow * 128);
  f32x4 acc[4];
#pragma unroll
  for (int nt = 0; nt < 4; nt++) acc[nt] = (f32x4){0.f, 0.f, 0.f, 0.f};
#pragma unroll
  for (int kc = 0; kc < 4; kc++) {
    bf16x8 a = ap[kc * 4 + quad];
#pragma unroll
    for (int nt = 0; nt < 4; nt++) {
      bf16x8 b = *(const bf16x8*)&sB[nt * 16 + j][kc * 32 + quad * 8];
      acc[nt] = __builtin_amdgcn_mfma_f32_16x16x32_bf16(a, b, acc[nt], 0, 0, 0);
    }
  }
#pragma unroll
  for (int nt = 0; nt < 4; nt++)
#pragma unroll
    for (int r = 0; r < 4; r++) {
      int row = row0 + quad * 4 + r;
      if (row < M) QK[(size_t)row * 640 + nb + nt * 16 + j] = bf16_1(acc[nt][r]);
    }
}

// ---------------- edge MLP body ----------------
__device__ void edge_mlp_body(int bx, const float* __restrict__ EA,
                              const float* __restrict__ We1,
                              const float* __restrict__ be1,
                              const float* __restrict__ We2,
                              const float* __restrict__ be2,
                              float* __restrict__ a2) {
  __shared__ float sW1[16 * 128];
  __shared__ float sb1[128];
  __shared__ float sW2[128];
  int tid = threadIdx.x;
  for (int i = tid; i < 2048; i += 256) sW1[i] = We1[i];
  if (tid < 128) { sb1[tid] = be1[tid]; sW2[tid] = We2[tid]; }
  __syncthreads();
  int w = tid >> 6, l = tid & 63;
  int m = l & 15, q = l >> 4;
  union u8 { bf16x8 v; ushort_t s[8]; };
  u8 bf[8];
  float bb[8], ww[8];
#pragma unroll
  for (int nt = 0; nt < 8; nt++) {
    int n = nt * 16 + m;
#pragma unroll
    for (int j = 0; j < 8; j++) {
      int k = q * 8 + j;
      bf[nt].s[j] = (k < 16) ? bf16_1(sW1[k * 128 + n]) : (ushort_t)0;
    }
    bb[nt] = sb1[n];
    ww[nt] = sW2[n];
  }
  float be2v = be2[0];
  for (int batch = 0; batch < 4; batch++) {
    int e0 = bx * 256 + batch * 64 + w * 16;
    u8 af;
    if (q < 2) {
      const float* ep = EA + (size_t)(e0 + m) * 16 + q * 8;
      float4 v0 = *(const float4*)ep;
      float4 v1 = *(const float4*)(ep + 4);
      af.s[0] = bf16_1(v0.x); af.s[1] = bf16_1(v0.y);
      af.s[2] = bf16_1(v0.z); af.s[3] = bf16_1(v0.w);
      af.s[4] = bf16_1(v1.x); af.s[5] = bf16_1(v1.y);
      af.s[6] = bf16_1(v1.z); af.s[7] = bf16_1(v1.w);
    } else {
#pragma unroll
      for (int j = 0; j < 8; j++) af.s[j] = 0;
    }
    float s0 = 0.f, s1 = 0.f, s2 = 0.f, s3 = 0.f;
#pragma unroll
    for (int nt = 0; nt < 8; nt++) {
      float bias = bb[nt];
      f32x4 cin = (f32x4){bias, bias, bias, bias};
      f32x4 acc = __builtin_amdgcn_mfma_f32_16x16x32_bf16(af.v, bf[nt].v, cin, 0, 0, 0);
      float w2v = ww[nt];
      s0 = fmaf(gelu_fast(acc[0]), w2v, s0);
      s1 = fmaf(gelu_fast(acc[1]), w2v, s1);
      s2 = fmaf(gelu_fast(acc[2]), w2v, s2);
      s3 = fmaf(gelu_fast(acc[3]), w2v, s3);
    }
    s0 = redsum16(s0); s1 = redsum16(s1); s2 = redsum16(s2); s3 = redsum16(s3);
    if (m == 0) {
      int eb = e0 + q * 4;
      a2[eb + 0] = s0 + be2v;
      a2[eb + 1] = s1 + be2v;
      a2[eb + 2] = s2 + be2v;
      a2[eb + 3] = s3 + be2v;
    }
  }
}

// fused fwd: mfma_fwd (MFMA pipe) + edge_mlp (VALU pipe) in one dispatch
__global__ __launch_bounds__(256) void fwd_k(const ushort_t* __restrict__ Gb,
                                             const ushort_t* __restrict__ Wt,
                                             ushort_t* __restrict__ QK,
                                             const float* __restrict__ EA,
                                             const float* __restrict__ We1,
                                             const float* __restrict__ be1,
                                             const float* __restrict__ We2,
                                             const float* __restrict__ be2,
                                             float* __restrict__ a2) {
  int bx = blockIdx.x;
  if (bx < MB * 10) {
    mfma_fwd_body(bx / 10, bx % 10, Gb, Wt, QK, NN);
  } else {
    edge_mlp_body(bx - MB * 10, EA, We1, be1, We2, be2, a2);
  }
}

// ---------------- bwd MFMA GEMM: dG[M,128](bf16) = dAll[M,640](bf16) @ Wc^T ----------------
__global__ __launch_bounds__(256) void mfma_bwd(const ushort_t* __restrict__ dAll,
                                                const ushort_t* __restrict__ Wc,
                                                unsigned* __restrict__ dG, int M) {
  __shared__ ushort_t sB[64][40];
  int tid = threadIdx.x;
  int nb = blockIdx.y * 64;
  int w = tid >> 6, l = tid & 63, quad = l >> 4, j = l & 15;
  int row0 = blockIdx.x * 64 + w * 16;
  int arow = row0 + j; if (arow >= M) arow = M - 1;
  const ushort_t* arp = dAll + (size_t)arow * 640;
  f32x4 acc[4];
#pragma unroll
  for (int nt = 0; nt < 4; nt++) acc[nt] = (f32x4){0.f, 0.f, 0.f, 0.f};
  int sr = tid >> 2, sc = tid & 3;
  for (int kc = 0; kc < 20; kc++) {
    __syncthreads();
    *(bf16x8*)&sB[sr][sc * 8] = *(const bf16x8*)(Wc + (size_t)(nb + sr) * 640 + kc * 32 + sc * 8);
    __syncthreads();
    bf16x8 a = *(const bf16x8*)(arp + kc * 32 + quad * 8);
#pragma unroll
    for (int nt = 0; nt < 4; nt++) {
      bf16x8 b = *(const bf16x8*)&sB[nt * 16 + j][quad * 8];
      acc[nt] = __builtin_amdgcn_mfma_f32_16x16x32_bf16(a, b, acc[nt], 0, 0, 0);
    }
  }
#pragma unroll
  for (int nt = 0; nt < 4; nt++)
#pragma unroll
    for (int r = 0; r < 4; r++) {
      int row = row0 + quad * 4 + r;
      if (row < M) ((ushort_t*)dG)[(size_t)row * 128 + nb + nt * 16 + j] = bf16_1(acc[nt][r]);
    }
}

// ---------------- small fp32 GEMM for Km = B_mem @ W_Km ----------------
__global__ __launch_bounds__(256, 1) void gemm_km(const float* __restrict__ A,
                                                  const float* __restrict__ W,
                                                  float* __restrict__ C, int M) {
  __shared__ float As[32][132];
  __shared__ float Wst[128][136];
  const int tid = threadIdx.x;
  for (int idx = tid; idx < 128 * 128; idx += 256) {
    int k = idx >> 7, jj = idx & 127;
    Wst[k][jj] = W[k * 128 + jj];
  }
  for (int idx = tid; idx < 32 * 128; idx += 256) {
    int r = idx >> 7, d = idx & 127;
    As[r][d] = A[r * 128 + d];
  }
  __syncthreads();
  int r = tid >> 3, c0 = (tid & 7) * 16;
  float acc[16];
#pragma unroll
  for (int q = 0; q < 16; q++) acc[q] = 0.f;
  for (int k = 0; k < 128; k++) {
    float av = As[r][k];
#pragma unroll
    for (int q = 0; q < 16; q++) acc[q] = fmaf(av, Wst[k][c0 + q], acc[q]);
  }
#pragma unroll
  for (int q = 0; q < 16; q++) C[r * 128 + c0 + q] = acc[q];
}

// ---------------- fused histograms (4-deep ILP) ----------------
__device__ void hist2_body(int bx, const int* __restrict__ a,
                           const int* __restrict__ b,
                           int* __restrict__ ca, int* __restrict__ cb, int n) {
  int base = bx * 1024 + threadIdx.x;
  if (base + 768 < n) {
    int av[4], bv[4];
#pragma unroll
    for (int k = 0; k < 4; k++) { int e = base + k * 256; av[k] = a[e]; bv[k] = b[e]; }
#pragma unroll
    for (int k = 0; k < 4; k++) atomicAdd(&ca[av[k]], 1);
#pragma unroll
    for (int k = 0; k < 4; k++) atomicAdd(&cb[bv[k]], 1);
  } else {
#pragma unroll
    for (int k = 0; k < 4; k++) {
      int e = base + k * 256;
      if (e < n) { atomicAdd(&ca[a[e]], 1); atomicAdd(&cb[b[e]], 1); }
    }
  }
}

__device__ void hist_t3_body(int bx, const int* __restrict__ c,
                             const int* __restrict__ u,
                             const int* __restrict__ v,
                             int* __restrict__ cc, int* __restrict__ cuv, int n) {
  int base = bx * 1024 + threadIdx.x;
  if (base + 768 < n) {
    int cv[4], uv[4], vv[4];
#pragma unroll
    for (int k = 0; k < 4; k++) { int t = base + k * 256; cv[k] = c[t]; uv[k] = u[t]; vv[k] = v[t]; }
#pragma unroll
    for (int k = 0; k < 4; k++) atomicAdd(&cc[cv[k]], 1);
#pragma unroll
    for (int k = 0; k < 4; k++) atomicAdd(&cuv[uv[k]], 1);
#pragma unroll
    for (int k = 0; k < 4; k++) atomicAdd(&cuv[vv[k]], 1);
  } else {
#pragma unroll
    for (int k = 0; k < 4; k++) {
      int t = base + k * 256;
      if (t < n) { atomicAdd(&cc[c[t]], 1); atomicAdd(&cuv[u[t]], 1); atomicAdd(&cuv[v[t]], 1); }
    }
  }
}

__global__ __launch_bounds__(256) void hist_k(const int* __restrict__ c2,
                                              const int* __restrict__ u2,
                                              const int* __restrict__ c3,
                                              const int* __restrict__ u3,
                                              const int* __restrict__ v3,
                                              int* __restrict__ cnt_c2,
                                              int* __restrict__ cnt_u2,
                                              int* __restrict__ cnt_c3,
                                              int* __restrict__ cnt_uv) {
  int bx = blockIdx.x;
  if (bx < HB2) hist2_body(bx, c2, u2, cnt_c2, cnt_u2, EE);
  else hist_t3_body(bx - HB2, c3, u3, v3, cnt_c3, cnt_uv, TT);
}

// ---------------- parallel 3-phase scan over 4 count arrays ----------------
__global__ __launch_bounds__(256) void scan_p1(const int* __restrict__ cnt,
                                               int* __restrict__ part) {
  int arr = blockIdx.y, b = blockIdx.x;
  const int* c = cnt + (size_t)arr * NN;
  int gi = b * SCAN_TILE + threadIdx.x * 8;
  int s = 0;
#pragma unroll
  for (int t = 0; t < 8; t++) s += (gi + t < NN) ? c[gi + t] : 0;
#pragma unroll
  for (int m = 32; m; m >>= 1) s += __shfl_xor(s, m, 64);
  __shared__ int wt[4];
  int lane = threadIdx.x & 63, wid = threadIdx.x >> 6;
  if (lane == 0) wt[wid] = s;
  __syncthreads();
  if (threadIdx.x == 0) part[arr * SCAN_NB + b] = wt[0] + wt[1] + wt[2] + wt[3];
}

__global__ __launch_bounds__(256) void scan_p2(int* __restrict__ part) {
  int w = threadIdx.x >> 6, l = threadIdx.x & 63;
  int v = (l < SCAN_NB) ? part[w * SCAN_NB + l] : 0;
  int x = v;
#pragma unroll
  for (int d = 1; d < 64; d <<= 1) {
    int y = __shfl_up(x, d, 64);
    if (l >= d) x += y;
  }
  if (l < SCAN_NB) part[w * SCAN_NB + l] = x - v;
}

__global__ __launch_bounds__(256) void scan_p3(const int* __restrict__ cnt,
                                               const int* __restrict__ part,
                                               int* __restrict__ rowptr,
                                               int* __restrict__ cursor) {
  int arr = blockIdx.y, b = blockIdx.x;
  const int* c = cnt + (size_t)arr * NN;
  int* rp = rowptr + (size_t)arr * (NN + 1);
  int* cur = cursor + (size_t)arr * NN;
  int tid = threadIdx.x;
  int gi = b * SCAN_TILE + tid * 8;
  int vals[8];
#pragma unroll
  for (int t = 0; t < 8; t++) vals[t] = (gi + t < NN) ? c[gi + t] : 0;
  int tsum = 0;
#pragma unroll
  for (int t = 0; t < 8; t++) tsum += vals[t];
  int lane = tid & 63, wid = tid >> 6;
  int x = tsum;
#pragma unroll
  for (int d = 1; d < 64; d <<= 1) {
    int y = __shfl_up(x, d, 64);
    if (lane >= d) x += y;
  }
  __shared__ int wt[4];
  if (lane == 63) wt[wid] = x;
  __syncthreads();
  int wadd = 0;
  for (int w = 0; w < wid; w++) wadd += wt[w];
  int running = part[arr * SCAN_NB + b] + wadd + x - tsum;
#pragma unroll
  for (int t = 0; t < 8; t++) {
    if (gi + t < NN) { rp[gi + t] = running; cur[gi + t] = running; }
    running += vals[t];
  }
  if (b == SCAN_NB - 1 && tid == 255) rp[NN] = running;
}

// ---------------- fused packed scatter (4-deep ILP) ----------------
__device__ void scat2_body(int bx, const int* __restrict__ c2,
                           const int* __restrict__ u2,
                           const float* __restrict__ a2,
                           int* __restrict__ cuc, int* __restrict__ cuu,
                           uint2* __restrict__ payc, uint2* __restrict__ payu, int n) {
  int base = bx * 1024 + threadIdx.x;
  if (base + 768 < n) {
    int c[4], u[4]; float a[4]; int p[4], p2[4];
#pragma unroll
    for (int k = 0; k < 4; k++) { int e = base + k * 256; c[k] = c2[e]; u[k] = u2[e]; a[k] = a2[e]; }
#pragma unroll
    for (int k = 0; k < 4; k++) p[k] = atomicAdd(&cuc[c[k]], 1);
#pragma unroll
    for (int k = 0; k < 4; k++) p2[k] = atomicAdd(&cuu[u[k]], 1);
#pragma unroll
    for (int k = 0; k < 4; k++) {
      uint2 t; t.x = (unsigned)u[k]; t.y = __float_as_uint(a[k]);
      payc[p[k]] = t;
    }
#pragma unroll
    for (int k = 0; k < 4; k++) {
      uint2 t; t.x = (unsigned)p[k]; t.y = (unsigned)c[k];
      payu[p2[k]] = t;
    }
  } else {
#pragma unroll
    for (int k = 0; k < 4; k++) {
      int e = base + k * 256;
      if (e < n) {
        int cc = c2[e], uu = u2[e];
        int pp = atomicAdd(&cuc[cc], 1);
        int qq = atomicAdd(&cuu[uu], 1);
        uint2 t; t.x = (unsigned)uu; t.y = __float_as_uint(a2[e]);
        payc[pp] = t;
        uint2 t2; t2.x = (unsigned)pp; t2.y = (unsigned)cc;
        payu[qq] = t2;
      }
    }
  }
}

__device__ void scat_t3_body(int bx, const int* __restrict__ c3,
                             const int* __restrict__ u3,
                             const int* __restrict__ v3,
                             const int* __restrict__ ttau,
                             int* __restrict__ cuc, int* __restrict__ cuv,
                             uint2* __restrict__ payc, uint2* __restrict__ payuv, int n) {
  int base = bx * 1024 + threadIdx.x;
  if (base + 768 < n) {
    int c[4], u[4], v[4], ta[4]; int p[4], q1[4], q2[4];
#pragma unroll
    for (int k = 0; k < 4; k++) {
      int t = base + k * 256;
      c[k] = c3[t]; u[k] = u3[t]; v[k] = v3[t]; ta[k] = ttau[t] & 1;
    }
#pragma unroll
    for (int k = 0; k < 4; k++) p[k] = atomicAdd(&cuc[c[k]], 1);
#pragma unroll
    for (int k = 0; k < 4; k++) q1[k] = atomicAdd(&cuv[u[k]], 1);
#pragma unroll
    for (int k = 0; k < 4; k++) q2[k] = atomicAdd(&cuv[v[k]], 1);
#pragma unroll
    for (int k = 0; k < 4; k++) {
      uint2 a; a.x = ((unsigned)u[k] << 16) | (unsigned)v[k]; a.y = (unsigned)ta[k];
      payc[p[k]] = a;
    }
#pragma unroll
    for (int k = 0; k < 4; k++) {
      unsigned sp = ((unsigned)p[k] << 1) | (unsigned)ta[k];
      uint2 b1; b1.x = ((unsigned)v[k] << 16) | (unsigned)c[k]; b1.y = sp;
      payuv[q1[k]] = b1;
      uint2 b2; b2.x = ((unsigned)u[k] << 16) | (unsigned)c[k]; b2.y = sp;
      payuv[q2[k]] = b2;
    }
  } else {
#pragma unroll
    for (int k = 0; k < 4; k++) {
      int t = base + k * 256;
      if (t < n) {
        int c = c3[t], u = u3[t], v = v3[t], ta = ttau[t] & 1;
        int p = atomicAdd(&cuc[c], 1);
        int q1 = atomicAdd(&cuv[u], 1);
        int q2 = atomicAdd(&cuv[v], 1);
        unsigned sp = ((unsigned)p << 1) | (unsigned)ta;
        uint2 a; a.x = ((unsigned)u << 16) | (unsigned)v; a.y = (unsigned)ta;
        payc[p] = a;
        uint2 b1; b1.x = ((unsigned)v << 16) | (unsigned)c; b1.y = sp;
        payuv[q1] = b1;
        uint2 b2; b2.x = ((unsigned)u << 16) | (unsigned)c; b2.y = sp;
        payuv[q2] = b2;
      }
    }
  }
}

__global__ __launch_bounds__(256) void scat_k(const int* __restrict__ c2,
                                              const int* __restrict__ u2,
                                              const float* __restrict__ a2,
                                              int* __restrict__ cu_c2,
                                              int* __restrict__ cu_u2,
                                              uint2* __restrict__ payc2,
                                              uint2* __restrict__ payu2,
                                              const int* __restrict__ c3,
                                              const int* __restrict__ u3,
                                              const int* __restrict__ v3,
                                              const int* __restrict__ ttau,
                                              int* __restrict__ cu_c3,
                                              int* __restrict__ cu_uv,
                                              uint2* __restrict__ payc3,
                                              uint2* __restrict__ payuv) {
  int bx = blockIdx.x;
  if (bx < HB2) scat2_body(bx, c2, u2, a2, cu_c2, cu_u2, payc2, payu2, EE);
  else scat_t3_body(bx - HB2, c3, u3, v3, ttau, cu_c3, cu_uv, payc3, payuv, TT);
}

// ---------------- fused e2 fwd + dQ2 body ----------------
__device__ void e2_body(int bx, const unsigned* __restrict__ QK,
                        const float* __restrict__ P,
                        const uint2* __restrict__ pay,
                        const int* __restrict__ rp,
                        float* __restrict__ s2c,
                        float* __restrict__ L2,
                        unsigned* __restrict__ dAll) {
  int row = bx * 4 + (threadIdx.x >> 6);
  int l = threadIdx.x & 63, g = l >> 4, j = l & 15;
  float b2s = P[0] * INV_SQRT_D, cw2 = P[3];
  float q[8];
  unp8(*(const uint4*)(QK + (size_t)row * UU + j * 4), q);
  int s = rp[row], e = rp[row + 1];
  float m = -3.0e38f, z = 0.f;
  float acc[8] = {0.f, 0.f, 0.f, 0.f, 0.f, 0.f, 0.f, 0.f};
  int i0 = s + g;
  uint4 kA = {0, 0, 0, 0}, kB = {0, 0, 0, 0};
  float aA = 0.f, aB = 0.f;
  if (i0 < e) {
    uint2 w = pay[i0]; aA = __uint_as_float(w.y);
    kA = *(const uint4*)(QK + (size_t)w.x * UU + 64 + j * 4);
  }
  if (i0 + 4 < e) {
    uint2 w = pay[i0 + 4]; aB = __uint_as_float(w.y);
    kB = *(const uint4*)(QK + (size_t)w.x * UU + 64 + j * 4);
  }
  for (int i = i0; i < e; i += 4) {
    uint4 kC = {0, 0, 0, 0}; float aC = 0.f;
    if (i + 8 < e) {
      uint2 w = pay[i + 8]; aC = __uint_as_float(w.y);
      kC = *(const uint4*)(QK + (size_t)w.x * UU + 64 + j * 4);
    }
    float k[8]; unp8(kA, k);
    float d = 0.f;
#pragma unroll
    for (int t = 0; t < 8; t++) d = fmaf(q[t], k[t], d);
    d = redsum16(d);
    float sv = b2s * d + aA;
    if (j == 0) s2c[i] = sv;
    if (sv <= m) {
      float p = __expf(sv - m);
      z += p;
#pragma unroll
      for (int t = 0; t < 8; t++) acc[t] = fmaf(p, k[t], acc[t]);
    } else {
      float r = __expf(m - sv);
      z = fmaf(z, r, 1.f);
#pragma unroll
      for (int t = 0; t < 8; t++) acc[t] = fmaf(acc[t], r, k[t]);
      m = sv;
    }
    kA = kB; aA = aB; kB = kC; aB = aC;
  }
  float mx = fmaxf(m, __shfl_xor(m, 16, 64));
  mx = fmaxf(mx, __shfl_xor(mx, 32, 64));
  float r = (z > 0.f) ? __expf(m - mx) : 0.f;
  float zz = z * r;
  zz += __shfl_xor(zz, 16, 64);
  zz += __shfl_xor(zz, 32, 64);
#pragma unroll
  for (int t = 0; t < 8; t++) {
    float v = acc[t] * r;
    v += __shfl_xor(v, 16, 64);
    v += __shfl_xor(v, 32, 64);
    acc[t] = v;
  }
  if (l == 0) L2[row] = (zz > 0.f) ? (mx + __logf(zz)) : 0.f;
  if (g == 0) {
    float coef = (zz > 0.f) ? cw2 / zz : 0.f;
    float o[8];
#pragma unroll
    for (int t = 0; t < 8; t++) o[t] = coef * acc[t];
    *(uint4*)(dAll + (size_t)row * UU + 0 + j * 4) = pk8(o);
  }
}

// ---------------- fused t3 fwd + dQ3 body ----------------
__device__ void t3_body(int bx, const unsigned* __restrict__ QK,
                        const float* __restrict__ Tt,
                        const float* __restrict__ P,
                        const uint2* __restrict__ pay,
                        const int* __restrict__ rp,
                        float* __restrict__ s3c,
                        float* __restrict__ L3,
                        unsigned* __restrict__ dAll) {
  __shared__ float sT[2 * DD];
  int tid = threadIdx.x;
  sT[tid] = Tt[tid];
  __syncthreads();
  int row = bx * 4 + (tid >> 6);
  int l = tid & 63, g = l >> 4, j = l & 15;
  float b3s = P[1] * INV_D, cw3 = P[4];
  float q[8];
  unp8(*(const uint4*)(QK + (size_t)row * UU + 128 + j * 4), q);
  int s = rp[row], e = rp[row + 1];
  float m = -3.0e38f, z = 0.f;
  float acc[8] = {0.f, 0.f, 0.f, 0.f, 0.f, 0.f, 0.f, 0.f};
  int i0 = s + g;
  uint4 kuA = {0, 0, 0, 0}, kvA = {0, 0, 0, 0};
  uint4 kuB = {0, 0, 0, 0}, kvB = {0, 0, 0, 0};
  int taA = 0, taB = 0;
  if (i0 < e) {
    uint2 w = pay[i0]; int u = w.x >> 16, v = w.x & 0xffff; taA = (int)w.y;
    kuA = *(const uint4*)(QK + (size_t)u * UU + 192 + j * 4);
    kvA = *(const uint4*)(QK + (size_t)v * UU + 192 + j * 4);
  }
  if (i0 + 4 < e) {
    uint2 w = pay[i0 + 4]; int u = w.x >> 16, v = w.x & 0xffff; taB = (int)w.y;
    kuB = *(const uint4*)(QK + (size_t)u * UU + 192 + j * 4);
    kvB = *(const uint4*)(QK + (size_t)v * UU + 192 + j * 4);
  }
  for (int i = i0; i < e; i += 4) {
    uint4 kuC = {0, 0, 0, 0}, kvC = {0, 0, 0, 0}; int taC = 0;
    if (i + 8 < e) {
      uint2 w = pay[i + 8]; int u = w.x >> 16, v = w.x & 0xffff; taC = (int)w.y;
      kuC = *(const uint4*)(QK + (size_t)u * UU + 192 + j * 4);
      kvC = *(const uint4*)(QK + (size_t)v * UU + 192 + j * 4);
    }
    float ku[8], kv[8]; unp8(kuA, ku); unp8(kvA, kv);
    const float* tv = &sT[taA * DD + j * 8];
    float et[8], d = 0.f;
#pragma unroll
    for (int t = 0; t < 8; t++) { et[t] = ku[t] * kv[t] * tv[t]; d = fmaf(q[t], et[t], d); }
    d = redsum16(d);
    float sv = b3s * d;
    if (j == 0) s3c[i] = sv;
    if (sv <= m) {
      float p = __expf(sv - m);
      z += p;
#pragma unroll
      for (int t = 0; t < 8; t++) acc[t] = fmaf(p, et[t], acc[t]);
    } else {
      float r = __expf(m - sv);
      z = fmaf(z, r, 1.f);
#pragma unroll
      for (int t = 0; t < 8; t++) acc[t] = fmaf(acc[t], r, et[t]);
      m = sv;
    }
    kuA = kuB; kvA = kvB; taA = taB;
    kuB = kuC; kvB = kvC; taB = taC;
  }
  float mx = fmaxf(m, __shfl_xor(m, 16, 64));
  mx = fmaxf(mx, __shfl_xor(mx, 32, 64));
  float r = (z > 0.f) ? __expf(m - mx) : 0.f;
  float zz = z * r;
  zz += __shfl_xor(zz, 16, 64);
  zz += __shfl_xor(zz, 32, 64);
#pragma unroll
  for (int t = 0; t < 8; t++) {
    float v = acc[t] * r;
    v += __shfl_xor(v, 16, 64);
    v += __shfl_xor(v, 32, 64);
    acc[t] = v;
  }
  if (l == 0) L3[row] = (zz > 0.f) ? (mx + __logf(zz)) : 0.f;
  if (g == 0) {
    float coef = (zz > 0.f) ? cw3 / zz : 0.f;
    float o[8];
#pragma unroll
    for (int t = 0; t < 8; t++) o[t] = coef * acc[t];
    *(uint4*)(dAll + (size_t)row * UU + 128 + j * 4) = pk8(o);
  }
}

// ---------------- memory-bank energy body ----------------
__device__ void em_body(int bx, const unsigned* __restrict__ QK,
                        const float* __restrict__ Km,
                        const float* __restrict__ P,
                        unsigned* __restrict__ dAll,
                        float* __restrict__ Lm) {
  __shared__ float sKm[KM * DD];
  int tid = threadIdx.x;
  for (int i = tid; i < KM * DD; i += 256) sKm[i] = Km[i];
  __syncthreads();
  int row = bx * 4 + (tid >> 6);
  int l = tid & 63, g = l >> 4, j = l & 15;
  float bms = P[2] * INV_SQRT_D, cwm = P[5];
  float q[8];
  unp8(*(const uint4*)(QK + (size_t)row * UU + 256 + j * 4), q);
  float dk[8];
#pragma unroll
  for (int kk = 0; kk < 8; kk++) {
    int k = g * 8 + kk;
    const float* kr = &sKm[k * DD + j * 8];
    float d = 0.f;
#pragma unroll
    for (int t = 0; t < 8; t++) d = fmaf(q[t], kr[t], d);
    dk[kk] = redsum16(d) * bms;
  }
  float m = dk[0];
#pragma unroll
  for (int kk = 1; kk < 8; kk++) m = fmaxf(m, dk[kk]);
  float mx = fmaxf(m, __shfl_xor(m, 16, 64));
  mx = fmaxf(mx, __shfl_xor(mx, 32, 64));
  float p[8], z = 0.f;
#pragma unroll
  for (int kk = 0; kk < 8; kk++) { p[kk] = __expf(dk[kk] - mx); z += p[kk]; }
  float zz = z;
  zz += __shfl_xor(zz, 16, 64);
  zz += __shfl_xor(zz, 32, 64);
  if (l == 0) Lm[row] = mx + __logf(zz);
  float coef = cwm / zz;
  float acc[8] = {0.f, 0.f, 0.f, 0.f, 0.f, 0.f, 0.f, 0.f};
#pragma unroll
  for (int kk = 0; kk < 8; kk++) {
    int k = g * 8 + kk;
    const float* kr = &sKm[k * DD + j * 8];
    float pc_ = p[kk] * coef;
#pragma unroll
    for (int t = 0; t < 8; t++) acc[t] = fmaf(pc_, kr[t], acc[t]);
  }
#pragma unroll
  for (int t = 0; t < 8; t++) {
    float v = acc[t];
    v += __shfl_xor(v, 16, 64);
    v += __shfl_xor(v, 32, 64);
    acc[t] = v;
  }
  if (g == 0) *(uint4*)(dAll + (size_t)row * UU + 256 + j * 4) = pk8(acc);
}

// fused phase2: e2_fused + t3_fused + em_row (mutually independent)
__global__ __launch_bounds__(256) void phase2_k(const unsigned* __restrict__ QK,
                                                const float* __restrict__ Tt,
                                                const float* __restrict__ Km,
                                                const float* __restrict__ P,
                                                const uint2* __restrict__ payc2,
                                                const int* __restrict__ rp_c2,
                                                const uint2* __restrict__ payc3,
                                                const int* __restrict__ rp_c3,
                                                float* __restrict__ s2c,
                                                float* __restrict__ L2,
                                                float* __restrict__ s3c,
                                                float* __restrict__ L3,
                                                float* __restrict__ Lm,
                                                unsigned* __restrict__ dAll) {
  int bx = blockIdx.x;
  if (bx < ROWB) e2_body(bx, QK, P, payc2, rp_c2, s2c, L2, dAll);
  else if (bx < 2 * ROWB) t3_body(bx - ROWB, QK, Tt, P, payc3, rp_c3, s3c, L3, dAll);
  else em_body(bx - 2 * ROWB, QK, Km, P, dAll, Lm);
}

// ---------------- dK2 gather body ----------------
__device__ void dk2_body(int bx, const unsigned* __restrict__ QK,
                         const float* __restrict__ s2c,
                         const float* __restrict__ L2,
                         const float* __restrict__ P,
                         const uint2* __restrict__ pay,
                         const int* __restrict__ rp,
                         unsigned* __restrict__ dAll) {
  int row = bx * 4 + (threadIdx.x >> 6);
  int l = threadIdx.x & 63, g = l >> 4, j = l & 15;
  float cw2 = P[3];
  int s = rp[row], e = rp[row + 1];
  float acc[8] = {0.f, 0.f, 0.f, 0.f, 0.f, 0.f, 0.f, 0.f};
  int i0 = s + g;
  uint4 qA = {0, 0, 0, 0}, qB = {0, 0, 0, 0};
  float scA = 0.f, lcA = 0.f, scB = 0.f, lcB = 0.f;
  if (i0 < e) {
    uint2 w = pay[i0]; scA = s2c[w.x]; lcA = L2[w.y];
    qA = *(const uint4*)(QK + (size_t)w.y * UU + 0 + j * 4);
  }
  if (i0 + 4 < e) {
    uint2 w = pay[i0 + 4]; scB = s2c[w.x]; lcB = L2[w.y];
    qB = *(const uint4*)(QK + (size_t)w.y * UU + 0 + j * 4);
  }
  for (int i = i0; i < e; i += 4) {
    uint4 qC = {0, 0, 0, 0}; float scC = 0.f, lcC = 0.f;
    if (i + 8 < e) {
      uint2 w = pay[i + 8]; scC = s2c[w.x]; lcC = L2[w.y];
      qC = *(const uint4*)(QK + (size_t)w.y * UU + 0 + j * 4);
    }
    float w = cw2 * __expf(scA - lcA);
    float qv[8]; unp8(qA, qv);
#pragma unroll
    for (int t = 0; t < 8; t++) acc[t] = fmaf(w, qv[t], acc[t]);
    qA = qB; scA = scB; lcA = lcB;
    qB = qC; scB = scC; lcB = lcC;
  }
#pragma unroll
  for (int t = 0; t < 8; t++) {
    float v = acc[t];
    v += __shfl_xor(v, 16, 64);
    v += __shfl_xor(v, 32, 64);
    acc[t] = v;
  }
  if (g == 0) *(uint4*)(dAll + (size_t)row * UU + 64 + j * 4) = pk8(acc);
}

// ---------------- dK3 gather body ----------------
__device__ void dk3_body(int bx, const unsigned* __restrict__ QK,
                         const float* __restrict__ Tt,
                         const float* __restrict__ s3c,
                         const float* __restrict__ L3,
                         const float* __restrict__ P,
                         const uint2* __restrict__ pay,
                         const int* __restrict__ rp,
                         unsigned* __restrict__ dAll) {
  __shared__ float sT[2 * DD];
  int tid = threadIdx.x;
  sT[tid] = Tt[tid];
  __syncthreads();
  int row = bx * 4 + (tid >> 6);
  int l = tid & 63, g = l >> 4, j = l & 15;
  float cw3 = P[4];
  int s = rp[row], e = rp[row + 1];
  float acc[8] = {0.f, 0.f, 0.f, 0.f, 0.f, 0.f, 0.f, 0.f};
  int i0 = s + g;
  uint4 qA = {0, 0, 0, 0}, kA = {0, 0, 0, 0};
  uint4 qB = {0, 0, 0, 0}, kB = {0, 0, 0, 0};
  int taA = 0, taB = 0;
  float scA = 0.f, lcA = 0.f, scB = 0.f, lcB = 0.f;
  if (i0 < e) {
    uint2 w = pay[i0]; int o = w.x >> 16, c = w.x & 0xffff; unsigned sp = w.y;
    taA = (int)(sp & 1); scA = s3c[sp >> 1]; lcA = L3[c];
    qA = *(const uint4*)(QK + (size_t)c * UU + 128 + j * 4);
    kA = *(const uint4*)(QK + (size_t)o * UU + 192 + j * 4);
  }
  if (i0 + 4 < e) {
    uint2 w = pay[i0 + 4]; int o = w.x >> 16, c = w.x & 0xffff; unsigned sp = w.y;
    taB = (int)(sp & 1); scB = s3c[sp >> 1]; lcB = L3[c];
    qB = *(const uint4*)(QK + (size_t)c * UU + 128 + j * 4);
    kB = *(const uint4*)(QK + (size_t)o * UU + 192 + j * 4);
  }
  for (int i = i0; i < e; i += 4) {
    uint4 qC = {0, 0, 0, 0}, kC = {0, 0, 0, 0}; int taC = 0;
    float scC = 0.f, lcC = 0.f;
    if (i + 8 < e) {
      uint2 w = pay[i + 8]; int o = w.x >> 16, c = w.x & 0xffff; unsigned sp = w.y;
      taC = (int)(sp & 1); scC = s3c[sp >> 1]; lcC = L3[c];
      qC = *(const uint4*)(QK + (size_t)c * UU + 128 + j * 4);
      kC = *(const uint4*)(QK + (size_t)o * UU + 192 + j * 4);
    }
    float w = cw3 * __expf(scA - lcA);
    float qv[8], ko[8]; unp8(qA, qv); unp8(kA, ko);
    const float* tv = &sT[taA * DD + j * 8];
#pragma unroll
    for (int t = 0; t < 8; t++) acc[t] = fmaf(w * tv[t], qv[t] * ko[t], acc[t]);
    qA = qB; kA = kB; taA = taB; scA = scB; lcA = lcB;
    qB = qC; kB = kC; taB = taC; scB = scC; lcB = lcC;
  }
#pragma unroll
  for (int t = 0; t < 8; t++) {
    float v = acc[t];
    v += __shfl_xor(v, 16, 64);
    v += __shfl_xor(v, 32, 64);
    acc[t] = v;
  }
  if (g == 0) *(uint4*)(dAll + (size_t)row * UU + 192 + j * 4) = pk8(acc);
}

// fused phase3: dk2_gather + dk3_gather (mutually independent)
__global__ __launch_bounds__(256) void phase3_k(const unsigned* __restrict__ QK,
                                                const float* __restrict__ Tt,
                                                const float* __restrict__ P,
                                                const float* __restrict__ s2c,
                                                const float* __restrict__ L2,
                                                const uint2* __restrict__ payu2,
                                                const int* __restrict__ rp_u2,
                                                const float* __restrict__ s3c,
                                                const float* __restrict__ L3,
                                                const uint2* __restrict__ payuv,
                                                const int* __restrict__ rp_uv,
                                                unsigned* __restrict__ dAll) {
  int bx = blockIdx.x;
  if (bx < ROWB) dk2_body(bx, QK, s2c, L2, P, payu2, rp_u2, dAll);
  else dk3_body(bx - ROWB, QK, Tt, s3c, L3, P, payuv, rp_uv, dAll);
}

// ---------------- LN backward + clips + update ----------------
__global__ __launch_bounds__(256) void ln_bwd(const float* __restrict__ X,
                                              const unsigned* __restrict__ dG,
                                              const float* __restrict__ gamma,
                                              const float* __restrict__ meanv,
                                              const float* __restrict__ rstdv,
                                              float* __restrict__ out) {
  int row = blockIdx.x * 4 + (threadIdx.x >> 6);
  if (row >= NN) return;
  int l = threadIdx.x & 63;
  float mu = meanv[row], rstd = rstdv[row];
  float2 x2 = *(const float2*)(X + row * DD + 2 * l);
  unsigned gw = dG[(size_t)row * 64 + l];
  float2 ga = *(const float2*)(gamma + 2 * l);
  float xh0 = (x2.x - mu) * rstd, xh1 = (x2.y - mu) * rstd;
  float dh0 = blo(gw) * ga.x, dh1 = bhi(gw) * ga.y;
  float sa = wredsum(dh0 + dh1) * (1.f / DD);
  float sb = wredsum(dh0 * xh0 + dh1 * xh1) * (1.f / DD);
  float dx0 = rstd * (dh0 - sa - xh0 * sb);
  float dx1 = rstd * (dh1 - sa - xh1 * sb);
  float gn = fmaxf(sqrtf(wredsum(dx0 * dx0 + dx1 * dx1)), 1e-6f);
  float sc = fminf(1.f / gn, 1.f);
  dx0 *= sc; dx1 *= sc;
  float xn0 = x2.x - 0.1f * 0.9999f * dx0;
  float xn1 = x2.y - 0.1f * 0.9999f * dx1;
  float sn = fmaxf(sqrtf(wredsum(xn0 * xn0 + xn1 * xn1)), 1e-6f);
  float sc2 = fminf(10.f / sn, 1.f);
  float2 o; o.x = xn0 * sc2; o.y = xn1 * sc2;
  *(float2*)(out + row * DD + 2 * l) = o;
}

// ---------------- final energy scalar (parallel, atomic) ----------------
__global__ __launch_bounds__(256) void eval_write(const float* __restrict__ L2,
                                                  const float* __restrict__ L3,
                                                  const float* __restrict__ Lm,
                                                  const float* __restrict__ P,
                                                  float* __restrict__ out) {
  int i = blockIdx.x * 256 + threadIdx.x;
  float a2 = 0.f, a3 = 0.f, am = 0.f;
  if (i < NN) { a2 = L2[i]; a3 = L3[i]; am = Lm[i]; }
  a2 = wredsum(a2); a3 = wredsum(a3); am = wredsum(am);
  __shared__ float r2[4], r3[4], rm[4];
  int wv = threadIdx.x >> 6, l = threadIdx.x & 63;
  if (l == 0) { r2[wv] = a2; r3[wv] = a3; rm[wv] = am; }
  __syncthreads();
  if (threadIdx.x == 0) {
    float S2 = r2[0] + r2[1] + r2[2] + r2[3];
    float S3 = r3[0] + r3[1] + r3[2] + r3[3];
    float Sm = rm[0] + rm[1] + rm[2] + rm[3];
    atomicAdd(out, P[6] * S2 + P[7] * S3 + P[8] * Sm);
  }
}

extern "C" void kernel_launch(void* const* d_in, const int* in_sizes, int n_in,
                              void* d_out, int out_size, void* d_ws, size_t ws_size,
                              hipStream_t stream) {
  (void)in_sizes; (void)n_in; (void)out_size;
  const float* X = (const float*)d_in[0];
  const float* EA = (const float*)d_in[1];
  const float* ln_g = (const float*)d_in[2];
  const float* ln_b = (const float*)d_in[3];
  const float* W_Q2 = (const float*)d_in[4];
  const float* W_K2 = (const float*)d_in[5];
  const float* W_Q3 = (const float*)d_in[6];
  const float* W_K3 = (const float*)d_in[7];
  const float* T_tau = (const float*)d_in[8];
  const float* W_Qm = (const float*)d_in[9];
  const float* W_Km = (const float*)d_in[10];
  const float* B_mem = (const float*)d_in[11];
  const float* We1 = (const float*)d_in[12];
  const float* be1 = (const float*)d_in[13];
  const float* We2 = (const float*)d_in[14];
  const float* be2 = (const float*)d_in[15];
  const float* l2s = (const float*)d_in[16];
  const float* l3s = (const float*)d_in[17];
  const float* lms = (const float*)d_in[18];
  const float* b2s = (const float*)d_in[19];
  const float* b3s = (const float*)d_in[20];
  const float* bms = (const float*)d_in[21];
  const int* c2 = (const int*)d_in[22];
  const int* u2 = (const int*)d_in[23];
  const int* c3 = (const int*)d_in[24];
  const int* u3 = (const int*)d_in[25];
  const int* v3 = (const int*)d_in[26];
  const int* ttau = (const int*)d_in[27];
  float* out = (float*)d_out;

  float* ws = (float*)d_ws;
  size_t off = 0;
  auto alloc = [&](size_t n) { float* p = ws + off; off += n; return p; };
  const size_t ND = (size_t)NN * DD;
  unsigned* Gb = (unsigned*)alloc(ND / 2);
  unsigned* QKall = (unsigned*)alloc((size_t)NN * UU);
  unsigned* dAll = (unsigned*)alloc((size_t)NN * UU);
  unsigned* dG = (unsigned*)alloc(ND / 2);
  ushort_t* Wt5 = (ushort_t*)alloc(640 * 128 / 2);
  ushort_t* Wcat = (ushort_t*)alloc(640 * 128 / 2);
  float* Km = alloc((size_t)KM * DD);
  float* a2 = alloc(EE);
  float* s2c = alloc(EE);
  float* s3c = alloc(TT);
  float* meanv = alloc(NN);
  float* rstdv = alloc(NN);
  float* L2 = alloc(NN);
  float* L3 = alloc(NN);
  float* Lm = alloc(NN);
  float* Pparams = alloc(16);
  int* cnt = (int*)alloc(4 * (size_t)NN);
  int* rowptr = (int*)alloc(4 * (size_t)(NN + 1));
  int* cursor = (int*)alloc(4 * (size_t)NN);
  int* spart = (int*)alloc(4 * SCAN_NB);
  uint2* payc2 = (uint2*)alloc(2 * (size_t)EE);
  uint2* payu2 = (uint2*)alloc(2 * (size_t)EE);
  uint2* payc3 = (uint2*)alloc(2 * (size_t)TT);
  uint2* payuv = (uint2*)alloc(4 * (size_t)TT);
  if (off * sizeof(float) > ws_size) return;

  int* cnt_c2 = cnt, *cnt_u2 = cnt + NN, *cnt_c3 = cnt + 2 * NN, *cnt_uv = cnt + 3 * NN;
  int* rp_c2 = rowptr, *rp_u2 = rowptr + (NN + 1), *rp_c3 = rowptr + 2 * (NN + 1), *rp_uv = rowptr + 3 * (NN + 1);
  int* cu_c2 = cursor, *cu_u2 = cursor + NN, *cu_c3 = cursor + 2 * NN, *cu_uv = cursor + 3 * NN;

  hipMemsetAsync(cnt, 0, 4ull * NN * sizeof(int), stream);
  hipMemsetAsync(out + ND, 0, sizeof(float), stream);

  params_k<<<1, 64, 0, stream>>>(l2s, l3s, lms, b2s, b3s, bms, Pparams);

  int rowB = ROWB;

  ln_fwd<<<rowB, 256, 0, stream>>>(X, ln_g, ln_b, Gb, meanv, rstdv);
  w_conv<<<320, 256, 0, stream>>>(W_Q2, W_K2, W_Q3, W_K3, W_Qm, Wt5, Wcat);
  gemm_km<<<1, 256, 0, stream>>>(B_mem, W_Km, Km, KM);
  fwd_k<<<MB * 10 + EDGE_BLKS, 256, 0, stream>>>((const ushort_t*)Gb, Wt5, (ushort_t*)QKall,
                                                 EA, We1, be1, We2, be2, a2);

  hist_k<<<HB2 + HBT, 256, 0, stream>>>(c2, u2, c3, u3, v3, cnt_c2, cnt_u2, cnt_c3, cnt_uv);
  scan_p1<<<dim3(SCAN_NB, 4), 256, 0, stream>>>(cnt, spart);
  scan_p2<<<1, 256, 0, stream>>>(spart);
  scan_p3<<<dim3(SCAN_NB, 4), 256, 0, stream>>>(cnt, spart, rowptr, cursor);
  scat_k<<<HB2 + HBT, 256, 0, stream>>>(c2, u2, a2, cu_c2, cu_u2, payc2, payu2,
                                        c3, u3, v3, ttau, cu_c3, cu_uv, payc3, payuv);

  phase2_k<<<3 * ROWB, 256, 0, stream>>>(QKall, T_tau, Km, Pparams,
                                         payc2, rp_c2, payc3, rp_c3,
                                         s2c, L2, s3c, L3, Lm, dAll);
  phase3_k<<<2 * ROWB, 256, 0, stream>>>(QKall, T_tau, Pparams,
                                         s2c, L2, payu2, rp_u2,
                                         s3c, L3, payuv, rp_uv, dAll);

  mfma_bwd<<<dim3(MB, 2), 256, 0, stream>>>((const ushort_t*)dAll, Wcat, dG, NN);

  ln_bwd<<<rowB, 256, 0, stream>>>(X, dG, ln_g, meanv, rstdv, out);
  eval_write<<<(NN + 255) / 256, 256, 0, stream>>>(L2, L3, Lm, Pparams, out + ND);
}

// Round 5
// 768.280 us; speedup vs baseline: 1.2358x; 1.2358x over previous
//
#include <hip/hip_runtime.h>

#define NN 50000
#define DD 128
#define EE 800000
#define TT 400000
#define KM 32
#define UU 320  // uints per 640-col bf16 row
#define ROWB 12500           // NN/4
#define MB 782               // ceil(NN/64)
#define EDGE_BLKS 3125       // EE/256
#define SCAN_TILE 2048
#define SCAN_NB ((NN + SCAN_TILE - 1) / SCAN_TILE)  // 25

static constexpr float INV_SQRT_D = 0.08838834764831845f; // 1/sqrt(128)
static constexpr float INV_D = 1.f / 128.f;

typedef __attribute__((ext_vector_type(8))) short bf16x8;
typedef __attribute__((ext_vector_type(4))) float f32x4;
typedef unsigned short ushort_t;

__device__ __forceinline__ float softplus_f(float x) {
  return (x > 20.f) ? x : log1pf(__expf(x));
}

// exact rewrite of tanh-gelu: 0.5x(1+tanh(z)) == x * sigmoid(2z)
__device__ __forceinline__ float gelu_fast(float x) {
  float p = fmaf(0.044715f * x * x, x, x);
  float e = __expf(-1.5957691216057308f * p);
  return x * __builtin_amdgcn_rcpf(1.f + e);
}

__device__ __forceinline__ float wredsum(float v) {
#pragma unroll
  for (int m = 32; m; m >>= 1) v += __shfl_xor(v, m, 64);
  return v;
}

__device__ __forceinline__ float redsum16(float v) {
#pragma unroll
  for (int m = 1; m < 16; m <<= 1) v += __shfl_xor(v, m, 64);
  return v;
}

__device__ __forceinline__ float blo(unsigned w) { return __uint_as_float(w << 16); }
__device__ __forceinline__ float bhi(unsigned w) { return __uint_as_float(w & 0xffff0000u); }
__device__ __forceinline__ unsigned pack_bf16(float a, float b) {
  unsigned ua = __float_as_uint(a); ua += 0x7fff + ((ua >> 16) & 1);
  unsigned ub = __float_as_uint(b); ub += 0x7fff + ((ub >> 16) & 1);
  return (ua >> 16) | (ub & 0xffff0000u);
}
__device__ __forceinline__ ushort_t bf16_1(float x) {
  unsigned u = __float_as_uint(x); u += 0x7fff + ((u >> 16) & 1);
  return (ushort_t)(u >> 16);
}
__device__ __forceinline__ void unp8(uint4 w, float* f) {
  f[0] = blo(w.x); f[1] = bhi(w.x); f[2] = blo(w.y); f[3] = bhi(w.y);
  f[4] = blo(w.z); f[5] = bhi(w.z); f[6] = blo(w.w); f[7] = bhi(w.w);
}
__device__ __forceinline__ uint4 pk8(const float* f) {
  uint4 r;
  r.x = pack_bf16(f[0], f[1]); r.y = pack_bf16(f[2], f[3]);
  r.z = pack_bf16(f[4], f[5]); r.w = pack_bf16(f[6], f[7]);
  return r;
}

// params: [0]=b2 [1]=b3 [2]=bm [3]=cw2 [4]=cw3 [5]=cwm [6]=-sp2/b2 [7]=-sp3/b3 [8]=-spm/bm
__global__ void params_k(const float* l2, const float* l3, const float* lm,
                         const float* b2, const float* b3, const float* bm,
                         float* __restrict__ P) {
  if (threadIdx.x != 0) return;
  float B2 = fminf(softplus_f(b2[0]), 5.f);
  float B3 = fminf(softplus_f(b3[0]), 5.f);
  float Bm = fminf(softplus_f(bm[0]), 5.f);
  float S2 = softplus_f(l2[0]);
  float S3 = softplus_f(l3[0]);
  float Sm = softplus_f(lm[0]);
  P[0] = B2; P[1] = B3; P[2] = Bm;
  P[3] = -S2 * INV_SQRT_D; P[4] = -S3 * INV_D; P[5] = -Sm * INV_SQRT_D;
  P[6] = -S2 / B2; P[7] = -S3 / B3; P[8] = -Sm / Bm;
}

// ---------------- LayerNorm forward -> bf16 G ----------------
__global__ __launch_bounds__(256) void ln_fwd(const float* __restrict__ X,
                                              const float* __restrict__ gamma,
                                              const float* __restrict__ beta,
                                              unsigned* __restrict__ Gb,
                                              float* __restrict__ meanv,
                                              float* __restrict__ rstdv) {
  int row = blockIdx.x * 4 + (threadIdx.x >> 6);
  if (row >= NN) return;
  int l = threadIdx.x & 63;
  float2 x2 = *(const float2*)(X + row * DD + 2 * l);
  float mu = wredsum(x2.x + x2.y) * (1.f / DD);
  float d0 = x2.x - mu, d1 = x2.y - mu;
  float var = wredsum(d0 * d0 + d1 * d1) * (1.f / DD);
  float rstd = rsqrtf(var + 1e-5f);
  float2 g2 = *(const float2*)(gamma + 2 * l);
  float2 b2 = *(const float2*)(beta + 2 * l);
  float o0 = d0 * rstd * g2.x + b2.x;
  float o1 = d1 * rstd * g2.y + b2.y;
  Gb[(size_t)row * 64 + l] = pack_bf16(o0, o1);
  if (l == 0) { meanv[row] = mu; rstdv[row] = rstd; }
}

// ---------------- weight conversion ----------------
__global__ __launch_bounds__(256) void w_conv(const float* W0, const float* W1, const float* W2,
                                              const float* W3, const float* W4,
                                              ushort_t* __restrict__ Wt,
                                              ushort_t* __restrict__ Wc) {
  int idx = blockIdx.x * 256 + threadIdx.x;
  if (idx >= 640 * 128) return;
  const float* Ws[5] = {W0, W1, W2, W3, W4};
  int n = idx >> 7, k = idx & 127;
  Wt[idx] = bf16_1(Ws[n >> 7][(size_t)k * 128 + (n & 127)]);
  int k2 = idx >> 7, n2 = idx & 127;
  Wc[(size_t)n2 * 640 + k2] = bf16_1(Ws[k2 >> 7][(size_t)n2 * 128 + (k2 & 127)]);
}

// ---------------- fwd MFMA GEMM body ----------------
__device__ void mfma_fwd_body(int bxr, int by, const ushort_t* __restrict__ Gb,
                              const ushort_t* __restrict__ Wt,
                              ushort_t* __restrict__ QK, int M) {
  __shared__ ushort_t sB[64][136];
  int tid = threadIdx.x;
  int nb = by * 64;
  for (int idx = tid; idx < 64 * 16; idx += 256) {
    int r = idx >> 4, c8 = idx & 15;
    *(bf16x8*)&sB[r][c8 * 8] = *(const bf16x8*)(Wt + (size_t)(nb + r) * 128 + c8 * 8);
  }
  __syncthreads();
  int w = tid >> 6, l = tid & 63, quad = l >> 4, j = l & 15;
  int row0 = bxr * 64 + w * 16;
  int arow = row0 + j; if (arow >= M) arow = M - 1;
  const bf16x8* ap = (const bf16x8*)(Gb + (size_t)arow * 128);
  f32x4 acc[4];
#pragma unroll
  for (int nt = 0; nt < 4; nt++) acc[nt] = (f32x4){0.f, 0.f, 0.f, 0.f};
#pragma unroll
  for (int kc = 0; kc < 4; kc++) {
    bf16x8 a = ap[kc * 4 + quad];
#pragma unroll
    for (int nt = 0; nt < 4; nt++) {
      bf16x8 b = *(const bf16x8*)&sB[nt * 16 + j][kc * 32 + quad * 8];
      acc[nt] = __builtin_amdgcn_mfma_f32_16x16x32_bf16(a, b, acc[nt], 0, 0, 0);
    }
  }
#pragma unroll
  for (int nt = 0; nt < 4; nt++)
#pragma unroll
    for (int r = 0; r < 4; r++) {
      int row = row0 + quad * 4 + r;
      if (row < M) QK[(size_t)row * 640 + nb + nt * 16 + j] = bf16_1(acc[nt][r]);
    }
}

// ---------------- edge MLP body ----------------
__device__ void edge_mlp_body(int bx, const float* __restrict__ EA,
                              const float* __restrict__ We1,
                              const float* __restrict__ be1,
                              const float* __restrict__ We2,
                              const float* __restrict__ be2,
                              float* __restrict__ a2) {
  __shared__ float sW1[16 * 128];
  __shared__ float sb1[128];
  __shared__ float sW2[128];
  int tid = threadIdx.x;
  for (int i = tid; i < 2048; i += 256) sW1[i] = We1[i];
  if (tid < 128) { sb1[tid] = be1[tid]; sW2[tid] = We2[tid]; }
  __syncthreads();
  int w = tid >> 6, l = tid & 63;
  int m = l & 15, q = l >> 4;
  union u8 { bf16x8 v; ushort_t s[8]; };
  u8 bf[8];
  float bb[8], ww[8];
#pragma unroll
  for (int nt = 0; nt < 8; nt++) {
    int n = nt * 16 + m;
#pragma unroll
    for (int j = 0; j < 8; j++) {
      int k = q * 8 + j;
      bf[nt].s[j] = (k < 16) ? bf16_1(sW1[k * 128 + n]) : (ushort_t)0;
    }
    bb[nt] = sb1[n];
    ww[nt] = sW2[n];
  }
  float be2v = be2[0];
  for (int batch = 0; batch < 4; batch++) {
    int e0 = bx * 256 + batch * 64 + w * 16;
    u8 af;
    if (q < 2) {
      const float* ep = EA + (size_t)(e0 + m) * 16 + q * 8;
      float4 v0 = *(const float4*)ep;
      float4 v1 = *(const float4*)(ep + 4);
      af.s[0] = bf16_1(v0.x); af.s[1] = bf16_1(v0.y);
      af.s[2] = bf16_1(v0.z); af.s[3] = bf16_1(v0.w);
      af.s[4] = bf16_1(v1.x); af.s[5] = bf16_1(v1.y);
      af.s[6] = bf16_1(v1.z); af.s[7] = bf16_1(v1.w);
    } else {
#pragma unroll
      for (int j = 0; j < 8; j++) af.s[j] = 0;
    }
    float s0 = 0.f, s1 = 0.f, s2 = 0.f, s3 = 0.f;
#pragma unroll
    for (int nt = 0; nt < 8; nt++) {
      float bias = bb[nt];
      f32x4 cin = (f32x4){bias, bias, bias, bias};
      f32x4 acc = __builtin_amdgcn_mfma_f32_16x16x32_bf16(af.v, bf[nt].v, cin, 0, 0, 0);
      float w2v = ww[nt];
      s0 = fmaf(gelu_fast(acc[0]), w2v, s0);
      s1 = fmaf(gelu_fast(acc[1]), w2v, s1);
      s2 = fmaf(gelu_fast(acc[2]), w2v, s2);
      s3 = fmaf(gelu_fast(acc[3]), w2v, s3);
    }
    s0 = redsum16(s0); s1 = redsum16(s1); s2 = redsum16(s2); s3 = redsum16(s3);
    if (m == 0) {
      int eb = e0 + q * 4;
      a2[eb + 0] = s0 + be2v;
      a2[eb + 1] = s1 + be2v;
      a2[eb + 2] = s2 + be2v;
      a2[eb + 3] = s3 + be2v;
    }
  }
}

// fused fwd: mfma_fwd (MFMA pipe) + edge_mlp (VALU pipe) in one dispatch
__global__ __launch_bounds__(256) void fwd_k(const ushort_t* __restrict__ Gb,
                                             const ushort_t* __restrict__ Wt,
                                             ushort_t* __restrict__ QK,
                                             const float* __restrict__ EA,
                                             const float* __restrict__ We1,
                                             const float* __restrict__ be1,
                                             const float* __restrict__ We2,
                                             const float* __restrict__ be2,
                                             float* __restrict__ a2) {
  int bx = blockIdx.x;
  if (bx < MB * 10) {
    mfma_fwd_body(bx / 10, bx % 10, Gb, Wt, QK, NN);
  } else {
    edge_mlp_body(bx - MB * 10, EA, We1, be1, We2, be2, a2);
  }
}

// ---------------- bwd MFMA GEMM: dG[M,128](bf16) = dAll[M,640](bf16) @ Wc^T ----------------
__global__ __launch_bounds__(256) void mfma_bwd(const ushort_t* __restrict__ dAll,
                                                const ushort_t* __restrict__ Wc,
                                                unsigned* __restrict__ dG, int M) {
  __shared__ ushort_t sB[64][40];
  int tid = threadIdx.x;
  int nb = blockIdx.y * 64;
  int w = tid >> 6, l = tid & 63, quad = l >> 4, j = l & 15;
  int row0 = blockIdx.x * 64 + w * 16;
  int arow = row0 + j; if (arow >= M) arow = M - 1;
  const ushort_t* arp = dAll + (size_t)arow * 640;
  f32x4 acc[4];
#pragma unroll
  for (int nt = 0; nt < 4; nt++) acc[nt] = (f32x4){0.f, 0.f, 0.f, 0.f};
  int sr = tid >> 2, sc = tid & 3;
  for (int kc = 0; kc < 20; kc++) {
    __syncthreads();
    *(bf16x8*)&sB[sr][sc * 8] = *(const bf16x8*)(Wc + (size_t)(nb + sr) * 640 + kc * 32 + sc * 8);
    __syncthreads();
    bf16x8 a = *(const bf16x8*)(arp + kc * 32 + quad * 8);
#pragma unroll
    for (int nt = 0; nt < 4; nt++) {
      bf16x8 b = *(const bf16x8*)&sB[nt * 16 + j][quad * 8];
      acc[nt] = __builtin_amdgcn_mfma_f32_16x16x32_bf16(a, b, acc[nt], 0, 0, 0);
    }
  }
#pragma unroll
  for (int nt = 0; nt < 4; nt++)
#pragma unroll
    for (int r = 0; r < 4; r++) {
      int row = row0 + quad * 4 + r;
      if (row < M) ((ushort_t*)dG)[(size_t)row * 128 + nb + nt * 16 + j] = bf16_1(acc[nt][r]);
    }
}

// ---------------- small fp32 GEMM for Km = B_mem @ W_Km ----------------
__global__ __launch_bounds__(256, 1) void gemm_km(const float* __restrict__ A,
                                                  const float* __restrict__ W,
                                                  float* __restrict__ C, int M) {
  __shared__ float As[32][132];
  __shared__ float Wst[128][136];
  const int tid = threadIdx.x;
  for (int idx = tid; idx < 128 * 128; idx += 256) {
    int k = idx >> 7, jj = idx & 127;
    Wst[k][jj] = W[k * 128 + jj];
  }
  for (int idx = tid; idx < 32 * 128; idx += 256) {
    int r = idx >> 7, d = idx & 127;
    As[r][d] = A[r * 128 + d];
  }
  __syncthreads();
  int r = tid >> 3, c0 = (tid & 7) * 16;
  float acc[16];
#pragma unroll
  for (int q = 0; q < 16; q++) acc[q] = 0.f;
  for (int k = 0; k < 128; k++) {
    float av = As[r][k];
#pragma unroll
    for (int q = 0; q < 16; q++) acc[q] = fmaf(av, Wst[k][c0 + q], acc[q]);
  }
#pragma unroll
  for (int q = 0; q < 16; q++) C[r * 128 + c0 + q] = acc[q];
}

// ---------------- histograms with position capture (8-deep ILP) ----------------
// pos arrays record each item's within-row rank so the scatter pass needs NO atomics.
__global__ __launch_bounds__(256) void hist2(const int* __restrict__ a,
                                             const int* __restrict__ b,
                                             int* __restrict__ ca,
                                             int* __restrict__ cb,
                                             int* __restrict__ pos_a,
                                             int* __restrict__ pos_b, int n) {
  int base = blockIdx.x * 2048 + threadIdx.x;
  if (base + 1792 < n) {
    int av[8], bv[8], pa[8], pb[8];
#pragma unroll
    for (int k = 0; k < 8; k++) { int e = base + k * 256; av[k] = a[e]; bv[k] = b[e]; }
#pragma unroll
    for (int k = 0; k < 8; k++) pa[k] = atomicAdd(&ca[av[k]], 1);
#pragma unroll
    for (int k = 0; k < 8; k++) pb[k] = atomicAdd(&cb[bv[k]], 1);
#pragma unroll
    for (int k = 0; k < 8; k++) pos_a[base + k * 256] = pa[k];
#pragma unroll
    for (int k = 0; k < 8; k++) pos_b[base + k * 256] = pb[k];
  } else {
#pragma unroll
    for (int k = 0; k < 8; k++) {
      int e = base + k * 256;
      if (e < n) {
        pos_a[e] = atomicAdd(&ca[a[e]], 1);
        pos_b[e] = atomicAdd(&cb[b[e]], 1);
      }
    }
  }
}

__global__ __launch_bounds__(256) void hist_t3(const int* __restrict__ c,
                                               const int* __restrict__ u,
                                               const int* __restrict__ v,
                                               int* __restrict__ cc,
                                               int* __restrict__ cuv,
                                               int* __restrict__ pos_c,
                                               int* __restrict__ pos_u,
                                               int* __restrict__ pos_v, int n) {
  int base = blockIdx.x * 2048 + threadIdx.x;
  if (base + 1792 < n) {
    int cv[8], uv[8], vv[8], pc[8], pu[8], pv[8];
#pragma unroll
    for (int k = 0; k < 8; k++) { int t = base + k * 256; cv[k] = c[t]; uv[k] = u[t]; vv[k] = v[t]; }
#pragma unroll
    for (int k = 0; k < 8; k++) pc[k] = atomicAdd(&cc[cv[k]], 1);
#pragma unroll
    for (int k = 0; k < 8; k++) pu[k] = atomicAdd(&cuv[uv[k]], 1);
#pragma unroll
    for (int k = 0; k < 8; k++) pv[k] = atomicAdd(&cuv[vv[k]], 1);
#pragma unroll
    for (int k = 0; k < 8; k++) pos_c[base + k * 256] = pc[k];
#pragma unroll
    for (int k = 0; k < 8; k++) pos_u[base + k * 256] = pu[k];
#pragma unroll
    for (int k = 0; k < 8; k++) pos_v[base + k * 256] = pv[k];
  } else {
#pragma unroll
    for (int k = 0; k < 8; k++) {
      int t = base + k * 256;
      if (t < n) {
        pos_c[t] = atomicAdd(&cc[c[t]], 1);
        pos_u[t] = atomicAdd(&cuv[u[t]], 1);
        pos_v[t] = atomicAdd(&cuv[v[t]], 1);
      }
    }
  }
}

// ---------------- parallel 3-phase scan over 4 count arrays ----------------
__global__ __launch_bounds__(256) void scan_p1(const int* __restrict__ cnt,
                                               int* __restrict__ part) {
  int arr = blockIdx.y, b = blockIdx.x;
  const int* c = cnt + (size_t)arr * NN;
  int gi = b * SCAN_TILE + threadIdx.x * 8;
  int s = 0;
#pragma unroll
  for (int t = 0; t < 8; t++) s += (gi + t < NN) ? c[gi + t] : 0;
#pragma unroll
  for (int m = 32; m; m >>= 1) s += __shfl_xor(s, m, 64);
  __shared__ int wt[4];
  int lane = threadIdx.x & 63, wid = threadIdx.x >> 6;
  if (lane == 0) wt[wid] = s;
  __syncthreads();
  if (threadIdx.x == 0) part[arr * SCAN_NB + b] = wt[0] + wt[1] + wt[2] + wt[3];
}

__global__ __launch_bounds__(256) void scan_p2(int* __restrict__ part) {
  int w = threadIdx.x >> 6, l = threadIdx.x & 63;
  int v = (l < SCAN_NB) ? part[w * SCAN_NB + l] : 0;
  int x = v;
#pragma unroll
  for (int d = 1; d < 64; d <<= 1) {
    int y = __shfl_up(x, d, 64);
    if (l >= d) x += y;
  }
  if (l < SCAN_NB) part[w * SCAN_NB + l] = x - v;
}

__global__ __launch_bounds__(256) void scan_p3(const int* __restrict__ cnt,
                                               const int* __restrict__ part,
                                               int* __restrict__ rowptr) {
  int arr = blockIdx.y, b = blockIdx.x;
  const int* c = cnt + (size_t)arr * NN;
  int* rp = rowptr + (size_t)arr * (NN + 1);
  int tid = threadIdx.x;
  int gi = b * SCAN_TILE + tid * 8;
  int vals[8];
#pragma unroll
  for (int t = 0; t < 8; t++) vals[t] = (gi + t < NN) ? c[gi + t] : 0;
  int tsum = 0;
#pragma unroll
  for (int t = 0; t < 8; t++) tsum += vals[t];
  int lane = tid & 63, wid = tid >> 6;
  int x = tsum;
#pragma unroll
  for (int d = 1; d < 64; d <<= 1) {
    int y = __shfl_up(x, d, 64);
    if (lane >= d) x += y;
  }
  __shared__ int wt[4];
  if (lane == 63) wt[wid] = x;
  __syncthreads();
  int wadd = 0;
  for (int w = 0; w < wid; w++) wadd += wt[w];
  int running = part[arr * SCAN_NB + b] + wadd + x - tsum;
#pragma unroll
  for (int t = 0; t < 8; t++) {
    if (gi + t < NN) rp[gi + t] = running;
    running += vals[t];
  }
  if (b == SCAN_NB - 1 && tid == 255) rp[NN] = running;
}

// ---------------- atomic-free packed scatter (8-deep ILP) ----------------
// slot = rp[id] + pos (rp is 200KB, L2-resident). Stores are fire-and-forget.
__global__ __launch_bounds__(256) void scat2(const int* __restrict__ c2,
                                             const int* __restrict__ u2,
                                             const float* __restrict__ a2,
                                             const int* __restrict__ posc,
                                             const int* __restrict__ posu,
                                             const int* __restrict__ rpc,
                                             const int* __restrict__ rpu,
                                             uint2* __restrict__ payc,
                                             uint2* __restrict__ payu, int n) {
  int base = blockIdx.x * 2048 + threadIdx.x;
  if (base + 1792 < n) {
    int c[8], u[8]; float a[8]; int pc[8], pu[8];
#pragma unroll
    for (int k = 0; k < 8; k++) {
      int e = base + k * 256;
      c[k] = c2[e]; u[k] = u2[e]; a[k] = a2[e]; pc[k] = posc[e]; pu[k] = posu[e];
    }
    int p[8], q[8];
#pragma unroll
    for (int k = 0; k < 8; k++) { p[k] = rpc[c[k]] + pc[k]; q[k] = rpu[u[k]] + pu[k]; }
#pragma unroll
    for (int k = 0; k < 8; k++) {
      uint2 t; t.x = (unsigned)u[k]; t.y = __float_as_uint(a[k]);
      payc[p[k]] = t;
    }
#pragma unroll
    for (int k = 0; k < 8; k++) {
      uint2 t; t.x = (unsigned)p[k]; t.y = (unsigned)c[k];
      payu[q[k]] = t;
    }
  } else {
#pragma unroll
    for (int k = 0; k < 8; k++) {
      int e = base + k * 256;
      if (e < n) {
        int cc = c2[e], uu = u2[e];
        int pp = rpc[cc] + posc[e];
        int qq = rpu[uu] + posu[e];
        uint2 t; t.x = (unsigned)uu; t.y = __float_as_uint(a2[e]);
        payc[pp] = t;
        uint2 t2; t2.x = (unsigned)pp; t2.y = (unsigned)cc;
        payu[qq] = t2;
      }
    }
  }
}

// payc3[p] = {(u<<16)|v, ta}; payuv[q] = {(other<<16)|c, sp}; node ids < 2^16
__global__ __launch_bounds__(256) void scat_t3(const int* __restrict__ c3,
                                               const int* __restrict__ u3,
                                               const int* __restrict__ v3,
                                               const int* __restrict__ ttau,
                                               const int* __restrict__ posc,
                                               const int* __restrict__ posu,
                                               const int* __restrict__ posv,
                                               const int* __restrict__ rpc,
                                               const int* __restrict__ rpuv,
                                               uint2* __restrict__ payc,
                                               uint2* __restrict__ payuv, int n) {
  int base = blockIdx.x * 2048 + threadIdx.x;
  if (base + 1792 < n) {
    int c[8], u[8], v[8], ta[8], p[8], q1[8], q2[8];
#pragma unroll
    for (int k = 0; k < 8; k++) {
      int t = base + k * 256;
      c[k] = c3[t]; u[k] = u3[t]; v[k] = v3[t]; ta[k] = ttau[t] & 1;
    }
#pragma unroll
    for (int k = 0; k < 8; k++) {
      int t = base + k * 256;
      p[k] = rpc[c[k]] + posc[t];
      q1[k] = rpuv[u[k]] + posu[t];
      q2[k] = rpuv[v[k]] + posv[t];
    }
#pragma unroll
    for (int k = 0; k < 8; k++) {
      uint2 a; a.x = ((unsigned)u[k] << 16) | (unsigned)v[k]; a.y = (unsigned)ta[k];
      payc[p[k]] = a;
    }
#pragma unroll
    for (int k = 0; k < 8; k++) {
      unsigned sp = ((unsigned)p[k] << 1) | (unsigned)ta[k];
      uint2 b1; b1.x = ((unsigned)v[k] << 16) | (unsigned)c[k]; b1.y = sp;
      payuv[q1[k]] = b1;
      uint2 b2; b2.x = ((unsigned)u[k] << 16) | (unsigned)c[k]; b2.y = sp;
      payuv[q2[k]] = b2;
    }
  } else {
#pragma unroll
    for (int k = 0; k < 8; k++) {
      int t = base + k * 256;
      if (t < n) {
        int c = c3[t], u = u3[t], v = v3[t], ta = ttau[t] & 1;
        int p = rpc[c] + posc[t];
        int q1 = rpuv[u] + posu[t];
        int q2 = rpuv[v] + posv[t];
        unsigned sp = ((unsigned)p << 1) | (unsigned)ta;
        uint2 a; a.x = ((unsigned)u << 16) | (unsigned)v; a.y = (unsigned)ta;
        payc[p] = a;
        uint2 b1; b1.x = ((unsigned)v << 16) | (unsigned)c; b1.y = sp;
        payuv[q1] = b1;
        uint2 b2; b2.x = ((unsigned)u << 16) | (unsigned)c; b2.y = sp;
        payuv[q2] = b2;
      }
    }
  }
}

// ---------------- fused e2 fwd + dQ2 body ----------------
__device__ void e2_body(int bx, const unsigned* __restrict__ QK,
                        const float* __restrict__ P,
                        const uint2* __restrict__ pay,
                        const int* __restrict__ rp,
                        float* __restrict__ s2c,
                        float* __restrict__ L2,
                        unsigned* __restrict__ dAll) {
  int row = bx * 4 + (threadIdx.x >> 6);
  int l = threadIdx.x & 63, g = l >> 4, j = l & 15;
  float b2s = P[0] * INV_SQRT_D, cw2 = P[3];
  float q[8];
  unp8(*(const uint4*)(QK + (size_t)row * UU + j * 4), q);
  int s = rp[row], e = rp[row + 1];
  float m = -3.0e38f, z = 0.f;
  float acc[8] = {0.f, 0.f, 0.f, 0.f, 0.f, 0.f, 0.f, 0.f};
  int i0 = s + g;
  uint4 kA = {0, 0, 0, 0}, kB = {0, 0, 0, 0};
  float aA = 0.f, aB = 0.f;
  if (i0 < e) {
    uint2 w = pay[i0]; aA = __uint_as_float(w.y);
    kA = *(const uint4*)(QK + (size_t)w.x * UU + 64 + j * 4);
  }
  if (i0 + 4 < e) {
    uint2 w = pay[i0 + 4]; aB = __uint_as_float(w.y);
    kB = *(const uint4*)(QK + (size_t)w.x * UU + 64 + j * 4);
  }
  for (int i = i0; i < e; i += 4) {
    uint4 kC = {0, 0, 0, 0}; float aC = 0.f;
    if (i + 8 < e) {
      uint2 w = pay[i + 8]; aC = __uint_as_float(w.y);
      kC = *(const uint4*)(QK + (size_t)w.x * UU + 64 + j * 4);
    }
    float k[8]; unp8(kA, k);
    float d = 0.f;
#pragma unroll
    for (int t = 0; t < 8; t++) d = fmaf(q[t], k[t], d);
    d = redsum16(d);
    float sv = b2s * d + aA;
    if (j == 0) s2c[i] = sv;
    if (sv <= m) {
      float p = __expf(sv - m);
      z += p;
#pragma unroll
      for (int t = 0; t < 8; t++) acc[t] = fmaf(p, k[t], acc[t]);
    } else {
      float r = __expf(m - sv);
      z = fmaf(z, r, 1.f);
#pragma unroll
      for (int t = 0; t < 8; t++) acc[t] = fmaf(acc[t], r, k[t]);
      m = sv;
    }
    kA = kB; aA = aB; kB = kC; aB = aC;
  }
  float mx = fmaxf(m, __shfl_xor(m, 16, 64));
  mx = fmaxf(mx, __shfl_xor(mx, 32, 64));
  float r = (z > 0.f) ? __expf(m - mx) : 0.f;
  float zz = z * r;
  zz += __shfl_xor(zz, 16, 64);
  zz += __shfl_xor(zz, 32, 64);
#pragma unroll
  for (int t = 0; t < 8; t++) {
    float v = acc[t] * r;
    v += __shfl_xor(v, 16, 64);
    v += __shfl_xor(v, 32, 64);
    acc[t] = v;
  }
  if (l == 0) L2[row] = (zz > 0.f) ? (mx + __logf(zz)) : 0.f;
  if (g == 0) {
    float coef = (zz > 0.f) ? cw2 / zz : 0.f;
    float o[8];
#pragma unroll
    for (int t = 0; t < 8; t++) o[t] = coef * acc[t];
    *(uint4*)(dAll + (size_t)row * UU + 0 + j * 4) = pk8(o);
  }
}

// ---------------- fused t3 fwd + dQ3 body ----------------
__device__ void t3_body(int bx, const unsigned* __restrict__ QK,
                        const float* __restrict__ Tt,
                        const float* __restrict__ P,
                        const uint2* __restrict__ pay,
                        const int* __restrict__ rp,
                        float* __restrict__ s3c,
                        float* __restrict__ L3,
                        unsigned* __restrict__ dAll) {
  __shared__ float sT[2 * DD];
  int tid = threadIdx.x;
  sT[tid] = Tt[tid];
  __syncthreads();
  int row = bx * 4 + (tid >> 6);
  int l = tid & 63, g = l >> 4, j = l & 15;
  float b3s = P[1] * INV_D, cw3 = P[4];
  float q[8];
  unp8(*(const uint4*)(QK + (size_t)row * UU + 128 + j * 4), q);
  int s = rp[row], e = rp[row + 1];
  float m = -3.0e38f, z = 0.f;
  float acc[8] = {0.f, 0.f, 0.f, 0.f, 0.f, 0.f, 0.f, 0.f};
  int i0 = s + g;
  uint4 kuA = {0, 0, 0, 0}, kvA = {0, 0, 0, 0};
  uint4 kuB = {0, 0, 0, 0}, kvB = {0, 0, 0, 0};
  int taA = 0, taB = 0;
  if (i0 < e) {
    uint2 w = pay[i0]; int u = w.x >> 16, v = w.x & 0xffff; taA = (int)w.y;
    kuA = *(const uint4*)(QK + (size_t)u * UU + 192 + j * 4);
    kvA = *(const uint4*)(QK + (size_t)v * UU + 192 + j * 4);
  }
  if (i0 + 4 < e) {
    uint2 w = pay[i0 + 4]; int u = w.x >> 16, v = w.x & 0xffff; taB = (int)w.y;
    kuB = *(const uint4*)(QK + (size_t)u * UU + 192 + j * 4);
    kvB = *(const uint4*)(QK + (size_t)v * UU + 192 + j * 4);
  }
  for (int i = i0; i < e; i += 4) {
    uint4 kuC = {0, 0, 0, 0}, kvC = {0, 0, 0, 0}; int taC = 0;
    if (i + 8 < e) {
      uint2 w = pay[i + 8]; int u = w.x >> 16, v = w.x & 0xffff; taC = (int)w.y;
      kuC = *(const uint4*)(QK + (size_t)u * UU + 192 + j * 4);
      kvC = *(const uint4*)(QK + (size_t)v * UU + 192 + j * 4);
    }
    float ku[8], kv[8]; unp8(kuA, ku); unp8(kvA, kv);
    const float* tv = &sT[taA * DD + j * 8];
    float et[8], d = 0.f;
#pragma unroll
    for (int t = 0; t < 8; t++) { et[t] = ku[t] * kv[t] * tv[t]; d = fmaf(q[t], et[t], d); }
    d = redsum16(d);
    float sv = b3s * d;
    if (j == 0) s3c[i] = sv;
    if (sv <= m) {
      float p = __expf(sv - m);
      z += p;
#pragma unroll
      for (int t = 0; t < 8; t++) acc[t] = fmaf(p, et[t], acc[t]);
    } else {
      float r = __expf(m - sv);
      z = fmaf(z, r, 1.f);
#pragma unroll
      for (int t = 0; t < 8; t++) acc[t] = fmaf(acc[t], r, et[t]);
      m = sv;
    }
    kuA = kuB; kvA = kvB; taA = taB;
    kuB = kuC; kvB = kvC; taB = taC;
  }
  float mx = fmaxf(m, __shfl_xor(m, 16, 64));
  mx = fmaxf(mx, __shfl_xor(mx, 32, 64));
  float r = (z > 0.f) ? __expf(m - mx) : 0.f;
  float zz = z * r;
  zz += __shfl_xor(zz, 16, 64);
  zz += __shfl_xor(zz, 32, 64);
#pragma unroll
  for (int t = 0; t < 8; t++) {
    float v = acc[t] * r;
    v += __shfl_xor(v, 16, 64);
    v += __shfl_xor(v, 32, 64);
    acc[t] = v;
  }
  if (l == 0) L3[row] = (zz > 0.f) ? (mx + __logf(zz)) : 0.f;
  if (g == 0) {
    float coef = (zz > 0.f) ? cw3 / zz : 0.f;
    float o[8];
#pragma unroll
    for (int t = 0; t < 8; t++) o[t] = coef * acc[t];
    *(uint4*)(dAll + (size_t)row * UU + 128 + j * 4) = pk8(o);
  }
}

// ---------------- memory-bank energy body ----------------
__device__ void em_body(int bx, const unsigned* __restrict__ QK,
                        const float* __restrict__ Km,
                        const float* __restrict__ P,
                        unsigned* __restrict__ dAll,
                        float* __restrict__ Lm) {
  __shared__ float sKm[KM * DD];
  int tid = threadIdx.x;
  for (int i = tid; i < KM * DD; i += 256) sKm[i] = Km[i];
  __syncthreads();
  int row = bx * 4 + (tid >> 6);
  int l = tid & 63, g = l >> 4, j = l & 15;
  float bms = P[2] * INV_SQRT_D, cwm = P[5];
  float q[8];
  unp8(*(const uint4*)(QK + (size_t)row * UU + 256 + j * 4), q);
  float dk[8];
#pragma unroll
  for (int kk = 0; kk < 8; kk++) {
    int k = g * 8 + kk;
    const float* kr = &sKm[k * DD + j * 8];
    float d = 0.f;
#pragma unroll
    for (int t = 0; t < 8; t++) d = fmaf(q[t], kr[t], d);
    dk[kk] = redsum16(d) * bms;
  }
  float m = dk[0];
#pragma unroll
  for (int kk = 1; kk < 8; kk++) m = fmaxf(m, dk[kk]);
  float mx = fmaxf(m, __shfl_xor(m, 16, 64));
  mx = fmaxf(mx, __shfl_xor(mx, 32, 64));
  float p[8], z = 0.f;
#pragma unroll
  for (int kk = 0; kk < 8; kk++) { p[kk] = __expf(dk[kk] - mx); z += p[kk]; }
  float zz = z;
  zz += __shfl_xor(zz, 16, 64);
  zz += __shfl_xor(zz, 32, 64);
  if (l == 0) Lm[row] = mx + __logf(zz);
  float coef = cwm / zz;
  float acc[8] = {0.f, 0.f, 0.f, 0.f, 0.f, 0.f, 0.f, 0.f};
#pragma unroll
  for (int kk = 0; kk < 8; kk++) {
    int k = g * 8 + kk;
    const float* kr = &sKm[k * DD + j * 8];
    float pc_ = p[kk] * coef;
#pragma unroll
    for (int t = 0; t < 8; t++) acc[t] = fmaf(pc_, kr[t], acc[t]);
  }
#pragma unroll
  for (int t = 0; t < 8; t++) {
    float v = acc[t];
    v += __shfl_xor(v, 16, 64);
    v += __shfl_xor(v, 32, 64);
    acc[t] = v;
  }
  if (g == 0) *(uint4*)(dAll + (size_t)row * UU + 256 + j * 4) = pk8(acc);
}

// fused phase2: e2_fused + t3_fused + em_row (mutually independent)
__global__ __launch_bounds__(256) void phase2_k(const unsigned* __restrict__ QK,
                                                const float* __restrict__ Tt,
                                                const float* __restrict__ Km,
                                                const float* __restrict__ P,
                                                const uint2* __restrict__ payc2,
                                                const int* __restrict__ rp_c2,
                                                const uint2* __restrict__ payc3,
                                                const int* __restrict__ rp_c3,
                                                float* __restrict__ s2c,
                                                float* __restrict__ L2,
                                                float* __restrict__ s3c,
                                                float* __restrict__ L3,
                                                float* __restrict__ Lm,
                                                unsigned* __restrict__ dAll) {
  int bx = blockIdx.x;
  if (bx < ROWB) e2_body(bx, QK, P, payc2, rp_c2, s2c, L2, dAll);
  else if (bx < 2 * ROWB) t3_body(bx - ROWB, QK, Tt, P, payc3, rp_c3, s3c, L3, dAll);
  else em_body(bx - 2 * ROWB, QK, Km, P, dAll, Lm);
}

// ---------------- dK2 gather body ----------------
__device__ void dk2_body(int bx, const unsigned* __restrict__ QK,
                         const float* __restrict__ s2c,
                         const float* __restrict__ L2,
                         const float* __restrict__ P,
                         const uint2* __restrict__ pay,
                         const int* __restrict__ rp,
                         unsigned* __restrict__ dAll) {
  int row = bx * 4 + (threadIdx.x >> 6);
  int l = threadIdx.x & 63, g = l >> 4, j = l & 15;
  float cw2 = P[3];
  int s = rp[row], e = rp[row + 1];
  float acc[8] = {0.f, 0.f, 0.f, 0.f, 0.f, 0.f, 0.f, 0.f};
  int i0 = s + g;
  uint4 qA = {0, 0, 0, 0}, qB = {0, 0, 0, 0};
  float scA = 0.f, lcA = 0.f, scB = 0.f, lcB = 0.f;
  if (i0 < e) {
    uint2 w = pay[i0]; scA = s2c[w.x]; lcA = L2[w.y];
    qA = *(const uint4*)(QK + (size_t)w.y * UU + 0 + j * 4);
  }
  if (i0 + 4 < e) {
    uint2 w = pay[i0 + 4]; scB = s2c[w.x]; lcB = L2[w.y];
    qB = *(const uint4*)(QK + (size_t)w.y * UU + 0 + j * 4);
  }
  for (int i = i0; i < e; i += 4) {
    uint4 qC = {0, 0, 0, 0}; float scC = 0.f, lcC = 0.f;
    if (i + 8 < e) {
      uint2 w = pay[i + 8]; scC = s2c[w.x]; lcC = L2[w.y];
      qC = *(const uint4*)(QK + (size_t)w.y * UU + 0 + j * 4);
    }
    float w = cw2 * __expf(scA - lcA);
    float qv[8]; unp8(qA, qv);
#pragma unroll
    for (int t = 0; t < 8; t++) acc[t] = fmaf(w, qv[t], acc[t]);
    qA = qB; scA = scB; lcA = lcB;
    qB = qC; scB = scC; lcB = lcC;
  }
#pragma unroll
  for (int t = 0; t < 8; t++) {
    float v = acc[t];
    v += __shfl_xor(v, 16, 64);
    v += __shfl_xor(v, 32, 64);
    acc[t] = v;
  }
  if (g == 0) *(uint4*)(dAll + (size_t)row * UU + 64 + j * 4) = pk8(acc);
}

// ---------------- dK3 gather body ----------------
__device__ void dk3_body(int bx, const unsigned* __restrict__ QK,
                         const float* __restrict__ Tt,
                         const float* __restrict__ s3c,
                         const float* __restrict__ L3,
                         const float* __restrict__ P,
                         const uint2* __restrict__ pay,
                         const int* __restrict__ rp,
                         unsigned* __restrict__ dAll) {
  __shared__ float sT[2 * DD];
  int tid = threadIdx.x;
  sT[tid] = Tt[tid];
  __syncthreads();
  int row = bx * 4 + (tid >> 6);
  int l = tid & 63, g = l >> 4, j = l & 15;
  float cw3 = P[4];
  int s = rp[row], e = rp[row + 1];
  float acc[8] = {0.f, 0.f, 0.f, 0.f, 0.f, 0.f, 0.f, 0.f};
  int i0 = s + g;
  uint4 qA = {0, 0, 0, 0}, kA = {0, 0, 0, 0};
  uint4 qB = {0, 0, 0, 0}, kB = {0, 0, 0, 0};
  int taA = 0, taB = 0;
  float scA = 0.f, lcA = 0.f, scB = 0.f, lcB = 0.f;
  if (i0 < e) {
    uint2 w = pay[i0]; int o = w.x >> 16, c = w.x & 0xffff; unsigned sp = w.y;
    taA = (int)(sp & 1); scA = s3c[sp >> 1]; lcA = L3[c];
    qA = *(const uint4*)(QK + (size_t)c * UU + 128 + j * 4);
    kA = *(const uint4*)(QK + (size_t)o * UU + 192 + j * 4);
  }
  if (i0 + 4 < e) {
    uint2 w = pay[i0 + 4]; int o = w.x >> 16, c = w.x & 0xffff; unsigned sp = w.y;
    taB = (int)(sp & 1); scB = s3c[sp >> 1]; lcB = L3[c];
    qB = *(const uint4*)(QK + (size_t)c * UU + 128 + j * 4);
    kB = *(const uint4*)(QK + (size_t)o * UU + 192 + j * 4);
  }
  for (int i = i0; i < e; i += 4) {
    uint4 qC = {0, 0, 0, 0}, kC = {0, 0, 0, 0}; int taC = 0;
    float scC = 0.f, lcC = 0.f;
    if (i + 8 < e) {
      uint2 w = pay[i + 8]; int o = w.x >> 16, c = w.x & 0xffff; unsigned sp = w.y;
      taC = (int)(sp & 1); scC = s3c[sp >> 1]; lcC = L3[c];
      qC = *(const uint4*)(QK + (size_t)c * UU + 128 + j * 4);
      kC = *(const uint4*)(QK + (size_t)o * UU + 192 + j * 4);
    }
    float w = cw3 * __expf(scA - lcA);
    float qv[8], ko[8]; unp8(qA, qv); unp8(kA, ko);
    const float* tv = &sT[taA * DD + j * 8];
#pragma unroll
    for (int t = 0; t < 8; t++) acc[t] = fmaf(w * tv[t], qv[t] * ko[t], acc[t]);
    qA = qB; kA = kB; taA = taB; scA = scB; lcA = lcB;
    qB = qC; kB = kC; taB = taC; scB = scC; lcB = lcC;
  }
#pragma unroll
  for (int t = 0; t < 8; t++) {
    float v = acc[t];
    v += __shfl_xor(v, 16, 64);
    v += __shfl_xor(v, 32, 64);
    acc[t] = v;
  }
  if (g == 0) *(uint4*)(dAll + (size_t)row * UU + 192 + j * 4) = pk8(acc);
}

// fused phase3: dk2_gather + dk3_gather (mutually independent)
__global__ __launch_bounds__(256) void phase3_k(const unsigned* __restrict__ QK,
                                                const float* __restrict__ Tt,
                                                const float* __restrict__ P,
                                                const float* __restrict__ s2c,
                                                const float* __restrict__ L2,
                                                const uint2* __restrict__ payu2,
                                                const int* __restrict__ rp_u2,
                                                const float* __restrict__ s3c,
                                                const float* __restrict__ L3,
                                                const uint2* __restrict__ payuv,
                                                const int* __restrict__ rp_uv,
                                                unsigned* __restrict__ dAll) {
  int bx = blockIdx.x;
  if (bx < ROWB) dk2_body(bx, QK, s2c, L2, P, payu2, rp_u2, dAll);
  else dk3_body(bx - ROWB, QK, Tt, s3c, L3, P, payuv, rp_uv, dAll);
}

// ---------------- LN backward + clips + update ----------------
__global__ __launch_bounds__(256) void ln_bwd(const float* __restrict__ X,
                                              const unsigned* __restrict__ dG,
                                              const float* __restrict__ gamma,
                                              const float* __restrict__ meanv,
                                              const float* __restrict__ rstdv,
                                              float* __restrict__ out) {
  int row = blockIdx.x * 4 + (threadIdx.x >> 6);
  if (row >= NN) return;
  int l = threadIdx.x & 63;
  float mu = meanv[row], rstd = rstdv[row];
  float2 x2 = *(const float2*)(X + row * DD + 2 * l);
  unsigned gw = dG[(size_t)row * 64 + l];
  float2 ga = *(const float2*)(gamma + 2 * l);
  float xh0 = (x2.x - mu) * rstd, xh1 = (x2.y - mu) * rstd;
  float dh0 = blo(gw) * ga.x, dh1 = bhi(gw) * ga.y;
  float sa = wredsum(dh0 + dh1) * (1.f / DD);
  float sb = wredsum(dh0 * xh0 + dh1 * xh1) * (1.f / DD);
  float dx0 = rstd * (dh0 - sa - xh0 * sb);
  float dx1 = rstd * (dh1 - sa - xh1 * sb);
  float gn = fmaxf(sqrtf(wredsum(dx0 * dx0 + dx1 * dx1)), 1e-6f);
  float sc = fminf(1.f / gn, 1.f);
  dx0 *= sc; dx1 *= sc;
  float xn0 = x2.x - 0.1f * 0.9999f * dx0;
  float xn1 = x2.y - 0.1f * 0.9999f * dx1;
  float sn = fmaxf(sqrtf(wredsum(xn0 * xn0 + xn1 * xn1)), 1e-6f);
  float sc2 = fminf(10.f / sn, 1.f);
  float2 o; o.x = xn0 * sc2; o.y = xn1 * sc2;
  *(float2*)(out + row * DD + 2 * l) = o;
}

// ---------------- final energy scalar (parallel, atomic) ----------------
__global__ __launch_bounds__(256) void eval_write(const float* __restrict__ L2,
                                                  const float* __restrict__ L3,
                                                  const float* __restrict__ Lm,
                                                  const float* __restrict__ P,
                                                  float* __restrict__ out) {
  int i = blockIdx.x * 256 + threadIdx.x;
  float a2 = 0.f, a3 = 0.f, am = 0.f;
  if (i < NN) { a2 = L2[i]; a3 = L3[i]; am = Lm[i]; }
  a2 = wredsum(a2); a3 = wredsum(a3); am = wredsum(am);
  __shared__ float r2[4], r3[4], rm[4];
  int wv = threadIdx.x >> 6, l = threadIdx.x & 63;
  if (l == 0) { r2[wv] = a2; r3[wv] = a3; rm[wv] = am; }
  __syncthreads();
  if (threadIdx.x == 0) {
    float S2 = r2[0] + r2[1] + r2[2] + r2[3];
    float S3 = r3[0] + r3[1] + r3[2] + r3[3];
    float Sm = rm[0] + rm[1] + rm[2] + rm[3];
    atomicAdd(out, P[6] * S2 + P[7] * S3 + P[8] * Sm);
  }
}

extern "C" void kernel_launch(void* const* d_in, const int* in_sizes, int n_in,
                              void* d_out, int out_size, void* d_ws, size_t ws_size,
                              hipStream_t stream) {
  (void)in_sizes; (void)n_in; (void)out_size;
  const float* X = (const float*)d_in[0];
  const float* EA = (const float*)d_in[1];
  const float* ln_g = (const float*)d_in[2];
  const float* ln_b = (const float*)d_in[3];
  const float* W_Q2 = (const float*)d_in[4];
  const float* W_K2 = (const float*)d_in[5];
  const float* W_Q3 = (const float*)d_in[6];
  const float* W_K3 = (const float*)d_in[7];
  const float* T_tau = (const float*)d_in[8];
  const float* W_Qm = (const float*)d_in[9];
  const float* W_Km = (const float*)d_in[10];
  const float* B_mem = (const float*)d_in[11];
  const float* We1 = (const float*)d_in[12];
  const float* be1 = (const float*)d_in[13];
  const float* We2 = (const float*)d_in[14];
  const float* be2 = (const float*)d_in[15];
  const float* l2s = (const float*)d_in[16];
  const float* l3s = (const float*)d_in[17];
  const float* lms = (const float*)d_in[18];
  const float* b2s = (const float*)d_in[19];
  const float* b3s = (const float*)d_in[20];
  const float* bms = (const float*)d_in[21];
  const int* c2 = (const int*)d_in[22];
  const int* u2 = (const int*)d_in[23];
  const int* c3 = (const int*)d_in[24];
  const int* u3 = (const int*)d_in[25];
  const int* v3 = (const int*)d_in[26];
  const int* ttau = (const int*)d_in[27];
  float* out = (float*)d_out;

  float* ws = (float*)d_ws;
  size_t off = 0;
  auto alloc = [&](size_t n) { float* p = ws + off; off += n; return p; };
  const size_t ND = (size_t)NN * DD;
  unsigned* Gb = (unsigned*)alloc(ND / 2);
  unsigned* QKall = (unsigned*)alloc((size_t)NN * UU);
  unsigned* dAll = (unsigned*)alloc((size_t)NN * UU);
  unsigned* dG = (unsigned*)alloc(ND / 2);
  ushort_t* Wt5 = (ushort_t*)alloc(640 * 128 / 2);
  ushort_t* Wcat = (ushort_t*)alloc(640 * 128 / 2);
  float* Km = alloc((size_t)KM * DD);
  float* a2 = alloc(EE);
  float* s2c = alloc(EE);
  float* s3c = alloc(TT);
  float* meanv = alloc(NN);
  float* rstdv = alloc(NN);
  float* L2 = alloc(NN);
  float* L3 = alloc(NN);
  float* Lm = alloc(NN);
  float* Pparams = alloc(16);
  int* cnt = (int*)alloc(4 * (size_t)NN);
  int* rowptr = (int*)alloc(4 * (size_t)(NN + 1));
  int* spart = (int*)alloc(4 * SCAN_NB);
  int* pos_c2 = (int*)alloc(EE);
  int* pos_u2 = (int*)alloc(EE);
  int* pos_c3 = (int*)alloc(TT);
  int* pos_u3 = (int*)alloc(TT);
  int* pos_v3 = (int*)alloc(TT);
  uint2* payc2 = (uint2*)alloc(2 * (size_t)EE);
  uint2* payu2 = (uint2*)alloc(2 * (size_t)EE);
  uint2* payc3 = (uint2*)alloc(2 * (size_t)TT);
  uint2* payuv = (uint2*)alloc(4 * (size_t)TT);
  if (off * sizeof(float) > ws_size) return;

  int* cnt_c2 = cnt, *cnt_u2 = cnt + NN, *cnt_c3 = cnt + 2 * NN, *cnt_uv = cnt + 3 * NN;
  int* rp_c2 = rowptr, *rp_u2 = rowptr + (NN + 1), *rp_c3 = rowptr + 2 * (NN + 1), *rp_uv = rowptr + 3 * (NN + 1);

  hipMemsetAsync(cnt, 0, 4ull * NN * sizeof(int), stream);
  hipMemsetAsync(out + ND, 0, sizeof(float), stream);

  params_k<<<1, 64, 0, stream>>>(l2s, l3s, lms, b2s, b3s, bms, Pparams);

  int rowB = ROWB;

  ln_fwd<<<rowB, 256, 0, stream>>>(X, ln_g, ln_b, Gb, meanv, rstdv);
  w_conv<<<320, 256, 0, stream>>>(W_Q2, W_K2, W_Q3, W_K3, W_Qm, Wt5, Wcat);
  gemm_km<<<1, 256, 0, stream>>>(B_mem, W_Km, Km, KM);
  fwd_k<<<MB * 10 + EDGE_BLKS, 256, 0, stream>>>((const ushort_t*)Gb, Wt5, (ushort_t*)QKall,
                                                 EA, We1, be1, We2, be2, a2);

  hist2<<<(EE + 2047) / 2048, 256, 0, stream>>>(c2, u2, cnt_c2, cnt_u2, pos_c2, pos_u2, EE);
  hist_t3<<<(TT + 2047) / 2048, 256, 0, stream>>>(c3, u3, v3, cnt_c3, cnt_uv,
                                                  pos_c3, pos_u3, pos_v3, TT);
  scan_p1<<<dim3(SCAN_NB, 4), 256, 0, stream>>>(cnt, spart);
  scan_p2<<<1, 256, 0, stream>>>(spart);
  scan_p3<<<dim3(SCAN_NB, 4), 256, 0, stream>>>(cnt, spart, rowptr);
  scat2<<<(EE + 2047) / 2048, 256, 0, stream>>>(c2, u2, a2, pos_c2, pos_u2,
                                                rp_c2, rp_u2, payc2, payu2, EE);
  scat_t3<<<(TT + 2047) / 2048, 256, 0, stream>>>(c3, u3, v3, ttau,
                                                  pos_c3, pos_u3, pos_v3,
                                                  rp_c3, rp_uv, payc3, payuv, TT);

  phase2_k<<<3 * ROWB, 256, 0, stream>>>(QKall, T_tau, Km, Pparams,
                                         payc2, rp_c2, payc3, rp_c3,
                                         s2c, L2, s3c, L3, Lm, dAll);
  phase3_k<<<2 * ROWB, 256, 0, stream>>>(QKall, T_tau, Pparams,
                                         s2c, L2, payu2, rp_u2,
                                         s3c, L3, payuv, rp_uv, dAll);

  mfma_bwd<<<dim3(MB, 2), 256, 0, stream>>>((const ushort_t*)dAll, Wcat, dG, NN);

  ln_bwd<<<rowB, 256, 0, stream>>>(X, dG, ln_g, meanv, rstdv, out);
  eval_write<<<(NN + 255) / 256, 256, 0, stream>>>(L2, L3, Lm, Pparams, out + ND);
}

// Round 6
// 766.948 us; speedup vs baseline: 1.2379x; 1.0017x over previous
//
#include <hip/hip_runtime.h>

#define NN 50000
#define DD 128
#define EE 800000
#define TT 400000
#define KM 32
#define UU 320  // uints per 640-col bf16 row
#define ROWB 12500           // NN/4
#define MB 782               // ceil(NN/64)
#define EDGE_BLKS 3125       // EE/256
#define SCAN_TILE 2048
#define SCAN_NB ((NN + SCAN_TILE - 1) / SCAN_TILE)  // 25

static constexpr float INV_SQRT_D = 0.08838834764831845f; // 1/sqrt(128)
static constexpr float INV_D = 1.f / 128.f;

typedef __attribute__((ext_vector_type(8))) short bf16x8;
typedef __attribute__((ext_vector_type(4))) float f32x4;
typedef unsigned short ushort_t;

__device__ __forceinline__ float softplus_f(float x) {
  return (x > 20.f) ? x : log1pf(__expf(x));
}

// exact rewrite of tanh-gelu: 0.5x(1+tanh(z)) == x * sigmoid(2z)
__device__ __forceinline__ float gelu_fast(float x) {
  float p = fmaf(0.044715f * x * x, x, x);
  float e = __expf(-1.5957691216057308f * p);
  return x * __builtin_amdgcn_rcpf(1.f + e);
}

__device__ __forceinline__ float wredsum(float v) {
#pragma unroll
  for (int m = 32; m; m >>= 1) v += __shfl_xor(v, m, 64);
  return v;
}

__device__ __forceinline__ float redsum16(float v) {
#pragma unroll
  for (int m = 1; m < 16; m <<= 1) v += __shfl_xor(v, m, 64);
  return v;
}

__device__ __forceinline__ float blo(unsigned w) { return __uint_as_float(w << 16); }
__device__ __forceinline__ float bhi(unsigned w) { return __uint_as_float(w & 0xffff0000u); }
__device__ __forceinline__ unsigned pack_bf16(float a, float b) {
  unsigned ua = __float_as_uint(a); ua += 0x7fff + ((ua >> 16) & 1);
  unsigned ub = __float_as_uint(b); ub += 0x7fff + ((ub >> 16) & 1);
  return (ua >> 16) | (ub & 0xffff0000u);
}
__device__ __forceinline__ ushort_t bf16_1(float x) {
  unsigned u = __float_as_uint(x); u += 0x7fff + ((u >> 16) & 1);
  return (ushort_t)(u >> 16);
}
__device__ __forceinline__ void unp8(uint4 w, float* f) {
  f[0] = blo(w.x); f[1] = bhi(w.x); f[2] = blo(w.y); f[3] = bhi(w.y);
  f[4] = blo(w.z); f[5] = bhi(w.z); f[6] = blo(w.w); f[7] = bhi(w.w);
}
__device__ __forceinline__ uint4 pk8(const float* f) {
  uint4 r;
  r.x = pack_bf16(f[0], f[1]); r.y = pack_bf16(f[2], f[3]);
  r.z = pack_bf16(f[4], f[5]); r.w = pack_bf16(f[6], f[7]);
  return r;
}

// params: [0]=b2 [1]=b3 [2]=bm [3]=cw2 [4]=cw3 [5]=cwm [6]=-sp2/b2 [7]=-sp3/b3 [8]=-spm/bm
__global__ void params_k(const float* l2, const float* l3, const float* lm,
                         const float* b2, const float* b3, const float* bm,
                         float* __restrict__ P) {
  if (threadIdx.x != 0) return;
  float B2 = fminf(softplus_f(b2[0]), 5.f);
  float B3 = fminf(softplus_f(b3[0]), 5.f);
  float Bm = fminf(softplus_f(bm[0]), 5.f);
  float S2 = softplus_f(l2[0]);
  float S3 = softplus_f(l3[0]);
  float Sm = softplus_f(lm[0]);
  P[0] = B2; P[1] = B3; P[2] = Bm;
  P[3] = -S2 * INV_SQRT_D; P[4] = -S3 * INV_D; P[5] = -Sm * INV_SQRT_D;
  P[6] = -S2 / B2; P[7] = -S3 / B3; P[8] = -Sm / Bm;
}

// ---------------- LayerNorm forward -> bf16 G ----------------
__global__ __launch_bounds__(256) void ln_fwd(const float* __restrict__ X,
                                              const float* __restrict__ gamma,
                                              const float* __restrict__ beta,
                                              unsigned* __restrict__ Gb,
                                              float* __restrict__ meanv,
                                              float* __restrict__ rstdv) {
  int row = blockIdx.x * 4 + (threadIdx.x >> 6);
  if (row >= NN) return;
  int l = threadIdx.x & 63;
  float2 x2 = *(const float2*)(X + row * DD + 2 * l);
  float mu = wredsum(x2.x + x2.y) * (1.f / DD);
  float d0 = x2.x - mu, d1 = x2.y - mu;
  float var = wredsum(d0 * d0 + d1 * d1) * (1.f / DD);
  float rstd = rsqrtf(var + 1e-5f);
  float2 g2 = *(const float2*)(gamma + 2 * l);
  float2 b2 = *(const float2*)(beta + 2 * l);
  float o0 = d0 * rstd * g2.x + b2.x;
  float o1 = d1 * rstd * g2.y + b2.y;
  Gb[(size_t)row * 64 + l] = pack_bf16(o0, o1);
  if (l == 0) { meanv[row] = mu; rstdv[row] = rstd; }
}

// ---------------- weight conversion ----------------
__global__ __launch_bounds__(256) void w_conv(const float* W0, const float* W1, const float* W2,
                                              const float* W3, const float* W4,
                                              ushort_t* __restrict__ Wt,
                                              ushort_t* __restrict__ Wc) {
  int idx = blockIdx.x * 256 + threadIdx.x;
  if (idx >= 640 * 128) return;
  const float* Ws[5] = {W0, W1, W2, W3, W4};
  int n = idx >> 7, k = idx & 127;
  Wt[idx] = bf16_1(Ws[n >> 7][(size_t)k * 128 + (n & 127)]);
  int k2 = idx >> 7, n2 = idx & 127;
  Wc[(size_t)n2 * 640 + k2] = bf16_1(Ws[k2 >> 7][(size_t)n2 * 128 + (k2 & 127)]);
}

// ---------------- fwd MFMA GEMM body ----------------
__device__ void mfma_fwd_body(int bxr, int by, const ushort_t* __restrict__ Gb,
                              const ushort_t* __restrict__ Wt,
                              ushort_t* __restrict__ QK, int M) {
  __shared__ ushort_t sB[64][136];
  int tid = threadIdx.x;
  int nb = by * 64;
  for (int idx = tid; idx < 64 * 16; idx += 256) {
    int r = idx >> 4, c8 = idx & 15;
    *(bf16x8*)&sB[r][c8 * 8] = *(const bf16x8*)(Wt + (size_t)(nb + r) * 128 + c8 * 8);
  }
  __syncthreads();
  int w = tid >> 6, l = tid & 63, quad = l >> 4, j = l & 15;
  int row0 = bxr * 64 + w * 16;
  int arow = row0 + j; if (arow >= M) arow = M - 1;
  const bf16x8* ap = (const bf16x8*)(Gb + (size_t)arow * 128);
  f32x4 acc[4];
#pragma unroll
  for (int nt = 0; nt < 4; nt++) acc[nt] = (f32x4){0.f, 0.f, 0.f, 0.f};
#pragma unroll
  for (int kc = 0; kc < 4; kc++) {
    bf16x8 a = ap[kc * 4 + quad];
#pragma unroll
    for (int nt = 0; nt < 4; nt++) {
      bf16x8 b = *(const bf16x8*)&sB[nt * 16 + j][kc * 32 + quad * 8];
      acc[nt] = __builtin_amdgcn_mfma_f32_16x16x32_bf16(a, b, acc[nt], 0, 0, 0);
    }
  }
#pragma unroll
  for (int nt = 0; nt < 4; nt++)
#pragma unroll
    for (int r = 0; r < 4; r++) {
      int row = row0 + quad * 4 + r;
      if (row < M) QK[(size_t)row * 640 + nb + nt * 16 + j] = bf16_1(acc[nt][r]);
    }
}

// ---------------- edge MLP body ----------------
__device__ void edge_mlp_body(int bx, const float* __restrict__ EA,
                              const float* __restrict__ We1,
                              const float* __restrict__ be1,
                              const float* __restrict__ We2,
                              const float* __restrict__ be2,
                              float* __restrict__ a2) {
  __shared__ float sW1[16 * 128];
  __shared__ float sb1[128];
  __shared__ float sW2[128];
  int tid = threadIdx.x;
  for (int i = tid; i < 2048; i += 256) sW1[i] = We1[i];
  if (tid < 128) { sb1[tid] = be1[tid]; sW2[tid] = We2[tid]; }
  __syncthreads();
  int w = tid >> 6, l = tid & 63;
  int m = l & 15, q = l >> 4;
  union u8 { bf16x8 v; ushort_t s[8]; };
  u8 bf[8];
  float bb[8], ww[8];
#pragma unroll
  for (int nt = 0; nt < 8; nt++) {
    int n = nt * 16 + m;
#pragma unroll
    for (int j = 0; j < 8; j++) {
      int k = q * 8 + j;
      bf[nt].s[j] = (k < 16) ? bf16_1(sW1[k * 128 + n]) : (ushort_t)0;
    }
    bb[nt] = sb1[n];
    ww[nt] = sW2[n];
  }
  float be2v = be2[0];
  for (int batch = 0; batch < 4; batch++) {
    int e0 = bx * 256 + batch * 64 + w * 16;
    u8 af;
    if (q < 2) {
      const float* ep = EA + (size_t)(e0 + m) * 16 + q * 8;
      float4 v0 = *(const float4*)ep;
      float4 v1 = *(const float4*)(ep + 4);
      af.s[0] = bf16_1(v0.x); af.s[1] = bf16_1(v0.y);
      af.s[2] = bf16_1(v0.z); af.s[3] = bf16_1(v0.w);
      af.s[4] = bf16_1(v1.x); af.s[5] = bf16_1(v1.y);
      af.s[6] = bf16_1(v1.z); af.s[7] = bf16_1(v1.w);
    } else {
#pragma unroll
      for (int j = 0; j < 8; j++) af.s[j] = 0;
    }
    float s0 = 0.f, s1 = 0.f, s2 = 0.f, s3 = 0.f;
#pragma unroll
    for (int nt = 0; nt < 8; nt++) {
      float bias = bb[nt];
      f32x4 cin = (f32x4){bias, bias, bias, bias};
      f32x4 acc = __builtin_amdgcn_mfma_f32_16x16x32_bf16(af.v, bf[nt].v, cin, 0, 0, 0);
      float w2v = ww[nt];
      s0 = fmaf(gelu_fast(acc[0]), w2v, s0);
      s1 = fmaf(gelu_fast(acc[1]), w2v, s1);
      s2 = fmaf(gelu_fast(acc[2]), w2v, s2);
      s3 = fmaf(gelu_fast(acc[3]), w2v, s3);
    }
    s0 = redsum16(s0); s1 = redsum16(s1); s2 = redsum16(s2); s3 = redsum16(s3);
    if (m == 0) {
      int eb = e0 + q * 4;
      a2[eb + 0] = s0 + be2v;
      a2[eb + 1] = s1 + be2v;
      a2[eb + 2] = s2 + be2v;
      a2[eb + 3] = s3 + be2v;
    }
  }
}

// fused fwd: mfma_fwd (MFMA pipe) + edge_mlp (VALU pipe) in one dispatch
__global__ __launch_bounds__(256) void fwd_k(const ushort_t* __restrict__ Gb,
                                             const ushort_t* __restrict__ Wt,
                                             ushort_t* __restrict__ QK,
                                             const float* __restrict__ EA,
                                             const float* __restrict__ We1,
                                             const float* __restrict__ be1,
                                             const float* __restrict__ We2,
                                             const float* __restrict__ be2,
                                             float* __restrict__ a2) {
  int bx = blockIdx.x;
  if (bx < MB * 10) {
    mfma_fwd_body(bx / 10, bx % 10, Gb, Wt, QK, NN);
  } else {
    edge_mlp_body(bx - MB * 10, EA, We1, be1, We2, be2, a2);
  }
}

// ---------------- bwd MFMA GEMM: dG[M,128](bf16) = dAll[M,640](bf16) @ Wc^T ----------------
__global__ __launch_bounds__(256) void mfma_bwd(const ushort_t* __restrict__ dAll,
                                                const ushort_t* __restrict__ Wc,
                                                unsigned* __restrict__ dG, int M) {
  __shared__ ushort_t sB[64][40];
  int tid = threadIdx.x;
  int nb = blockIdx.y * 64;
  int w = tid >> 6, l = tid & 63, quad = l >> 4, j = l & 15;
  int row0 = blockIdx.x * 64 + w * 16;
  int arow = row0 + j; if (arow >= M) arow = M - 1;
  const ushort_t* arp = dAll + (size_t)arow * 640;
  f32x4 acc[4];
#pragma unroll
  for (int nt = 0; nt < 4; nt++) acc[nt] = (f32x4){0.f, 0.f, 0.f, 0.f};
  int sr = tid >> 2, sc = tid & 3;
  for (int kc = 0; kc < 20; kc++) {
    __syncthreads();
    *(bf16x8*)&sB[sr][sc * 8] = *(const bf16x8*)(Wc + (size_t)(nb + sr) * 640 + kc * 32 + sc * 8);
    __syncthreads();
    bf16x8 a = *(const bf16x8*)(arp + kc * 32 + quad * 8);
#pragma unroll
    for (int nt = 0; nt < 4; nt++) {
      bf16x8 b = *(const bf16x8*)&sB[nt * 16 + j][quad * 8];
      acc[nt] = __builtin_amdgcn_mfma_f32_16x16x32_bf16(a, b, acc[nt], 0, 0, 0);
    }
  }
#pragma unroll
  for (int nt = 0; nt < 4; nt++)
#pragma unroll
    for (int r = 0; r < 4; r++) {
      int row = row0 + quad * 4 + r;
      if (row < M) ((ushort_t*)dG)[(size_t)row * 128 + nb + nt * 16 + j] = bf16_1(acc[nt][r]);
    }
}

// ---------------- small fp32 GEMM for Km = B_mem @ W_Km ----------------
__global__ __launch_bounds__(256, 1) void gemm_km(const float* __restrict__ A,
                                                  const float* __restrict__ W,
                                                  float* __restrict__ C, int M) {
  __shared__ float As[32][132];
  __shared__ float Wst[128][136];
  const int tid = threadIdx.x;
  for (int idx = tid; idx < 128 * 128; idx += 256) {
    int k = idx >> 7, jj = idx & 127;
    Wst[k][jj] = W[k * 128 + jj];
  }
  for (int idx = tid; idx < 32 * 128; idx += 256) {
    int r = idx >> 7, d = idx & 127;
    As[r][d] = A[r * 128 + d];
  }
  __syncthreads();
  int r = tid >> 3, c0 = (tid & 7) * 16;
  float acc[16];
#pragma unroll
  for (int q = 0; q < 16; q++) acc[q] = 0.f;
  for (int k = 0; k < 128; k++) {
    float av = As[r][k];
#pragma unroll
    for (int q = 0; q < 16; q++) acc[q] = fmaf(av, Wst[k][c0 + q], acc[q]);
  }
#pragma unroll
  for (int q = 0; q < 16; q++) C[r * 128 + c0 + q] = acc[q];
}

// ---------------- histograms with position capture (8-deep ILP) ----------------
__global__ __launch_bounds__(256) void hist2(const int* __restrict__ a,
                                             const int* __restrict__ b,
                                             int* __restrict__ ca,
                                             int* __restrict__ cb,
                                             int* __restrict__ pos_a,
                                             int* __restrict__ pos_b, int n) {
  int base = blockIdx.x * 2048 + threadIdx.x;
  if (base + 1792 < n) {
    int av[8], bv[8], pa[8], pb[8];
#pragma unroll
    for (int k = 0; k < 8; k++) { int e = base + k * 256; av[k] = a[e]; bv[k] = b[e]; }
#pragma unroll
    for (int k = 0; k < 8; k++) pa[k] = atomicAdd(&ca[av[k]], 1);
#pragma unroll
    for (int k = 0; k < 8; k++) pb[k] = atomicAdd(&cb[bv[k]], 1);
#pragma unroll
    for (int k = 0; k < 8; k++) pos_a[base + k * 256] = pa[k];
#pragma unroll
    for (int k = 0; k < 8; k++) pos_b[base + k * 256] = pb[k];
  } else {
#pragma unroll
    for (int k = 0; k < 8; k++) {
      int e = base + k * 256;
      if (e < n) {
        pos_a[e] = atomicAdd(&ca[a[e]], 1);
        pos_b[e] = atomicAdd(&cb[b[e]], 1);
      }
    }
  }
}

__global__ __launch_bounds__(256) void hist_t3(const int* __restrict__ c,
                                               const int* __restrict__ u,
                                               const int* __restrict__ v,
                                               int* __restrict__ cc,
                                               int* __restrict__ cuv,
                                               int* __restrict__ pos_c,
                                               int* __restrict__ pos_u,
                                               int* __restrict__ pos_v, int n) {
  int base = blockIdx.x * 2048 + threadIdx.x;
  if (base + 1792 < n) {
    int cv[8], uv[8], vv[8], pc[8], pu[8], pv[8];
#pragma unroll
    for (int k = 0; k < 8; k++) { int t = base + k * 256; cv[k] = c[t]; uv[k] = u[t]; vv[k] = v[t]; }
#pragma unroll
    for (int k = 0; k < 8; k++) pc[k] = atomicAdd(&cc[cv[k]], 1);
#pragma unroll
    for (int k = 0; k < 8; k++) pu[k] = atomicAdd(&cuv[uv[k]], 1);
#pragma unroll
    for (int k = 0; k < 8; k++) pv[k] = atomicAdd(&cuv[vv[k]], 1);
#pragma unroll
    for (int k = 0; k < 8; k++) pos_c[base + k * 256] = pc[k];
#pragma unroll
    for (int k = 0; k < 8; k++) pos_u[base + k * 256] = pu[k];
#pragma unroll
    for (int k = 0; k < 8; k++) pos_v[base + k * 256] = pv[k];
  } else {
#pragma unroll
    for (int k = 0; k < 8; k++) {
      int t = base + k * 256;
      if (t < n) {
        pos_c[t] = atomicAdd(&cc[c[t]], 1);
        pos_u[t] = atomicAdd(&cuv[u[t]], 1);
        pos_v[t] = atomicAdd(&cuv[v[t]], 1);
      }
    }
  }
}

// ---------------- parallel 3-phase scan over 4 count arrays ----------------
__global__ __launch_bounds__(256) void scan_p1(const int* __restrict__ cnt,
                                               int* __restrict__ part) {
  int arr = blockIdx.y, b = blockIdx.x;
  const int* c = cnt + (size_t)arr * NN;
  int gi = b * SCAN_TILE + threadIdx.x * 8;
  int s = 0;
#pragma unroll
  for (int t = 0; t < 8; t++) s += (gi + t < NN) ? c[gi + t] : 0;
#pragma unroll
  for (int m = 32; m; m >>= 1) s += __shfl_xor(s, m, 64);
  __shared__ int wt[4];
  int lane = threadIdx.x & 63, wid = threadIdx.x >> 6;
  if (lane == 0) wt[wid] = s;
  __syncthreads();
  if (threadIdx.x == 0) part[arr * SCAN_NB + b] = wt[0] + wt[1] + wt[2] + wt[3];
}

__global__ __launch_bounds__(256) void scan_p2(int* __restrict__ part) {
  int w = threadIdx.x >> 6, l = threadIdx.x & 63;
  int v = (l < SCAN_NB) ? part[w * SCAN_NB + l] : 0;
  int x = v;
#pragma unroll
  for (int d = 1; d < 64; d <<= 1) {
    int y = __shfl_up(x, d, 64);
    if (l >= d) x += y;
  }
  if (l < SCAN_NB) part[w * SCAN_NB + l] = x - v;
}

__global__ __launch_bounds__(256) void scan_p3(const int* __restrict__ cnt,
                                               const int* __restrict__ part,
                                               int* __restrict__ rowptr) {
  int arr = blockIdx.y, b = blockIdx.x;
  const int* c = cnt + (size_t)arr * NN;
  int* rp = rowptr + (size_t)arr * (NN + 1);
  int tid = threadIdx.x;
  int gi = b * SCAN_TILE + tid * 8;
  int vals[8];
#pragma unroll
  for (int t = 0; t < 8; t++) vals[t] = (gi + t < NN) ? c[gi + t] : 0;
  int tsum = 0;
#pragma unroll
  for (int t = 0; t < 8; t++) tsum += vals[t];
  int lane = tid & 63, wid = tid >> 6;
  int x = tsum;
#pragma unroll
  for (int d = 1; d < 64; d <<= 1) {
    int y = __shfl_up(x, d, 64);
    if (lane >= d) x += y;
  }
  __shared__ int wt[4];
  if (lane == 63) wt[wid] = x;
  __syncthreads();
  int wadd = 0;
  for (int w = 0; w < wid; w++) wadd += wt[w];
  int running = part[arr * SCAN_NB + b] + wadd + x - tsum;
#pragma unroll
  for (int t = 0; t < 8; t++) {
    if (gi + t < NN) rp[gi + t] = running;
    running += vals[t];
  }
  if (b == SCAN_NB - 1 && tid == 255) rp[NN] = running;
}

// ---------------- atomic-free packed scatter (8-deep ILP) ----------------
__global__ __launch_bounds__(256) void scat2(const int* __restrict__ c2,
                                             const int* __restrict__ u2,
                                             const float* __restrict__ a2,
                                             const int* __restrict__ posc,
                                             const int* __restrict__ posu,
                                             const int* __restrict__ rpc,
                                             const int* __restrict__ rpu,
                                             uint2* __restrict__ payc,
                                             uint2* __restrict__ payu, int n) {
  int base = blockIdx.x * 2048 + threadIdx.x;
  if (base + 1792 < n) {
    int c[8], u[8]; float a[8]; int pc[8], pu[8];
#pragma unroll
    for (int k = 0; k < 8; k++) {
      int e = base + k * 256;
      c[k] = c2[e]; u[k] = u2[e]; a[k] = a2[e]; pc[k] = posc[e]; pu[k] = posu[e];
    }
    int p[8], q[8];
#pragma unroll
    for (int k = 0; k < 8; k++) { p[k] = rpc[c[k]] + pc[k]; q[k] = rpu[u[k]] + pu[k]; }
#pragma unroll
    for (int k = 0; k < 8; k++) {
      uint2 t; t.x = (unsigned)u[k]; t.y = __float_as_uint(a[k]);
      payc[p[k]] = t;
    }
#pragma unroll
    for (int k = 0; k < 8; k++) {
      uint2 t; t.x = (unsigned)p[k]; t.y = (unsigned)c[k];
      payu[q[k]] = t;
    }
  } else {
#pragma unroll
    for (int k = 0; k < 8; k++) {
      int e = base + k * 256;
      if (e < n) {
        int cc = c2[e], uu = u2[e];
        int pp = rpc[cc] + posc[e];
        int qq = rpu[uu] + posu[e];
        uint2 t; t.x = (unsigned)uu; t.y = __float_as_uint(a2[e]);
        payc[pp] = t;
        uint2 t2; t2.x = (unsigned)pp; t2.y = (unsigned)cc;
        payu[qq] = t2;
      }
    }
  }
}

__global__ __launch_bounds__(256) void scat_t3(const int* __restrict__ c3,
                                               const int* __restrict__ u3,
                                               const int* __restrict__ v3,
                                               const int* __restrict__ ttau,
                                               const int* __restrict__ posc,
                                               const int* __restrict__ posu,
                                               const int* __restrict__ posv,
                                               const int* __restrict__ rpc,
                                               const int* __restrict__ rpuv,
                                               uint2* __restrict__ payc,
                                               uint2* __restrict__ payuv, int n) {
  int base = blockIdx.x * 2048 + threadIdx.x;
  if (base + 1792 < n) {
    int c[8], u[8], v[8], ta[8], p[8], q1[8], q2[8];
#pragma unroll
    for (int k = 0; k < 8; k++) {
      int t = base + k * 256;
      c[k] = c3[t]; u[k] = u3[t]; v[k] = v3[t]; ta[k] = ttau[t] & 1;
    }
#pragma unroll
    for (int k = 0; k < 8; k++) {
      int t = base + k * 256;
      p[k] = rpc[c[k]] + posc[t];
      q1[k] = rpuv[u[k]] + posu[t];
      q2[k] = rpuv[v[k]] + posv[t];
    }
#pragma unroll
    for (int k = 0; k < 8; k++) {
      uint2 a; a.x = ((unsigned)u[k] << 16) | (unsigned)v[k]; a.y = (unsigned)ta[k];
      payc[p[k]] = a;
    }
#pragma unroll
    for (int k = 0; k < 8; k++) {
      unsigned sp = ((unsigned)p[k] << 1) | (unsigned)ta[k];
      uint2 b1; b1.x = ((unsigned)v[k] << 16) | (unsigned)c[k]; b1.y = sp;
      payuv[q1[k]] = b1;
      uint2 b2; b2.x = ((unsigned)u[k] << 16) | (unsigned)c[k]; b2.y = sp;
      payuv[q2[k]] = b2;
    }
  } else {
#pragma unroll
    for (int k = 0; k < 8; k++) {
      int t = base + k * 256;
      if (t < n) {
        int c = c3[t], u = u3[t], v = v3[t], ta = ttau[t] & 1;
        int p = rpc[c] + posc[t];
        int q1 = rpuv[u] + posu[t];
        int q2 = rpuv[v] + posv[t];
        unsigned sp = ((unsigned)p << 1) | (unsigned)ta;
        uint2 a; a.x = ((unsigned)u << 16) | (unsigned)v; a.y = (unsigned)ta;
        payc[p] = a;
        uint2 b1; b1.x = ((unsigned)v << 16) | (unsigned)c; b1.y = sp;
        payuv[q1] = b1;
        uint2 b2; b2.x = ((unsigned)u << 16) | (unsigned)c; b2.y = sp;
        payuv[q2] = b2;
      }
    }
  }
}

// ---------------- fused e2 fwd + dQ2 (pair-processing, 6 gathers in flight) ----------------
__device__ void e2_body(int bx, const unsigned* __restrict__ QK,
                        const float* __restrict__ P,
                        const uint2* __restrict__ pay,
                        const int* __restrict__ rp,
                        float* __restrict__ s2c,
                        float* __restrict__ L2,
                        unsigned* __restrict__ dAll) {
  int row = bx * 4 + (threadIdx.x >> 6);
  int l = threadIdx.x & 63, g = l >> 4, j = l & 15;
  float b2s = P[0] * INV_SQRT_D, cw2 = P[3];
  float q[8];
  unp8(*(const uint4*)(QK + (size_t)row * UU + j * 4), q);
  int s = rp[row], e = rp[row + 1];
  float m = -3.0e38f, z = 0.f;
  float acc[8] = {0.f, 0.f, 0.f, 0.f, 0.f, 0.f, 0.f, 0.f};
  int i0 = s + g;
  uint4 kA1 = {0,0,0,0}, kA2 = {0,0,0,0}, kB1 = {0,0,0,0}, kB2 = {0,0,0,0};
  float aA1 = 0.f, aA2 = 0.f, aB1 = 0.f, aB2 = 0.f;
  if (i0 < e)      { uint2 w = pay[i0];      aA1 = __uint_as_float(w.y); kA1 = *(const uint4*)(QK + (size_t)w.x * UU + 64 + j * 4); }
  if (i0 + 4 < e)  { uint2 w = pay[i0 + 4];  aA2 = __uint_as_float(w.y); kA2 = *(const uint4*)(QK + (size_t)w.x * UU + 64 + j * 4); }
  if (i0 + 8 < e)  { uint2 w = pay[i0 + 8];  aB1 = __uint_as_float(w.y); kB1 = *(const uint4*)(QK + (size_t)w.x * UU + 64 + j * 4); }
  if (i0 + 12 < e) { uint2 w = pay[i0 + 12]; aB2 = __uint_as_float(w.y); kB2 = *(const uint4*)(QK + (size_t)w.x * UU + 64 + j * 4); }
  for (int i = i0; i < e; i += 8) {
    uint4 kC1 = {0,0,0,0}, kC2 = {0,0,0,0}; float aC1 = 0.f, aC2 = 0.f;
    if (i + 16 < e) { uint2 w = pay[i + 16]; aC1 = __uint_as_float(w.y); kC1 = *(const uint4*)(QK + (size_t)w.x * UU + 64 + j * 4); }
    if (i + 20 < e) { uint2 w = pay[i + 20]; aC2 = __uint_as_float(w.y); kC2 = *(const uint4*)(QK + (size_t)w.x * UU + 64 + j * 4); }
    // edge i
    {
      float k[8]; unp8(kA1, k);
      float d = 0.f;
#pragma unroll
      for (int t = 0; t < 8; t++) d = fmaf(q[t], k[t], d);
      d = redsum16(d);
      float sv = b2s * d + aA1;
      if (j == 0) s2c[i] = sv;
      if (sv <= m) {
        float p = __expf(sv - m);
        z += p;
#pragma unroll
        for (int t = 0; t < 8; t++) acc[t] = fmaf(p, k[t], acc[t]);
      } else {
        float r = __expf(m - sv);
        z = fmaf(z, r, 1.f);
#pragma unroll
        for (int t = 0; t < 8; t++) acc[t] = fmaf(acc[t], r, k[t]);
        m = sv;
      }
    }
    // edge i+4
    if (i + 4 < e) {
      float k[8]; unp8(kA2, k);
      float d = 0.f;
#pragma unroll
      for (int t = 0; t < 8; t++) d = fmaf(q[t], k[t], d);
      d = redsum16(d);
      float sv = b2s * d + aA2;
      if (j == 0) s2c[i + 4] = sv;
      if (sv <= m) {
        float p = __expf(sv - m);
        z += p;
#pragma unroll
        for (int t = 0; t < 8; t++) acc[t] = fmaf(p, k[t], acc[t]);
      } else {
        float r = __expf(m - sv);
        z = fmaf(z, r, 1.f);
#pragma unroll
        for (int t = 0; t < 8; t++) acc[t] = fmaf(acc[t], r, k[t]);
        m = sv;
      }
    }
    kA1 = kB1; aA1 = aB1; kA2 = kB2; aA2 = aB2;
    kB1 = kC1; aB1 = aC1; kB2 = kC2; aB2 = aC2;
  }
  float mx = fmaxf(m, __shfl_xor(m, 16, 64));
  mx = fmaxf(mx, __shfl_xor(mx, 32, 64));
  float r = (z > 0.f) ? __expf(m - mx) : 0.f;
  float zz = z * r;
  zz += __shfl_xor(zz, 16, 64);
  zz += __shfl_xor(zz, 32, 64);
#pragma unroll
  for (int t = 0; t < 8; t++) {
    float v = acc[t] * r;
    v += __shfl_xor(v, 16, 64);
    v += __shfl_xor(v, 32, 64);
    acc[t] = v;
  }
  if (l == 0) L2[row] = (zz > 0.f) ? (mx + __logf(zz)) : 0.f;
  if (g == 0) {
    float coef = (zz > 0.f) ? cw2 / zz : 0.f;
    float o[8];
#pragma unroll
    for (int t = 0; t < 8; t++) o[t] = coef * acc[t];
    *(uint4*)(dAll + (size_t)row * UU + 0 + j * 4) = pk8(o);
  }
}

// ---------------- fused t3 fwd + dQ3 (3-deep pipeline; padded T in LDS) ----------------
// smem layout: [2][16][9] floats; element d of row ta at ta*144 + (d>>3)*9 + (d&7)
__device__ void t3_body(int bx, const unsigned* __restrict__ QK,
                        const float* __restrict__ P,
                        const uint2* __restrict__ pay,
                        const int* __restrict__ rp,
                        float* __restrict__ s3c,
                        float* __restrict__ L3,
                        unsigned* __restrict__ dAll,
                        const float* __restrict__ sT) {
  int tid = threadIdx.x;
  int row = bx * 4 + (tid >> 6);
  int l = tid & 63, g = l >> 4, j = l & 15;
  float b3s = P[1] * INV_D, cw3 = P[4];
  float q[8];
  unp8(*(const uint4*)(QK + (size_t)row * UU + 128 + j * 4), q);
  int s = rp[row], e = rp[row + 1];
  float m = -3.0e38f, z = 0.f;
  float acc[8] = {0.f, 0.f, 0.f, 0.f, 0.f, 0.f, 0.f, 0.f};
  int i0 = s + g;
  uint4 kuA = {0,0,0,0}, kvA = {0,0,0,0};
  uint4 kuB = {0,0,0,0}, kvB = {0,0,0,0};
  int taA = 0, taB = 0;
  if (i0 < e) {
    uint2 w = pay[i0]; int u = w.x >> 16, v = w.x & 0xffff; taA = (int)w.y;
    kuA = *(const uint4*)(QK + (size_t)u * UU + 192 + j * 4);
    kvA = *(const uint4*)(QK + (size_t)v * UU + 192 + j * 4);
  }
  if (i0 + 4 < e) {
    uint2 w = pay[i0 + 4]; int u = w.x >> 16, v = w.x & 0xffff; taB = (int)w.y;
    kuB = *(const uint4*)(QK + (size_t)u * UU + 192 + j * 4);
    kvB = *(const uint4*)(QK + (size_t)v * UU + 192 + j * 4);
  }
  for (int i = i0; i < e; i += 4) {
    uint4 kuC = {0,0,0,0}, kvC = {0,0,0,0}; int taC = 0;
    if (i + 8 < e) {
      uint2 w = pay[i + 8]; int u = w.x >> 16, v = w.x & 0xffff; taC = (int)w.y;
      kuC = *(const uint4*)(QK + (size_t)u * UU + 192 + j * 4);
      kvC = *(const uint4*)(QK + (size_t)v * UU + 192 + j * 4);
    }
    float ku[8], kv[8]; unp8(kuA, ku); unp8(kvA, kv);
    const float* tv = &sT[taA * 144 + j * 9];
    float et[8], d = 0.f;
#pragma unroll
    for (int t = 0; t < 8; t++) { et[t] = ku[t] * kv[t] * tv[t]; d = fmaf(q[t], et[t], d); }
    d = redsum16(d);
    float sv = b3s * d;
    if (j == 0) s3c[i] = sv;
    if (sv <= m) {
      float p = __expf(sv - m);
      z += p;
#pragma unroll
      for (int t = 0; t < 8; t++) acc[t] = fmaf(p, et[t], acc[t]);
    } else {
      float r = __expf(m - sv);
      z = fmaf(z, r, 1.f);
#pragma unroll
      for (int t = 0; t < 8; t++) acc[t] = fmaf(acc[t], r, et[t]);
      m = sv;
    }
    kuA = kuB; kvA = kvB; taA = taB;
    kuB = kuC; kvB = kvC; taB = taC;
  }
  float mx = fmaxf(m, __shfl_xor(m, 16, 64));
  mx = fmaxf(mx, __shfl_xor(mx, 32, 64));
  float r = (z > 0.f) ? __expf(m - mx) : 0.f;
  float zz = z * r;
  zz += __shfl_xor(zz, 16, 64);
  zz += __shfl_xor(zz, 32, 64);
#pragma unroll
  for (int t = 0; t < 8; t++) {
    float v = acc[t] * r;
    v += __shfl_xor(v, 16, 64);
    v += __shfl_xor(v, 32, 64);
    acc[t] = v;
  }
  if (l == 0) L3[row] = (zz > 0.f) ? (mx + __logf(zz)) : 0.f;
  if (g == 0) {
    float coef = (zz > 0.f) ? cw3 / zz : 0.f;
    float o[8];
#pragma unroll
    for (int t = 0; t < 8; t++) o[t] = coef * acc[t];
    *(uint4*)(dAll + (size_t)row * UU + 128 + j * 4) = pk8(o);
  }
}

// ---------------- memory-bank energy (padded Km in LDS) ----------------
// smem layout: [32][16][9]; element d of row k at k*144 + (d>>3)*9 + (d&7)
__device__ void em_body(int bx, const unsigned* __restrict__ QK,
                        const float* __restrict__ P,
                        unsigned* __restrict__ dAll,
                        float* __restrict__ Lm,
                        const float* __restrict__ sKm) {
  int tid = threadIdx.x;
  int row = bx * 4 + (tid >> 6);
  int l = tid & 63, g = l >> 4, j = l & 15;
  float bms = P[2] * INV_SQRT_D, cwm = P[5];
  float q[8];
  unp8(*(const uint4*)(QK + (size_t)row * UU + 256 + j * 4), q);
  float dk[8];
#pragma unroll
  for (int kk = 0; kk < 8; kk++) {
    int k = g * 8 + kk;
    const float* kr = &sKm[k * 144 + j * 9];
    float d = 0.f;
#pragma unroll
    for (int t = 0; t < 8; t++) d = fmaf(q[t], kr[t], d);
    dk[kk] = redsum16(d) * bms;
  }
  float m = dk[0];
#pragma unroll
  for (int kk = 1; kk < 8; kk++) m = fmaxf(m, dk[kk]);
  float mx = fmaxf(m, __shfl_xor(m, 16, 64));
  mx = fmaxf(mx, __shfl_xor(mx, 32, 64));
  float p[8], z = 0.f;
#pragma unroll
  for (int kk = 0; kk < 8; kk++) { p[kk] = __expf(dk[kk] - mx); z += p[kk]; }
  float zz = z;
  zz += __shfl_xor(zz, 16, 64);
  zz += __shfl_xor(zz, 32, 64);
  if (l == 0) Lm[row] = mx + __logf(zz);
  float coef = cwm / zz;
  float acc[8] = {0.f, 0.f, 0.f, 0.f, 0.f, 0.f, 0.f, 0.f};
#pragma unroll
  for (int kk = 0; kk < 8; kk++) {
    int k = g * 8 + kk;
    const float* kr = &sKm[k * 144 + j * 9];
    float pc_ = p[kk] * coef;
#pragma unroll
    for (int t = 0; t < 8; t++) acc[t] = fmaf(pc_, kr[t], acc[t]);
  }
#pragma unroll
  for (int t = 0; t < 8; t++) {
    float v = acc[t];
    v += __shfl_xor(v, 16, 64);
    v += __shfl_xor(v, 32, 64);
    acc[t] = v;
  }
  if (g == 0) *(uint4*)(dAll + (size_t)row * UU + 256 + j * 4) = pk8(acc);
}

// fused phase2: e2_fused + t3_fused + em_row (mutually independent)
__global__ __launch_bounds__(256) void phase2_k(const unsigned* __restrict__ QK,
                                                const float* __restrict__ Tt,
                                                const float* __restrict__ Km,
                                                const float* __restrict__ P,
                                                const uint2* __restrict__ payc2,
                                                const int* __restrict__ rp_c2,
                                                const uint2* __restrict__ payc3,
                                                const int* __restrict__ rp_c3,
                                                float* __restrict__ s2c,
                                                float* __restrict__ L2,
                                                float* __restrict__ s3c,
                                                float* __restrict__ L3,
                                                float* __restrict__ Lm,
                                                unsigned* __restrict__ dAll) {
  __shared__ float smem[32 * 144];  // union: t3 uses [2][16][9]=288, em uses [32][16][9]=4608
  int bx = blockIdx.x;
  int tid = threadIdx.x;
  if (bx < ROWB) {
    e2_body(bx, QK, P, payc2, rp_c2, s2c, L2, dAll);
  } else if (bx < 2 * ROWB) {
    {
      int ta = tid >> 7, d = tid & 127;
      smem[ta * 144 + (d >> 3) * 9 + (d & 7)] = Tt[tid];
    }
    __syncthreads();
    t3_body(bx - ROWB, QK, P, payc3, rp_c3, s3c, L3, dAll, smem);
  } else {
    for (int i = tid; i < KM * DD; i += 256) {
      int k = i >> 7, d = i & 127;
      smem[k * 144 + (d >> 3) * 9 + (d & 7)] = Km[i];
    }
    __syncthreads();
    em_body(bx - 2 * ROWB, QK, P, dAll, Lm, smem);
  }
}

// ---------------- dK2 gather (pair-processing, 6 gathers in flight) ----------------
__device__ void dk2_body(int bx, const unsigned* __restrict__ QK,
                         const float* __restrict__ s2c,
                         const float* __restrict__ L2,
                         const float* __restrict__ P,
                         const uint2* __restrict__ pay,
                         const int* __restrict__ rp,
                         unsigned* __restrict__ dAll) {
  int row = bx * 4 + (threadIdx.x >> 6);
  int l = threadIdx.x & 63, g = l >> 4, j = l & 15;
  float cw2 = P[3];
  int s = rp[row], e = rp[row + 1];
  float acc[8] = {0.f, 0.f, 0.f, 0.f, 0.f, 0.f, 0.f, 0.f};
  int i0 = s + g;
  uint4 qA1 = {0,0,0,0}, qA2 = {0,0,0,0}, qB1 = {0,0,0,0}, qB2 = {0,0,0,0};
  float scA1 = 0.f, lcA1 = 0.f, scA2 = 0.f, lcA2 = 0.f;
  float scB1 = 0.f, lcB1 = 0.f, scB2 = 0.f, lcB2 = 0.f;
  if (i0 < e)      { uint2 w = pay[i0];      scA1 = s2c[w.x]; lcA1 = L2[w.y]; qA1 = *(const uint4*)(QK + (size_t)w.y * UU + 0 + j * 4); }
  if (i0 + 4 < e)  { uint2 w = pay[i0 + 4];  scA2 = s2c[w.x]; lcA2 = L2[w.y]; qA2 = *(const uint4*)(QK + (size_t)w.y * UU + 0 + j * 4); }
  if (i0 + 8 < e)  { uint2 w = pay[i0 + 8];  scB1 = s2c[w.x]; lcB1 = L2[w.y]; qB1 = *(const uint4*)(QK + (size_t)w.y * UU + 0 + j * 4); }
  if (i0 + 12 < e) { uint2 w = pay[i0 + 12]; scB2 = s2c[w.x]; lcB2 = L2[w.y]; qB2 = *(const uint4*)(QK + (size_t)w.y * UU + 0 + j * 4); }
  for (int i = i0; i < e; i += 8) {
    uint4 qC1 = {0,0,0,0}, qC2 = {0,0,0,0};
    float scC1 = 0.f, lcC1 = 0.f, scC2 = 0.f, lcC2 = 0.f;
    if (i + 16 < e) { uint2 w = pay[i + 16]; scC1 = s2c[w.x]; lcC1 = L2[w.y]; qC1 = *(const uint4*)(QK + (size_t)w.y * UU + 0 + j * 4); }
    if (i + 20 < e) { uint2 w = pay[i + 20]; scC2 = s2c[w.x]; lcC2 = L2[w.y]; qC2 = *(const uint4*)(QK + (size_t)w.y * UU + 0 + j * 4); }
    {
      float w1 = cw2 * __expf(scA1 - lcA1);
      float qv[8]; unp8(qA1, qv);
#pragma unroll
      for (int t = 0; t < 8; t++) acc[t] = fmaf(w1, qv[t], acc[t]);
    }
    if (i + 4 < e) {
      float w2 = cw2 * __expf(scA2 - lcA2);
      float qv[8]; unp8(qA2, qv);
#pragma unroll
      for (int t = 0; t < 8; t++) acc[t] = fmaf(w2, qv[t], acc[t]);
    }
    qA1 = qB1; scA1 = scB1; lcA1 = lcB1; qA2 = qB2; scA2 = scB2; lcA2 = lcB2;
    qB1 = qC1; scB1 = scC1; lcB1 = lcC1; qB2 = qC2; scB2 = scC2; lcB2 = lcC2;
  }
#pragma unroll
  for (int t = 0; t < 8; t++) {
    float v = acc[t];
    v += __shfl_xor(v, 16, 64);
    v += __shfl_xor(v, 32, 64);
    acc[t] = v;
  }
  if (g == 0) *(uint4*)(dAll + (size_t)row * UU + 64 + j * 4) = pk8(acc);
}

// ---------------- dK3 gather (3-deep pipeline; padded T in LDS) ----------------
__device__ void dk3_body(int bx, const unsigned* __restrict__ QK,
                         const float* __restrict__ s3c,
                         const float* __restrict__ L3,
                         const float* __restrict__ P,
                         const uint2* __restrict__ pay,
                         const int* __restrict__ rp,
                         unsigned* __restrict__ dAll,
                         const float* __restrict__ sT) {
  int tid = threadIdx.x;
  int row = bx * 4 + (tid >> 6);
  int l = tid & 63, g = l >> 4, j = l & 15;
  float cw3 = P[4];
  int s = rp[row], e = rp[row + 1];
  float acc[8] = {0.f, 0.f, 0.f, 0.f, 0.f, 0.f, 0.f, 0.f};
  int i0 = s + g;
  uint4 qA = {0,0,0,0}, kA = {0,0,0,0};
  uint4 qB = {0,0,0,0}, kB = {0,0,0,0};
  int taA = 0, taB = 0;
  float scA = 0.f, lcA = 0.f, scB = 0.f, lcB = 0.f;
  if (i0 < e) {
    uint2 w = pay[i0]; int o = w.x >> 16, c = w.x & 0xffff; unsigned sp = w.y;
    taA = (int)(sp & 1); scA = s3c[sp >> 1]; lcA = L3[c];
    qA = *(const uint4*)(QK + (size_t)c * UU + 128 + j * 4);
    kA = *(const uint4*)(QK + (size_t)o * UU + 192 + j * 4);
  }
  if (i0 + 4 < e) {
    uint2 w = pay[i0 + 4]; int o = w.x >> 16, c = w.x & 0xffff; unsigned sp = w.y;
    taB = (int)(sp & 1); scB = s3c[sp >> 1]; lcB = L3[c];
    qB = *(const uint4*)(QK + (size_t)c * UU + 128 + j * 4);
    kB = *(const uint4*)(QK + (size_t)o * UU + 192 + j * 4);
  }
  for (int i = i0; i < e; i += 4) {
    uint4 qC = {0,0,0,0}, kC = {0,0,0,0}; int taC = 0;
    float scC = 0.f, lcC = 0.f;
    if (i + 8 < e) {
      uint2 w = pay[i + 8]; int o = w.x >> 16, c = w.x & 0xffff; unsigned sp = w.y;
      taC = (int)(sp & 1); scC = s3c[sp >> 1]; lcC = L3[c];
      qC = *(const uint4*)(QK + (size_t)c * UU + 128 + j * 4);
      kC = *(const uint4*)(QK + (size_t)o * UU + 192 + j * 4);
    }
    float w = cw3 * __expf(scA - lcA);
    float qv[8], ko[8]; unp8(qA, qv); unp8(kA, ko);
    const float* tv = &sT[taA * 144 + j * 9];
#pragma unroll
    for (int t = 0; t < 8; t++) acc[t] = fmaf(w * tv[t], qv[t] * ko[t], acc[t]);
    qA = qB; kA = kB; taA = taB; scA = scB; lcA = lcB;
    qB = qC; kB = kC; taB = taC; scB = scC; lcB = lcC;
  }
#pragma unroll
  for (int t = 0; t < 8; t++) {
    float v = acc[t];
    v += __shfl_xor(v, 16, 64);
    v += __shfl_xor(v, 32, 64);
    acc[t] = v;
  }
  if (g == 0) *(uint4*)(dAll + (size_t)row * UU + 192 + j * 4) = pk8(acc);
}

// fused phase3: dk2_gather + dk3_gather (mutually independent)
__global__ __launch_bounds__(256) void phase3_k(const unsigned* __restrict__ QK,
                                                const float* __restrict__ Tt,
                                                const float* __restrict__ P,
                                                const float* __restrict__ s2c,
                                                const float* __restrict__ L2,
                                                const uint2* __restrict__ payu2,
                                                const int* __restrict__ rp_u2,
                                                const float* __restrict__ s3c,
                                                const float* __restrict__ L3,
                                                const uint2* __restrict__ payuv,
                                                const int* __restrict__ rp_uv,
                                                unsigned* __restrict__ dAll) {
  __shared__ float smem[2 * 144];
  int bx = blockIdx.x;
  int tid = threadIdx.x;
  if (bx < ROWB) {
    dk2_body(bx, QK, s2c, L2, P, payu2, rp_u2, dAll);
  } else {
    {
      int ta = tid >> 7, d = tid & 127;
      smem[ta * 144 + (d >> 3) * 9 + (d & 7)] = Tt[tid];
    }
    __syncthreads();
    dk3_body(bx - ROWB, QK, s3c, L3, P, payuv, rp_uv, dAll, smem);
  }
}

// ---------------- LN backward + clips + update ----------------
__global__ __launch_bounds__(256) void ln_bwd(const float* __restrict__ X,
                                              const unsigned* __restrict__ dG,
                                              const float* __restrict__ gamma,
                                              const float* __restrict__ meanv,
                                              const float* __restrict__ rstdv,
                                              float* __restrict__ out) {
  int row = blockIdx.x * 4 + (threadIdx.x >> 6);
  if (row >= NN) return;
  int l = threadIdx.x & 63;
  float mu = meanv[row], rstd = rstdv[row];
  float2 x2 = *(const float2*)(X + row * DD + 2 * l);
  unsigned gw = dG[(size_t)row * 64 + l];
  float2 ga = *(const float2*)(gamma + 2 * l);
  float xh0 = (x2.x - mu) * rstd, xh1 = (x2.y - mu) * rstd;
  float dh0 = blo(gw) * ga.x, dh1 = bhi(gw) * ga.y;
  float sa = wredsum(dh0 + dh1) * (1.f / DD);
  float sb = wredsum(dh0 * xh0 + dh1 * xh1) * (1.f / DD);
  float dx0 = rstd * (dh0 - sa - xh0 * sb);
  float dx1 = rstd * (dh1 - sa - xh1 * sb);
  float gn = fmaxf(sqrtf(wredsum(dx0 * dx0 + dx1 * dx1)), 1e-6f);
  float sc = fminf(1.f / gn, 1.f);
  dx0 *= sc; dx1 *= sc;
  float xn0 = x2.x - 0.1f * 0.9999f * dx0;
  float xn1 = x2.y - 0.1f * 0.9999f * dx1;
  float sn = fmaxf(sqrtf(wredsum(xn0 * xn0 + xn1 * xn1)), 1e-6f);
  float sc2 = fminf(10.f / sn, 1.f);
  float2 o; o.x = xn0 * sc2; o.y = xn1 * sc2;
  *(float2*)(out + row * DD + 2 * l) = o;
}

// ---------------- final energy scalar (parallel, atomic) ----------------
__global__ __launch_bounds__(256) void eval_write(const float* __restrict__ L2,
                                                  const float* __restrict__ L3,
                                                  const float* __restrict__ Lm,
                                                  const float* __restrict__ P,
                                                  float* __restrict__ out) {
  int i = blockIdx.x * 256 + threadIdx.x;
  float a2 = 0.f, a3 = 0.f, am = 0.f;
  if (i < NN) { a2 = L2[i]; a3 = L3[i]; am = Lm[i]; }
  a2 = wredsum(a2); a3 = wredsum(a3); am = wredsum(am);
  __shared__ float r2[4], r3[4], rm[4];
  int wv = threadIdx.x >> 6, l = threadIdx.x & 63;
  if (l == 0) { r2[wv] = a2; r3[wv] = a3; rm[wv] = am; }
  __syncthreads();
  if (threadIdx.x == 0) {
    float S2 = r2[0] + r2[1] + r2[2] + r2[3];
    float S3 = r3[0] + r3[1] + r3[2] + r3[3];
    float Sm = rm[0] + rm[1] + rm[2] + rm[3];
    atomicAdd(out, P[6] * S2 + P[7] * S3 + P[8] * Sm);
  }
}

extern "C" void kernel_launch(void* const* d_in, const int* in_sizes, int n_in,
                              void* d_out, int out_size, void* d_ws, size_t ws_size,
                              hipStream_t stream) {
  (void)in_sizes; (void)n_in; (void)out_size;
  const float* X = (const float*)d_in[0];
  const float* EA = (const float*)d_in[1];
  const float* ln_g = (const float*)d_in[2];
  const float* ln_b = (const float*)d_in[3];
  const float* W_Q2 = (const float*)d_in[4];
  const float* W_K2 = (const float*)d_in[5];
  const float* W_Q3 = (const float*)d_in[6];
  const float* W_K3 = (const float*)d_in[7];
  const float* T_tau = (const float*)d_in[8];
  const float* W_Qm = (const float*)d_in[9];
  const float* W_Km = (const float*)d_in[10];
  const float* B_mem = (const float*)d_in[11];
  const float* We1 = (const float*)d_in[12];
  const float* be1 = (const float*)d_in[13];
  const float* We2 = (const float*)d_in[14];
  const float* be2 = (const float*)d_in[15];
  const float* l2s = (const float*)d_in[16];
  const float* l3s = (const float*)d_in[17];
  const float* lms = (const float*)d_in[18];
  const float* b2s = (const float*)d_in[19];
  const float* b3s = (const float*)d_in[20];
  const float* bms = (const float*)d_in[21];
  const int* c2 = (const int*)d_in[22];
  const int* u2 = (const int*)d_in[23];
  const int* c3 = (const int*)d_in[24];
  const int* u3 = (const int*)d_in[25];
  const int* v3 = (const int*)d_in[26];
  const int* ttau = (const int*)d_in[27];
  float* out = (float*)d_out;

  float* ws = (float*)d_ws;
  size_t off = 0;
  auto alloc = [&](size_t n) { float* p = ws + off; off += n; return p; };
  const size_t ND = (size_t)NN * DD;
  unsigned* Gb = (unsigned*)alloc(ND / 2);
  unsigned* QKall = (unsigned*)alloc((size_t)NN * UU);
  unsigned* dAll = (unsigned*)alloc((size_t)NN * UU);
  unsigned* dG = (unsigned*)alloc(ND / 2);
  ushort_t* Wt5 = (ushort_t*)alloc(640 * 128 / 2);
  ushort_t* Wcat = (ushort_t*)alloc(640 * 128 / 2);
  float* Km = alloc((size_t)KM * DD);
  float* a2 = alloc(EE);
  float* s2c = alloc(EE);
  float* s3c = alloc(TT);
  float* meanv = alloc(NN);
  float* rstdv = alloc(NN);
  float* L2 = alloc(NN);
  float* L3 = alloc(NN);
  float* Lm = alloc(NN);
  float* Pparams = alloc(16);
  int* cnt = (int*)alloc(4 * (size_t)NN);
  int* rowptr = (int*)alloc(4 * (size_t)(NN + 1));
  int* spart = (int*)alloc(4 * SCAN_NB);
  int* pos_c2 = (int*)alloc(EE);
  int* pos_u2 = (int*)alloc(EE);
  int* pos_c3 = (int*)alloc(TT);
  int* pos_u3 = (int*)alloc(TT);
  int* pos_v3 = (int*)alloc(TT);
  uint2* payc2 = (uint2*)alloc(2 * (size_t)EE);
  uint2* payu2 = (uint2*)alloc(2 * (size_t)EE);
  uint2* payc3 = (uint2*)alloc(2 * (size_t)TT);
  uint2* payuv = (uint2*)alloc(4 * (size_t)TT);
  if (off * sizeof(float) > ws_size) return;

  int* cnt_c2 = cnt, *cnt_u2 = cnt + NN, *cnt_c3 = cnt + 2 * NN, *cnt_uv = cnt + 3 * NN;
  int* rp_c2 = rowptr, *rp_u2 = rowptr + (NN + 1), *rp_c3 = rowptr + 2 * (NN + 1), *rp_uv = rowptr + 3 * (NN + 1);

  hipMemsetAsync(cnt, 0, 4ull * NN * sizeof(int), stream);
  hipMemsetAsync(out + ND, 0, sizeof(float), stream);

  params_k<<<1, 64, 0, stream>>>(l2s, l3s, lms, b2s, b3s, bms, Pparams);

  int rowB = ROWB;

  ln_fwd<<<rowB, 256, 0, stream>>>(X, ln_g, ln_b, Gb, meanv, rstdv);
  w_conv<<<320, 256, 0, stream>>>(W_Q2, W_K2, W_Q3, W_K3, W_Qm, Wt5, Wcat);
  gemm_km<<<1, 256, 0, stream>>>(B_mem, W_Km, Km, KM);
  fwd_k<<<MB * 10 + EDGE_BLKS, 256, 0, stream>>>((const ushort_t*)Gb, Wt5, (ushort_t*)QKall,
                                                 EA, We1, be1, We2, be2, a2);

  hist2<<<(EE + 2047) / 2048, 256, 0, stream>>>(c2, u2, cnt_c2, cnt_u2, pos_c2, pos_u2, EE);
  hist_t3<<<(TT + 2047) / 2048, 256, 0, stream>>>(c3, u3, v3, cnt_c3, cnt_uv,
                                                  pos_c3, pos_u3, pos_v3, TT);
  scan_p1<<<dim3(SCAN_NB, 4), 256, 0, stream>>>(cnt, spart);
  scan_p2<<<1, 256, 0, stream>>>(spart);
  scan_p3<<<dim3(SCAN_NB, 4), 256, 0, stream>>>(cnt, spart, rowptr);
  scat2<<<(EE + 2047) / 2048, 256, 0, stream>>>(c2, u2, a2, pos_c2, pos_u2,
                                                rp_c2, rp_u2, payc2, payu2, EE);
  scat_t3<<<(TT + 2047) / 2048, 256, 0, stream>>>(c3, u3, v3, ttau,
                                                  pos_c3, pos_u3, pos_v3,
                                                  rp_c3, rp_uv, payc3, payuv, TT);

  phase2_k<<<3 * ROWB, 256, 0, stream>>>(QKall, T_tau, Km, Pparams,
                                         payc2, rp_c2, payc3, rp_c3,
                                         s2c, L2, s3c, L3, Lm, dAll);
  phase3_k<<<2 * ROWB, 256, 0, stream>>>(QKall, T_tau, Pparams,
                                         s2c, L2, payu2, rp_u2,
                                         s3c, L3, payuv, rp_uv, dAll);

  mfma_bwd<<<dim3(MB, 2), 256, 0, stream>>>((const ushort_t*)dAll, Wcat, dG, NN);

  ln_bwd<<<rowB, 256, 0, stream>>>(X, dG, ln_g, meanv, rstdv, out);
  eval_write<<<(NN + 255) / 256, 256, 0, stream>>>(L2, L3, Lm, Pparams, out + ND);
}

// Round 7
// 765.196 us; speedup vs baseline: 1.2408x; 1.0023x over previous
//
#include <hip/hip_runtime.h>

#define NN 50000
#define DD 128
#define EE 800000
#define TT 400000
#define KM 32
#define UU 320  // uints per 640-col bf16 row
#define ROWB 12500           // NN/4
#define MB 782               // ceil(NN/64)
#define EDGE_BLKS 3125       // EE/256
#define HB2 391              // ceil(EE/2048)
#define HBT 196              // ceil(TT/2048)
#define WCB 320
#define ZCB 196              // cnt zero blocks (196*1024 >= 200000)
#define SCAN_TILE 2048
#define SCAN_NB ((NN + SCAN_TILE - 1) / SCAN_TILE)  // 25

static constexpr float INV_SQRT_D = 0.08838834764831845f; // 1/sqrt(128)
static constexpr float INV_D = 1.f / 128.f;

typedef __attribute__((ext_vector_type(8))) short bf16x8;
typedef __attribute__((ext_vector_type(4))) float f32x4;
typedef unsigned short ushort_t;

__device__ __forceinline__ float softplus_f(float x) {
  return (x > 20.f) ? x : log1pf(__expf(x));
}

// exact rewrite of tanh-gelu: 0.5x(1+tanh(z)) == x * sigmoid(2z)
__device__ __forceinline__ float gelu_fast(float x) {
  float p = fmaf(0.044715f * x * x, x, x);
  float e = __expf(-1.5957691216057308f * p);
  return x * __builtin_amdgcn_rcpf(1.f + e);
}

__device__ __forceinline__ float wredsum(float v) {
#pragma unroll
  for (int m = 32; m; m >>= 1) v += __shfl_xor(v, m, 64);
  return v;
}

__device__ __forceinline__ float redsum16(float v) {
#pragma unroll
  for (int m = 1; m < 16; m <<= 1) v += __shfl_xor(v, m, 64);
  return v;
}

__device__ __forceinline__ float blo(unsigned w) { return __uint_as_float(w << 16); }
__device__ __forceinline__ float bhi(unsigned w) { return __uint_as_float(w & 0xffff0000u); }
__device__ __forceinline__ unsigned pack_bf16(float a, float b) {
  unsigned ua = __float_as_uint(a); ua += 0x7fff + ((ua >> 16) & 1);
  unsigned ub = __float_as_uint(b); ub += 0x7fff + ((ub >> 16) & 1);
  return (ua >> 16) | (ub & 0xffff0000u);
}
__device__ __forceinline__ ushort_t bf16_1(float x) {
  unsigned u = __float_as_uint(x); u += 0x7fff + ((u >> 16) & 1);
  return (ushort_t)(u >> 16);
}
__device__ __forceinline__ void unp8(uint4 w, float* f) {
  f[0] = blo(w.x); f[1] = bhi(w.x); f[2] = blo(w.y); f[3] = bhi(w.y);
  f[4] = blo(w.z); f[5] = bhi(w.z); f[6] = blo(w.w); f[7] = bhi(w.w);
}
__device__ __forceinline__ uint4 pk8(const float* f) {
  uint4 r;
  r.x = pack_bf16(f[0], f[1]); r.y = pack_bf16(f[2], f[3]);
  r.z = pack_bf16(f[4], f[5]); r.w = pack_bf16(f[6], f[7]);
  return r;
}

// ---------------- prep bodies ----------------
__device__ void ln_fwd_body(int bx, const float* __restrict__ X,
                            const float* __restrict__ gamma,
                            const float* __restrict__ beta,
                            unsigned* __restrict__ Gb,
                            float* __restrict__ meanv,
                            float* __restrict__ rstdv) {
  int row = bx * 4 + (threadIdx.x >> 6);
  if (row >= NN) return;
  int l = threadIdx.x & 63;
  float2 x2 = *(const float2*)(X + row * DD + 2 * l);
  float mu = wredsum(x2.x + x2.y) * (1.f / DD);
  float d0 = x2.x - mu, d1 = x2.y - mu;
  float var = wredsum(d0 * d0 + d1 * d1) * (1.f / DD);
  float rstd = rsqrtf(var + 1e-5f);
  float2 g2 = *(const float2*)(gamma + 2 * l);
  float2 b2 = *(const float2*)(beta + 2 * l);
  float o0 = d0 * rstd * g2.x + b2.x;
  float o1 = d1 * rstd * g2.y + b2.y;
  Gb[(size_t)row * 64 + l] = pack_bf16(o0, o1);
  if (l == 0) { meanv[row] = mu; rstdv[row] = rstd; }
}

__device__ void w_conv_body(int b, const float* W0, const float* W1, const float* W2,
                            const float* W3, const float* W4,
                            ushort_t* __restrict__ Wt,
                            ushort_t* __restrict__ Wc) {
  int idx = b * 256 + threadIdx.x;
  const float* Ws[5] = {W0, W1, W2, W3, W4};
  int n = idx >> 7, k = idx & 127;
  Wt[idx] = bf16_1(Ws[n >> 7][(size_t)k * 128 + (n & 127)]);
  int k2 = idx >> 7, n2 = idx & 127;
  Wc[(size_t)n2 * 640 + k2] = bf16_1(Ws[k2 >> 7][(size_t)n2 * 128 + (k2 & 127)]);
}

// lean Km GEMM: stage A (32x128) in 16KB LDS, stream W from global (1 block only)
__device__ void gemm_km_lean(const float* __restrict__ A,
                             const float* __restrict__ W,
                             float* __restrict__ C) {
  __shared__ float As[32][129];
  int tid = threadIdx.x;
  for (int idx = tid; idx < 32 * 128; idx += 256) As[idx >> 7][idx & 127] = A[idx];
  __syncthreads();
  int r = tid >> 3, c0 = (tid & 7) * 16;
  float acc[16];
#pragma unroll
  for (int q = 0; q < 16; q++) acc[q] = 0.f;
  for (int k = 0; k < 128; k++) {
    float av = As[r][k];
#pragma unroll
    for (int q = 0; q < 16; q++) acc[q] = fmaf(av, W[k * 128 + c0 + q], acc[q]);
  }
#pragma unroll
  for (int q = 0; q < 16; q++) C[r * 128 + c0 + q] = acc[q];
}

// fused prep: ln_fwd | w_conv | gemm_km | params+zero-scalar | cnt zero
__global__ __launch_bounds__(256) void prep_k(const float* __restrict__ X,
                                              const float* __restrict__ ln_g,
                                              const float* __restrict__ ln_b,
                                              unsigned* __restrict__ Gb,
                                              float* __restrict__ meanv,
                                              float* __restrict__ rstdv,
                                              const float* W0, const float* W1,
                                              const float* W2, const float* W3,
                                              const float* W4,
                                              ushort_t* __restrict__ Wt,
                                              ushort_t* __restrict__ Wc,
                                              const float* __restrict__ Bm,
                                              const float* __restrict__ Wkm,
                                              float* __restrict__ Km,
                                              const float* l2, const float* l3,
                                              const float* lm, const float* b2,
                                              const float* b3, const float* bm,
                                              float* __restrict__ P,
                                              float* __restrict__ eout,
                                              int* __restrict__ cnt) {
  int bx = blockIdx.x, tid = threadIdx.x;
  if (bx < ROWB) {
    ln_fwd_body(bx, X, ln_g, ln_b, Gb, meanv, rstdv);
  } else if (bx < ROWB + WCB) {
    w_conv_body(bx - ROWB, W0, W1, W2, W3, W4, Wt, Wc);
  } else if (bx == ROWB + WCB) {
    gemm_km_lean(Bm, Wkm, Km);
  } else if (bx == ROWB + WCB + 1) {
    if (tid == 0) {
      float B2 = fminf(softplus_f(b2[0]), 5.f);
      float B3 = fminf(softplus_f(b3[0]), 5.f);
      float Bm_ = fminf(softplus_f(bm[0]), 5.f);
      float S2 = softplus_f(l2[0]);
      float S3 = softplus_f(l3[0]);
      float Sm = softplus_f(lm[0]);
      P[0] = B2; P[1] = B3; P[2] = Bm_;
      P[3] = -S2 * INV_SQRT_D; P[4] = -S3 * INV_D; P[5] = -Sm * INV_SQRT_D;
      P[6] = -S2 / B2; P[7] = -S3 / B3; P[8] = -Sm / Bm_;
    }
    if (tid == 1) eout[0] = 0.f;
  } else {
    int i = (bx - (ROWB + WCB + 2)) * 1024 + tid * 4;
    if (i + 3 < 4 * NN) {
      *(int4*)&cnt[i] = (int4){0, 0, 0, 0};
    } else {
#pragma unroll
      for (int t = 0; t < 4; t++) if (i + t < 4 * NN) cnt[i + t] = 0;
    }
  }
}

// ---------------- fwd MFMA GEMM body ----------------
__device__ void mfma_fwd_body(int bxr, int by, const ushort_t* __restrict__ Gb,
                              const ushort_t* __restrict__ Wt,
                              ushort_t* __restrict__ QK, int M) {
  __shared__ ushort_t sB[64][136];
  int tid = threadIdx.x;
  int nb = by * 64;
  for (int idx = tid; idx < 64 * 16; idx += 256) {
    int r = idx >> 4, c8 = idx & 15;
    *(bf16x8*)&sB[r][c8 * 8] = *(const bf16x8*)(Wt + (size_t)(nb + r) * 128 + c8 * 8);
  }
  __syncthreads();
  int w = tid >> 6, l = tid & 63, quad = l >> 4, j = l & 15;
  int row0 = bxr * 64 + w * 16;
  int arow = row0 + j; if (arow >= M) arow = M - 1;
  const bf16x8* ap = (const bf16x8*)(Gb + (size_t)arow * 128);
  f32x4 acc[4];
#pragma unroll
  for (int nt = 0; nt < 4; nt++) acc[nt] = (f32x4){0.f, 0.f, 0.f, 0.f};
#pragma unroll
  for (int kc = 0; kc < 4; kc++) {
    bf16x8 a = ap[kc * 4 + quad];
#pragma unroll
    for (int nt = 0; nt < 4; nt++) {
      bf16x8 b = *(const bf16x8*)&sB[nt * 16 + j][kc * 32 + quad * 8];
      acc[nt] = __builtin_amdgcn_mfma_f32_16x16x32_bf16(a, b, acc[nt], 0, 0, 0);
    }
  }
#pragma unroll
  for (int nt = 0; nt < 4; nt++)
#pragma unroll
    for (int r = 0; r < 4; r++) {
      int row = row0 + quad * 4 + r;
      if (row < M) QK[(size_t)row * 640 + nb + nt * 16 + j] = bf16_1(acc[nt][r]);
    }
}

// ---------------- edge MLP body ----------------
__device__ void edge_mlp_body(int bx, const float* __restrict__ EA,
                              const float* __restrict__ We1,
                              const float* __restrict__ be1,
                              const float* __restrict__ We2,
                              const float* __restrict__ be2,
                              float* __restrict__ a2) {
  __shared__ float sW1[16 * 128];
  __shared__ float sb1[128];
  __shared__ float sW2[128];
  int tid = threadIdx.x;
  for (int i = tid; i < 2048; i += 256) sW1[i] = We1[i];
  if (tid < 128) { sb1[tid] = be1[tid]; sW2[tid] = We2[tid]; }
  __syncthreads();
  int w = tid >> 6, l = tid & 63;
  int m = l & 15, q = l >> 4;
  union u8 { bf16x8 v; ushort_t s[8]; };
  u8 bf[8];
  float bb[8], ww[8];
#pragma unroll
  for (int nt = 0; nt < 8; nt++) {
    int n = nt * 16 + m;
#pragma unroll
    for (int j = 0; j < 8; j++) {
      int k = q * 8 + j;
      bf[nt].s[j] = (k < 16) ? bf16_1(sW1[k * 128 + n]) : (ushort_t)0;
    }
    bb[nt] = sb1[n];
    ww[nt] = sW2[n];
  }
  float be2v = be2[0];
  for (int batch = 0; batch < 4; batch++) {
    int e0 = bx * 256 + batch * 64 + w * 16;
    u8 af;
    if (q < 2) {
      const float* ep = EA + (size_t)(e0 + m) * 16 + q * 8;
      float4 v0 = *(const float4*)ep;
      float4 v1 = *(const float4*)(ep + 4);
      af.s[0] = bf16_1(v0.x); af.s[1] = bf16_1(v0.y);
      af.s[2] = bf16_1(v0.z); af.s[3] = bf16_1(v0.w);
      af.s[4] = bf16_1(v1.x); af.s[5] = bf16_1(v1.y);
      af.s[6] = bf16_1(v1.z); af.s[7] = bf16_1(v1.w);
    } else {
#pragma unroll
      for (int j = 0; j < 8; j++) af.s[j] = 0;
    }
    float s0 = 0.f, s1 = 0.f, s2 = 0.f, s3 = 0.f;
#pragma unroll
    for (int nt = 0; nt < 8; nt++) {
      float bias = bb[nt];
      f32x4 cin = (f32x4){bias, bias, bias, bias};
      f32x4 acc = __builtin_amdgcn_mfma_f32_16x16x32_bf16(af.v, bf[nt].v, cin, 0, 0, 0);
      float w2v = ww[nt];
      s0 = fmaf(gelu_fast(acc[0]), w2v, s0);
      s1 = fmaf(gelu_fast(acc[1]), w2v, s1);
      s2 = fmaf(gelu_fast(acc[2]), w2v, s2);
      s3 = fmaf(gelu_fast(acc[3]), w2v, s3);
    }
    s0 = redsum16(s0); s1 = redsum16(s1); s2 = redsum16(s2); s3 = redsum16(s3);
    if (m == 0) {
      int eb = e0 + q * 4;
      a2[eb + 0] = s0 + be2v;
      a2[eb + 1] = s1 + be2v;
      a2[eb + 2] = s2 + be2v;
      a2[eb + 3] = s3 + be2v;
    }
  }
}

// ---------------- histogram bodies (8-deep ILP, position capture) ----------------
__device__ void hist2_body(int bx, const int* __restrict__ a,
                           const int* __restrict__ b,
                           int* __restrict__ ca, int* __restrict__ cb,
                           int* __restrict__ pos_a, int* __restrict__ pos_b, int n) {
  int base = bx * 2048 + threadIdx.x;
  if (base + 1792 < n) {
    int av[8], bv[8], pa[8], pb[8];
#pragma unroll
    for (int k = 0; k < 8; k++) { int e = base + k * 256; av[k] = a[e]; bv[k] = b[e]; }
#pragma unroll
    for (int k = 0; k < 8; k++) pa[k] = atomicAdd(&ca[av[k]], 1);
#pragma unroll
    for (int k = 0; k < 8; k++) pb[k] = atomicAdd(&cb[bv[k]], 1);
#pragma unroll
    for (int k = 0; k < 8; k++) pos_a[base + k * 256] = pa[k];
#pragma unroll
    for (int k = 0; k < 8; k++) pos_b[base + k * 256] = pb[k];
  } else {
#pragma unroll
    for (int k = 0; k < 8; k++) {
      int e = base + k * 256;
      if (e < n) {
        pos_a[e] = atomicAdd(&ca[a[e]], 1);
        pos_b[e] = atomicAdd(&cb[b[e]], 1);
      }
    }
  }
}

__device__ void hist_t3_body(int bx, const int* __restrict__ c,
                             const int* __restrict__ u,
                             const int* __restrict__ v,
                             int* __restrict__ cc, int* __restrict__ cuv,
                             int* __restrict__ pos_c, int* __restrict__ pos_u,
                             int* __restrict__ pos_v, int n) {
  int base = bx * 2048 + threadIdx.x;
  if (base + 1792 < n) {
    int cv[8], uv[8], vv[8], pc[8], pu[8], pv[8];
#pragma unroll
    for (int k = 0; k < 8; k++) { int t = base + k * 256; cv[k] = c[t]; uv[k] = u[t]; vv[k] = v[t]; }
#pragma unroll
    for (int k = 0; k < 8; k++) pc[k] = atomicAdd(&cc[cv[k]], 1);
#pragma unroll
    for (int k = 0; k < 8; k++) pu[k] = atomicAdd(&cuv[uv[k]], 1);
#pragma unroll
    for (int k = 0; k < 8; k++) pv[k] = atomicAdd(&cuv[vv[k]], 1);
#pragma unroll
    for (int k = 0; k < 8; k++) pos_c[base + k * 256] = pc[k];
#pragma unroll
    for (int k = 0; k < 8; k++) pos_u[base + k * 256] = pu[k];
#pragma unroll
    for (int k = 0; k < 8; k++) pos_v[base + k * 256] = pv[k];
  } else {
#pragma unroll
    for (int k = 0; k < 8; k++) {
      int t = base + k * 256;
      if (t < n) {
        pos_c[t] = atomicAdd(&cc[c[t]], 1);
        pos_u[t] = atomicAdd(&cuv[u[t]], 1);
        pos_v[t] = atomicAdd(&cuv[v[t]], 1);
      }
    }
  }
}

// fused fwd: hist (latency) | mfma_fwd (MFMA) | edge_mlp (VALU) in one dispatch
__global__ __launch_bounds__(256) void fwd_k(const ushort_t* __restrict__ Gb,
                                             const ushort_t* __restrict__ Wt,
                                             ushort_t* __restrict__ QK,
                                             const float* __restrict__ EA,
                                             const float* __restrict__ We1,
                                             const float* __restrict__ be1,
                                             const float* __restrict__ We2,
                                             const float* __restrict__ be2,
                                             float* __restrict__ a2,
                                             const int* __restrict__ c2,
                                             const int* __restrict__ u2,
                                             const int* __restrict__ c3,
                                             const int* __restrict__ u3,
                                             const int* __restrict__ v3,
                                             int* __restrict__ cnt_c2,
                                             int* __restrict__ cnt_u2,
                                             int* __restrict__ cnt_c3,
                                             int* __restrict__ cnt_uv,
                                             int* __restrict__ pos_c2,
                                             int* __restrict__ pos_u2,
                                             int* __restrict__ pos_c3,
                                             int* __restrict__ pos_u3,
                                             int* __restrict__ pos_v3) {
  int bx = blockIdx.x;
  if (bx < HB2) {
    hist2_body(bx, c2, u2, cnt_c2, cnt_u2, pos_c2, pos_u2, EE);
  } else if (bx < HB2 + HBT) {
    hist_t3_body(bx - HB2, c3, u3, v3, cnt_c3, cnt_uv, pos_c3, pos_u3, pos_v3, TT);
  } else if (bx < HB2 + HBT + MB * 10) {
    int b = bx - HB2 - HBT;
    mfma_fwd_body(b / 10, b % 10, Gb, Wt, QK, NN);
  } else {
    edge_mlp_body(bx - HB2 - HBT - MB * 10, EA, We1, be1, We2, be2, a2);
  }
}

// ---------------- bwd MFMA GEMM: dG[M,128](bf16) = dAll[M,640](bf16) @ Wc^T ----------------
__global__ __launch_bounds__(256) void mfma_bwd(const ushort_t* __restrict__ dAll,
                                                const ushort_t* __restrict__ Wc,
                                                unsigned* __restrict__ dG, int M) {
  __shared__ ushort_t sB[64][40];
  int tid = threadIdx.x;
  int nb = blockIdx.y * 64;
  int w = tid >> 6, l = tid & 63, quad = l >> 4, j = l & 15;
  int row0 = blockIdx.x * 64 + w * 16;
  int arow = row0 + j; if (arow >= M) arow = M - 1;
  const ushort_t* arp = dAll + (size_t)arow * 640;
  f32x4 acc[4];
#pragma unroll
  for (int nt = 0; nt < 4; nt++) acc[nt] = (f32x4){0.f, 0.f, 0.f, 0.f};
  int sr = tid >> 2, sc = tid & 3;
  for (int kc = 0; kc < 20; kc++) {
    __syncthreads();
    *(bf16x8*)&sB[sr][sc * 8] = *(const bf16x8*)(Wc + (size_t)(nb + sr) * 640 + kc * 32 + sc * 8);
    __syncthreads();
    bf16x8 a = *(const bf16x8*)(arp + kc * 32 + quad * 8);
#pragma unroll
    for (int nt = 0; nt < 4; nt++) {
      bf16x8 b = *(const bf16x8*)&sB[nt * 16 + j][quad * 8];
      acc[nt] = __builtin_amdgcn_mfma_f32_16x16x32_bf16(a, b, acc[nt], 0, 0, 0);
    }
  }
#pragma unroll
  for (int nt = 0; nt < 4; nt++)
#pragma unroll
    for (int r = 0; r < 4; r++) {
      int row = row0 + quad * 4 + r;
      if (row < M) ((ushort_t*)dG)[(size_t)row * 128 + nb + nt * 16 + j] = bf16_1(acc[nt][r]);
    }
}

// ---------------- parallel 3-phase scan over 4 count arrays ----------------
__global__ __launch_bounds__(256) void scan_p1(const int* __restrict__ cnt,
                                               int* __restrict__ part) {
  int arr = blockIdx.y, b = blockIdx.x;
  const int* c = cnt + (size_t)arr * NN;
  int gi = b * SCAN_TILE + threadIdx.x * 8;
  int s = 0;
#pragma unroll
  for (int t = 0; t < 8; t++) s += (gi + t < NN) ? c[gi + t] : 0;
#pragma unroll
  for (int m = 32; m; m >>= 1) s += __shfl_xor(s, m, 64);
  __shared__ int wt[4];
  int lane = threadIdx.x & 63, wid = threadIdx.x >> 6;
  if (lane == 0) wt[wid] = s;
  __syncthreads();
  if (threadIdx.x == 0) part[arr * SCAN_NB + b] = wt[0] + wt[1] + wt[2] + wt[3];
}

__global__ __launch_bounds__(256) void scan_p2(int* __restrict__ part) {
  int w = threadIdx.x >> 6, l = threadIdx.x & 63;
  int v = (l < SCAN_NB) ? part[w * SCAN_NB + l] : 0;
  int x = v;
#pragma unroll
  for (int d = 1; d < 64; d <<= 1) {
    int y = __shfl_up(x, d, 64);
    if (l >= d) x += y;
  }
  if (l < SCAN_NB) part[w * SCAN_NB + l] = x - v;
}

__global__ __launch_bounds__(256) void scan_p3(const int* __restrict__ cnt,
                                               const int* __restrict__ part,
                                               int* __restrict__ rowptr) {
  int arr = blockIdx.y, b = blockIdx.x;
  const int* c = cnt + (size_t)arr * NN;
  int* rp = rowptr + (size_t)arr * (NN + 1);
  int tid = threadIdx.x;
  int gi = b * SCAN_TILE + tid * 8;
  int vals[8];
#pragma unroll
  for (int t = 0; t < 8; t++) vals[t] = (gi + t < NN) ? c[gi + t] : 0;
  int tsum = 0;
#pragma unroll
  for (int t = 0; t < 8; t++) tsum += vals[t];
  int lane = tid & 63, wid = tid >> 6;
  int x = tsum;
#pragma unroll
  for (int d = 1; d < 64; d <<= 1) {
    int y = __shfl_up(x, d, 64);
    if (lane >= d) x += y;
  }
  __shared__ int wt[4];
  if (lane == 63) wt[wid] = x;
  __syncthreads();
  int wadd = 0;
  for (int w = 0; w < wid; w++) wadd += wt[w];
  int running = part[arr * SCAN_NB + b] + wadd + x - tsum;
#pragma unroll
  for (int t = 0; t < 8; t++) {
    if (gi + t < NN) rp[gi + t] = running;
    running += vals[t];
  }
  if (b == SCAN_NB - 1 && tid == 255) rp[NN] = running;
}

// ---------------- atomic-free packed scatter bodies (8-deep ILP) ----------------
__device__ void scat2_body(int bx, const int* __restrict__ c2,
                           const int* __restrict__ u2,
                           const float* __restrict__ a2,
                           const int* __restrict__ posc,
                           const int* __restrict__ posu,
                           const int* __restrict__ rpc,
                           const int* __restrict__ rpu,
                           uint2* __restrict__ payc,
                           uint2* __restrict__ payu, int n) {
  int base = bx * 2048 + threadIdx.x;
  if (base + 1792 < n) {
    int c[8], u[8]; float a[8]; int pc[8], pu[8];
#pragma unroll
    for (int k = 0; k < 8; k++) {
      int e = base + k * 256;
      c[k] = c2[e]; u[k] = u2[e]; a[k] = a2[e]; pc[k] = posc[e]; pu[k] = posu[e];
    }
    int p[8], q[8];
#pragma unroll
    for (int k = 0; k < 8; k++) { p[k] = rpc[c[k]] + pc[k]; q[k] = rpu[u[k]] + pu[k]; }
#pragma unroll
    for (int k = 0; k < 8; k++) {
      uint2 t; t.x = (unsigned)u[k]; t.y = __float_as_uint(a[k]);
      payc[p[k]] = t;
    }
#pragma unroll
    for (int k = 0; k < 8; k++) {
      uint2 t; t.x = (unsigned)p[k]; t.y = (unsigned)c[k];
      payu[q[k]] = t;
    }
  } else {
#pragma unroll
    for (int k = 0; k < 8; k++) {
      int e = base + k * 256;
      if (e < n) {
        int cc = c2[e], uu = u2[e];
        int pp = rpc[cc] + posc[e];
        int qq = rpu[uu] + posu[e];
        uint2 t; t.x = (unsigned)uu; t.y = __float_as_uint(a2[e]);
        payc[pp] = t;
        uint2 t2; t2.x = (unsigned)pp; t2.y = (unsigned)cc;
        payu[qq] = t2;
      }
    }
  }
}

__device__ void scat_t3_body(int bx, const int* __restrict__ c3,
                             const int* __restrict__ u3,
                             const int* __restrict__ v3,
                             const int* __restrict__ ttau,
                             const int* __restrict__ posc,
                             const int* __restrict__ posu,
                             const int* __restrict__ posv,
                             const int* __restrict__ rpc,
                             const int* __restrict__ rpuv,
                             uint2* __restrict__ payc,
                             uint2* __restrict__ payuv, int n) {
  int base = bx * 2048 + threadIdx.x;
  if (base + 1792 < n) {
    int c[8], u[8], v[8], ta[8], p[8], q1[8], q2[8];
#pragma unroll
    for (int k = 0; k < 8; k++) {
      int t = base + k * 256;
      c[k] = c3[t]; u[k] = u3[t]; v[k] = v3[t]; ta[k] = ttau[t] & 1;
    }
#pragma unroll
    for (int k = 0; k < 8; k++) {
      int t = base + k * 256;
      p[k] = rpc[c[k]] + posc[t];
      q1[k] = rpuv[u[k]] + posu[t];
      q2[k] = rpuv[v[k]] + posv[t];
    }
#pragma unroll
    for (int k = 0; k < 8; k++) {
      uint2 a; a.x = ((unsigned)u[k] << 16) | (unsigned)v[k]; a.y = (unsigned)ta[k];
      payc[p[k]] = a;
    }
#pragma unroll
    for (int k = 0; k < 8; k++) {
      unsigned sp = ((unsigned)p[k] << 1) | (unsigned)ta[k];
      uint2 b1; b1.x = ((unsigned)v[k] << 16) | (unsigned)c[k]; b1.y = sp;
      payuv[q1[k]] = b1;
      uint2 b2; b2.x = ((unsigned)u[k] << 16) | (unsigned)c[k]; b2.y = sp;
      payuv[q2[k]] = b2;
    }
  } else {
#pragma unroll
    for (int k = 0; k < 8; k++) {
      int t = base + k * 256;
      if (t < n) {
        int c = c3[t], u = u3[t], v = v3[t], ta = ttau[t] & 1;
        int p = rpc[c] + posc[t];
        int q1 = rpuv[u] + posu[t];
        int q2 = rpuv[v] + posv[t];
        unsigned sp = ((unsigned)p << 1) | (unsigned)ta;
        uint2 a; a.x = ((unsigned)u << 16) | (unsigned)v; a.y = (unsigned)ta;
        payc[p] = a;
        uint2 b1; b1.x = ((unsigned)v << 16) | (unsigned)c; b1.y = sp;
        payuv[q1] = b1;
        uint2 b2; b2.x = ((unsigned)u << 16) | (unsigned)c; b2.y = sp;
        payuv[q2] = b2;
      }
    }
  }
}

// fused scatter (both atomic-free)
__global__ __launch_bounds__(256) void scat_k(const int* __restrict__ c2,
                                              const int* __restrict__ u2,
                                              const float* __restrict__ a2,
                                              const int* __restrict__ pos_c2,
                                              const int* __restrict__ pos_u2,
                                              const int* __restrict__ rp_c2,
                                              const int* __restrict__ rp_u2,
                                              uint2* __restrict__ payc2,
                                              uint2* __restrict__ payu2,
                                              const int* __restrict__ c3,
                                              const int* __restrict__ u3,
                                              const int* __restrict__ v3,
                                              const int* __restrict__ ttau,
                                              const int* __restrict__ pos_c3,
                                              const int* __restrict__ pos_u3,
                                              const int* __restrict__ pos_v3,
                                              const int* __restrict__ rp_c3,
                                              const int* __restrict__ rp_uv,
                                              uint2* __restrict__ payc3,
                                              uint2* __restrict__ payuv) {
  int bx = blockIdx.x;
  if (bx < HB2) {
    scat2_body(bx, c2, u2, a2, pos_c2, pos_u2, rp_c2, rp_u2, payc2, payu2, EE);
  } else {
    scat_t3_body(bx - HB2, c3, u3, v3, ttau, pos_c3, pos_u3, pos_v3,
                 rp_c3, rp_uv, payc3, payuv, TT);
  }
}

// ---------------- fused e2 fwd + dQ2 (pair-processing, 6 gathers in flight) ----------------
__device__ void e2_body(int bx, const unsigned* __restrict__ QK,
                        const float* __restrict__ P,
                        const uint2* __restrict__ pay,
                        const int* __restrict__ rp,
                        float* __restrict__ s2c,
                        float* __restrict__ L2,
                        unsigned* __restrict__ dAll) {
  int row = bx * 4 + (threadIdx.x >> 6);
  int l = threadIdx.x & 63, g = l >> 4, j = l & 15;
  float b2s = P[0] * INV_SQRT_D, cw2 = P[3];
  float q[8];
  unp8(*(const uint4*)(QK + (size_t)row * UU + j * 4), q);
  int s = rp[row], e = rp[row + 1];
  float m = -3.0e38f, z = 0.f;
  float acc[8] = {0.f, 0.f, 0.f, 0.f, 0.f, 0.f, 0.f, 0.f};
  int i0 = s + g;
  uint4 kA1 = {0,0,0,0}, kA2 = {0,0,0,0}, kB1 = {0,0,0,0}, kB2 = {0,0,0,0};
  float aA1 = 0.f, aA2 = 0.f, aB1 = 0.f, aB2 = 0.f;
  if (i0 < e)      { uint2 w = pay[i0];      aA1 = __uint_as_float(w.y); kA1 = *(const uint4*)(QK + (size_t)w.x * UU + 64 + j * 4); }
  if (i0 + 4 < e)  { uint2 w = pay[i0 + 4];  aA2 = __uint_as_float(w.y); kA2 = *(const uint4*)(QK + (size_t)w.x * UU + 64 + j * 4); }
  if (i0 + 8 < e)  { uint2 w = pay[i0 + 8];  aB1 = __uint_as_float(w.y); kB1 = *(const uint4*)(QK + (size_t)w.x * UU + 64 + j * 4); }
  if (i0 + 12 < e) { uint2 w = pay[i0 + 12]; aB2 = __uint_as_float(w.y); kB2 = *(const uint4*)(QK + (size_t)w.x * UU + 64 + j * 4); }
  for (int i = i0; i < e; i += 8) {
    uint4 kC1 = {0,0,0,0}, kC2 = {0,0,0,0}; float aC1 = 0.f, aC2 = 0.f;
    if (i + 16 < e) { uint2 w = pay[i + 16]; aC1 = __uint_as_float(w.y); kC1 = *(const uint4*)(QK + (size_t)w.x * UU + 64 + j * 4); }
    if (i + 20 < e) { uint2 w = pay[i + 20]; aC2 = __uint_as_float(w.y); kC2 = *(const uint4*)(QK + (size_t)w.x * UU + 64 + j * 4); }
    {
      float k[8]; unp8(kA1, k);
      float d = 0.f;
#pragma unroll
      for (int t = 0; t < 8; t++) d = fmaf(q[t], k[t], d);
      d = redsum16(d);
      float sv = b2s * d + aA1;
      if (j == 0) s2c[i] = sv;
      if (sv <= m) {
        float p = __expf(sv - m);
        z += p;
#pragma unroll
        for (int t = 0; t < 8; t++) acc[t] = fmaf(p, k[t], acc[t]);
      } else {
        float r = __expf(m - sv);
        z = fmaf(z, r, 1.f);
#pragma unroll
        for (int t = 0; t < 8; t++) acc[t] = fmaf(acc[t], r, k[t]);
        m = sv;
      }
    }
    if (i + 4 < e) {
      float k[8]; unp8(kA2, k);
      float d = 0.f;
#pragma unroll
      for (int t = 0; t < 8; t++) d = fmaf(q[t], k[t], d);
      d = redsum16(d);
      float sv = b2s * d + aA2;
      if (j == 0) s2c[i + 4] = sv;
      if (sv <= m) {
        float p = __expf(sv - m);
        z += p;
#pragma unroll
        for (int t = 0; t < 8; t++) acc[t] = fmaf(p, k[t], acc[t]);
      } else {
        float r = __expf(m - sv);
        z = fmaf(z, r, 1.f);
#pragma unroll
        for (int t = 0; t < 8; t++) acc[t] = fmaf(acc[t], r, k[t]);
        m = sv;
      }
    }
    kA1 = kB1; aA1 = aB1; kA2 = kB2; aA2 = aB2;
    kB1 = kC1; aB1 = aC1; kB2 = kC2; aB2 = aC2;
  }
  float mx = fmaxf(m, __shfl_xor(m, 16, 64));
  mx = fmaxf(mx, __shfl_xor(mx, 32, 64));
  float r = (z > 0.f) ? __expf(m - mx) : 0.f;
  float zz = z * r;
  zz += __shfl_xor(zz, 16, 64);
  zz += __shfl_xor(zz, 32, 64);
#pragma unroll
  for (int t = 0; t < 8; t++) {
    float v = acc[t] * r;
    v += __shfl_xor(v, 16, 64);
    v += __shfl_xor(v, 32, 64);
    acc[t] = v;
  }
  if (l == 0) L2[row] = (zz > 0.f) ? (mx + __logf(zz)) : 0.f;
  if (g == 0) {
    float coef = (zz > 0.f) ? cw2 / zz : 0.f;
    float o[8];
#pragma unroll
    for (int t = 0; t < 8; t++) o[t] = coef * acc[t];
    *(uint4*)(dAll + (size_t)row * UU + 0 + j * 4) = pk8(o);
  }
}

// ---------------- fused t3 fwd + dQ3 (3-deep pipeline; padded T in LDS) ----------------
__device__ void t3_body(int bx, const unsigned* __restrict__ QK,
                        const float* __restrict__ P,
                        const uint2* __restrict__ pay,
                        const int* __restrict__ rp,
                        float* __restrict__ s3c,
                        float* __restrict__ L3,
                        unsigned* __restrict__ dAll,
                        const float* __restrict__ sT) {
  int tid = threadIdx.x;
  int row = bx * 4 + (tid >> 6);
  int l = tid & 63, g = l >> 4, j = l & 15;
  float b3s = P[1] * INV_D, cw3 = P[4];
  float q[8];
  unp8(*(const uint4*)(QK + (size_t)row * UU + 128 + j * 4), q);
  int s = rp[row], e = rp[row + 1];
  float m = -3.0e38f, z = 0.f;
  float acc[8] = {0.f, 0.f, 0.f, 0.f, 0.f, 0.f, 0.f, 0.f};
  int i0 = s + g;
  uint4 kuA = {0,0,0,0}, kvA = {0,0,0,0};
  uint4 kuB = {0,0,0,0}, kvB = {0,0,0,0};
  int taA = 0, taB = 0;
  if (i0 < e) {
    uint2 w = pay[i0]; int u = w.x >> 16, v = w.x & 0xffff; taA = (int)w.y;
    kuA = *(const uint4*)(QK + (size_t)u * UU + 192 + j * 4);
    kvA = *(const uint4*)(QK + (size_t)v * UU + 192 + j * 4);
  }
  if (i0 + 4 < e) {
    uint2 w = pay[i0 + 4]; int u = w.x >> 16, v = w.x & 0xffff; taB = (int)w.y;
    kuB = *(const uint4*)(QK + (size_t)u * UU + 192 + j * 4);
    kvB = *(const uint4*)(QK + (size_t)v * UU + 192 + j * 4);
  }
  for (int i = i0; i < e; i += 4) {
    uint4 kuC = {0,0,0,0}, kvC = {0,0,0,0}; int taC = 0;
    if (i + 8 < e) {
      uint2 w = pay[i + 8]; int u = w.x >> 16, v = w.x & 0xffff; taC = (int)w.y;
      kuC = *(const uint4*)(QK + (size_t)u * UU + 192 + j * 4);
      kvC = *(const uint4*)(QK + (size_t)v * UU + 192 + j * 4);
    }
    float ku[8], kv[8]; unp8(kuA, ku); unp8(kvA, kv);
    const float* tv = &sT[taA * 144 + j * 9];
    float et[8], d = 0.f;
#pragma unroll
    for (int t = 0; t < 8; t++) { et[t] = ku[t] * kv[t] * tv[t]; d = fmaf(q[t], et[t], d); }
    d = redsum16(d);
    float sv = b3s * d;
    if (j == 0) s3c[i] = sv;
    if (sv <= m) {
      float p = __expf(sv - m);
      z += p;
#pragma unroll
      for (int t = 0; t < 8; t++) acc[t] = fmaf(p, et[t], acc[t]);
    } else {
      float r = __expf(m - sv);
      z = fmaf(z, r, 1.f);
#pragma unroll
      for (int t = 0; t < 8; t++) acc[t] = fmaf(acc[t], r, et[t]);
      m = sv;
    }
    kuA = kuB; kvA = kvB; taA = taB;
    kuB = kuC; kvB = kvC; taB = taC;
  }
  float mx = fmaxf(m, __shfl_xor(m, 16, 64));
  mx = fmaxf(mx, __shfl_xor(mx, 32, 64));
  float r = (z > 0.f) ? __expf(m - mx) : 0.f;
  float zz = z * r;
  zz += __shfl_xor(zz, 16, 64);
  zz += __shfl_xor(zz, 32, 64);
#pragma unroll
  for (int t = 0; t < 8; t++) {
    float v = acc[t] * r;
    v += __shfl_xor(v, 16, 64);
    v += __shfl_xor(v, 32, 64);
    acc[t] = v;
  }
  if (l == 0) L3[row] = (zz > 0.f) ? (mx + __logf(zz)) : 0.f;
  if (g == 0) {
    float coef = (zz > 0.f) ? cw3 / zz : 0.f;
    float o[8];
#pragma unroll
    for (int t = 0; t < 8; t++) o[t] = coef * acc[t];
    *(uint4*)(dAll + (size_t)row * UU + 128 + j * 4) = pk8(o);
  }
}

// ---------------- memory-bank energy (padded Km in LDS) ----------------
__device__ void em_body(int bx, const unsigned* __restrict__ QK,
                        const float* __restrict__ P,
                        unsigned* __restrict__ dAll,
                        float* __restrict__ Lm,
                        const float* __restrict__ sKm) {
  int tid = threadIdx.x;
  int row = bx * 4 + (tid >> 6);
  int l = tid & 63, g = l >> 4, j = l & 15;
  float bms = P[2] * INV_SQRT_D, cwm = P[5];
  float q[8];
  unp8(*(const uint4*)(QK + (size_t)row * UU + 256 + j * 4), q);
  float dk[8];
#pragma unroll
  for (int kk = 0; kk < 8; kk++) {
    int k = g * 8 + kk;
    const float* kr = &sKm[k * 144 + j * 9];
    float d = 0.f;
#pragma unroll
    for (int t = 0; t < 8; t++) d = fmaf(q[t], kr[t], d);
    dk[kk] = redsum16(d) * bms;
  }
  float m = dk[0];
#pragma unroll
  for (int kk = 1; kk < 8; kk++) m = fmaxf(m, dk[kk]);
  float mx = fmaxf(m, __shfl_xor(m, 16, 64));
  mx = fmaxf(mx, __shfl_xor(mx, 32, 64));
  float p[8], z = 0.f;
#pragma unroll
  for (int kk = 0; kk < 8; kk++) { p[kk] = __expf(dk[kk] - mx); z += p[kk]; }
  float zz = z;
  zz += __shfl_xor(zz, 16, 64);
  zz += __shfl_xor(zz, 32, 64);
  if (l == 0) Lm[row] = mx + __logf(zz);
  float coef = cwm / zz;
  float acc[8] = {0.f, 0.f, 0.f, 0.f, 0.f, 0.f, 0.f, 0.f};
#pragma unroll
  for (int kk = 0; kk < 8; kk++) {
    int k = g * 8 + kk;
    const float* kr = &sKm[k * 144 + j * 9];
    float pc_ = p[kk] * coef;
#pragma unroll
    for (int t = 0; t < 8; t++) acc[t] = fmaf(pc_, kr[t], acc[t]);
  }
#pragma unroll
  for (int t = 0; t < 8; t++) {
    float v = acc[t];
    v += __shfl_xor(v, 16, 64);
    v += __shfl_xor(v, 32, 64);
    acc[t] = v;
  }
  if (g == 0) *(uint4*)(dAll + (size_t)row * UU + 256 + j * 4) = pk8(acc);
}

// fused phase2: e2 | t3 | em, block-interleaved to smooth tails
__global__ __launch_bounds__(256) void phase2_k(const unsigned* __restrict__ QK,
                                                const float* __restrict__ Tt,
                                                const float* __restrict__ Km,
                                                const float* __restrict__ P,
                                                const uint2* __restrict__ payc2,
                                                const int* __restrict__ rp_c2,
                                                const uint2* __restrict__ payc3,
                                                const int* __restrict__ rp_c3,
                                                float* __restrict__ s2c,
                                                float* __restrict__ L2,
                                                float* __restrict__ s3c,
                                                float* __restrict__ L3,
                                                float* __restrict__ Lm,
                                                unsigned* __restrict__ dAll) {
  __shared__ float smem[32 * 144];
  int bx = blockIdx.x;
  int body = bx % 3, b = bx / 3;
  int tid = threadIdx.x;
  if (body == 0) {
    e2_body(b, QK, P, payc2, rp_c2, s2c, L2, dAll);
  } else if (body == 1) {
    {
      int ta = tid >> 7, d = tid & 127;
      smem[ta * 144 + (d >> 3) * 9 + (d & 7)] = Tt[tid];
    }
    __syncthreads();
    t3_body(b, QK, P, payc3, rp_c3, s3c, L3, dAll, smem);
  } else {
    for (int i = tid; i < KM * DD; i += 256) {
      int k = i >> 7, d = i & 127;
      smem[k * 144 + (d >> 3) * 9 + (d & 7)] = Km[i];
    }
    __syncthreads();
    em_body(b, QK, P, dAll, Lm, smem);
  }
}

// ---------------- dK2 gather (pair-processing, 6 gathers in flight) ----------------
__device__ void dk2_body(int bx, const unsigned* __restrict__ QK,
                         const float* __restrict__ s2c,
                         const float* __restrict__ L2,
                         const float* __restrict__ P,
                         const uint2* __restrict__ pay,
                         const int* __restrict__ rp,
                         unsigned* __restrict__ dAll) {
  int row = bx * 4 + (threadIdx.x >> 6);
  int l = threadIdx.x & 63, g = l >> 4, j = l & 15;
  float cw2 = P[3];
  int s = rp[row], e = rp[row + 1];
  float acc[8] = {0.f, 0.f, 0.f, 0.f, 0.f, 0.f, 0.f, 0.f};
  int i0 = s + g;
  uint4 qA1 = {0,0,0,0}, qA2 = {0,0,0,0}, qB1 = {0,0,0,0}, qB2 = {0,0,0,0};
  float scA1 = 0.f, lcA1 = 0.f, scA2 = 0.f, lcA2 = 0.f;
  float scB1 = 0.f, lcB1 = 0.f, scB2 = 0.f, lcB2 = 0.f;
  if (i0 < e)      { uint2 w = pay[i0];      scA1 = s2c[w.x]; lcA1 = L2[w.y]; qA1 = *(const uint4*)(QK + (size_t)w.y * UU + 0 + j * 4); }
  if (i0 + 4 < e)  { uint2 w = pay[i0 + 4];  scA2 = s2c[w.x]; lcA2 = L2[w.y]; qA2 = *(const uint4*)(QK + (size_t)w.y * UU + 0 + j * 4); }
  if (i0 + 8 < e)  { uint2 w = pay[i0 + 8];  scB1 = s2c[w.x]; lcB1 = L2[w.y]; qB1 = *(const uint4*)(QK + (size_t)w.y * UU + 0 + j * 4); }
  if (i0 + 12 < e) { uint2 w = pay[i0 + 12]; scB2 = s2c[w.x]; lcB2 = L2[w.y]; qB2 = *(const uint4*)(QK + (size_t)w.y * UU + 0 + j * 4); }
  for (int i = i0; i < e; i += 8) {
    uint4 qC1 = {0,0,0,0}, qC2 = {0,0,0,0};
    float scC1 = 0.f, lcC1 = 0.f, scC2 = 0.f, lcC2 = 0.f;
    if (i + 16 < e) { uint2 w = pay[i + 16]; scC1 = s2c[w.x]; lcC1 = L2[w.y]; qC1 = *(const uint4*)(QK + (size_t)w.y * UU + 0 + j * 4); }
    if (i + 20 < e) { uint2 w = pay[i + 20]; scC2 = s2c[w.x]; lcC2 = L2[w.y]; qC2 = *(const uint4*)(QK + (size_t)w.y * UU + 0 + j * 4); }
    {
      float w1 = cw2 * __expf(scA1 - lcA1);
      float qv[8]; unp8(qA1, qv);
#pragma unroll
      for (int t = 0; t < 8; t++) acc[t] = fmaf(w1, qv[t], acc[t]);
    }
    if (i + 4 < e) {
      float w2 = cw2 * __expf(scA2 - lcA2);
      float qv[8]; unp8(qA2, qv);
#pragma unroll
      for (int t = 0; t < 8; t++) acc[t] = fmaf(w2, qv[t], acc[t]);
    }
    qA1 = qB1; scA1 = scB1; lcA1 = lcB1; qA2 = qB2; scA2 = scB2; lcA2 = lcB2;
    qB1 = qC1; scB1 = scC1; lcB1 = lcC1; qB2 = qC2; scB2 = scC2; lcB2 = lcC2;
  }
#pragma unroll
  for (int t = 0; t < 8; t++) {
    float v = acc[t];
    v += __shfl_xor(v, 16, 64);
    v += __shfl_xor(v, 32, 64);
    acc[t] = v;
  }
  if (g == 0) *(uint4*)(dAll + (size_t)row * UU + 64 + j * 4) = pk8(acc);
}

// ---------------- dK3 gather (3-deep pipeline; padded T in LDS) ----------------
__device__ void dk3_body(int bx, const unsigned* __restrict__ QK,
                         const float* __restrict__ s3c,
                         const float* __restrict__ L3,
                         const float* __restrict__ P,
                         const uint2* __restrict__ pay,
                         const int* __restrict__ rp,
                         unsigned* __restrict__ dAll,
                         const float* __restrict__ sT) {
  int tid = threadIdx.x;
  int row = bx * 4 + (tid >> 6);
  int l = tid & 63, g = l >> 4, j = l & 15;
  float cw3 = P[4];
  int s = rp[row], e = rp[row + 1];
  float acc[8] = {0.f, 0.f, 0.f, 0.f, 0.f, 0.f, 0.f, 0.f};
  int i0 = s + g;
  uint4 qA = {0,0,0,0}, kA = {0,0,0,0};
  uint4 qB = {0,0,0,0}, kB = {0,0,0,0};
  int taA = 0, taB = 0;
  float scA = 0.f, lcA = 0.f, scB = 0.f, lcB = 0.f;
  if (i0 < e) {
    uint2 w = pay[i0]; int o = w.x >> 16, c = w.x & 0xffff; unsigned sp = w.y;
    taA = (int)(sp & 1); scA = s3c[sp >> 1]; lcA = L3[c];
    qA = *(const uint4*)(QK + (size_t)c * UU + 128 + j * 4);
    kA = *(const uint4*)(QK + (size_t)o * UU + 192 + j * 4);
  }
  if (i0 + 4 < e) {
    uint2 w = pay[i0 + 4]; int o = w.x >> 16, c = w.x & 0xffff; unsigned sp = w.y;
    taB = (int)(sp & 1); scB = s3c[sp >> 1]; lcB = L3[c];
    qB = *(const uint4*)(QK + (size_t)c * UU + 128 + j * 4);
    kB = *(const uint4*)(QK + (size_t)o * UU + 192 + j * 4);
  }
  for (int i = i0; i < e; i += 4) {
    uint4 qC = {0,0,0,0}, kC = {0,0,0,0}; int taC = 0;
    float scC = 0.f, lcC = 0.f;
    if (i + 8 < e) {
      uint2 w = pay[i + 8]; int o = w.x >> 16, c = w.x & 0xffff; unsigned sp = w.y;
      taC = (int)(sp & 1); scC = s3c[sp >> 1]; lcC = L3[c];
      qC = *(const uint4*)(QK + (size_t)c * UU + 128 + j * 4);
      kC = *(const uint4*)(QK + (size_t)o * UU + 192 + j * 4);
    }
    float w = cw3 * __expf(scA - lcA);
    float qv[8], ko[8]; unp8(qA, qv); unp8(kA, ko);
    const float* tv = &sT[taA * 144 + j * 9];
#pragma unroll
    for (int t = 0; t < 8; t++) acc[t] = fmaf(w * tv[t], qv[t] * ko[t], acc[t]);
    qA = qB; kA = kB; taA = taB; scA = scB; lcA = lcB;
    qB = qC; kB = kC; taB = taC; scB = scC; lcB = lcC;
  }
#pragma unroll
  for (int t = 0; t < 8; t++) {
    float v = acc[t];
    v += __shfl_xor(v, 16, 64);
    v += __shfl_xor(v, 32, 64);
    acc[t] = v;
  }
  if (g == 0) *(uint4*)(dAll + (size_t)row * UU + 192 + j * 4) = pk8(acc);
}

// fused phase3: dk2 | dk3, block-interleaved
__global__ __launch_bounds__(256) void phase3_k(const unsigned* __restrict__ QK,
                                                const float* __restrict__ Tt,
                                                const float* __restrict__ P,
                                                const float* __restrict__ s2c,
                                                const float* __restrict__ L2,
                                                const uint2* __restrict__ payu2,
                                                const int* __restrict__ rp_u2,
                                                const float* __restrict__ s3c,
                                                const float* __restrict__ L3,
                                                const uint2* __restrict__ payuv,
                                                const int* __restrict__ rp_uv,
                                                unsigned* __restrict__ dAll) {
  __shared__ float smem[2 * 144];
  int bx = blockIdx.x;
  int body = bx & 1, b = bx >> 1;
  int tid = threadIdx.x;
  if (body == 0) {
    dk2_body(b, QK, s2c, L2, P, payu2, rp_u2, dAll);
  } else {
    {
      int ta = tid >> 7, d = tid & 127;
      smem[ta * 144 + (d >> 3) * 9 + (d & 7)] = Tt[tid];
    }
    __syncthreads();
    dk3_body(b, QK, s3c, L3, P, payuv, rp_uv, dAll, smem);
  }
}

// ---------------- LN backward body ----------------
__device__ void ln_bwd_body(int bx, const float* __restrict__ X,
                            const unsigned* __restrict__ dG,
                            const float* __restrict__ gamma,
                            const float* __restrict__ meanv,
                            const float* __restrict__ rstdv,
                            float* __restrict__ out) {
  int row = bx * 4 + (threadIdx.x >> 6);
  if (row >= NN) return;
  int l = threadIdx.x & 63;
  float mu = meanv[row], rstd = rstdv[row];
  float2 x2 = *(const float2*)(X + row * DD + 2 * l);
  unsigned gw = dG[(size_t)row * 64 + l];
  float2 ga = *(const float2*)(gamma + 2 * l);
  float xh0 = (x2.x - mu) * rstd, xh1 = (x2.y - mu) * rstd;
  float dh0 = blo(gw) * ga.x, dh1 = bhi(gw) * ga.y;
  float sa = wredsum(dh0 + dh1) * (1.f / DD);
  float sb = wredsum(dh0 * xh0 + dh1 * xh1) * (1.f / DD);
  float dx0 = rstd * (dh0 - sa - xh0 * sb);
  float dx1 = rstd * (dh1 - sa - xh1 * sb);
  float gn = fmaxf(sqrtf(wredsum(dx0 * dx0 + dx1 * dx1)), 1e-6f);
  float sc = fminf(1.f / gn, 1.f);
  dx0 *= sc; dx1 *= sc;
  float xn0 = x2.x - 0.1f * 0.9999f * dx0;
  float xn1 = x2.y - 0.1f * 0.9999f * dx1;
  float sn = fmaxf(sqrtf(wredsum(xn0 * xn0 + xn1 * xn1)), 1e-6f);
  float sc2 = fminf(10.f / sn, 1.f);
  float2 o; o.x = xn0 * sc2; o.y = xn1 * sc2;
  *(float2*)(out + row * DD + 2 * l) = o;
}

// ---------------- final energy scalar body ----------------
__device__ void eval_write_body(int bx, const float* __restrict__ L2,
                                const float* __restrict__ L3,
                                const float* __restrict__ Lm,
                                const float* __restrict__ P,
                                float* __restrict__ out) {
  int i = bx * 256 + threadIdx.x;
  float a2 = 0.f, a3 = 0.f, am = 0.f;
  if (i < NN) { a2 = L2[i]; a3 = L3[i]; am = Lm[i]; }
  a2 = wredsum(a2); a3 = wredsum(a3); am = wredsum(am);
  __shared__ float r2[4], r3[4], rm[4];
  int wv = threadIdx.x >> 6, l = threadIdx.x & 63;
  if (l == 0) { r2[wv] = a2; r3[wv] = a3; rm[wv] = am; }
  __syncthreads();
  if (threadIdx.x == 0) {
    float S2 = r2[0] + r2[1] + r2[2] + r2[3];
    float S3 = r3[0] + r3[1] + r3[2] + r3[3];
    float Sm = rm[0] + rm[1] + rm[2] + rm[3];
    atomicAdd(out, P[6] * S2 + P[7] * S3 + P[8] * Sm);
  }
}

// fused finish: ln_bwd | eval_write
__global__ __launch_bounds__(256) void fin_k(const float* __restrict__ X,
                                             const unsigned* __restrict__ dG,
                                             const float* __restrict__ gamma,
                                             const float* __restrict__ meanv,
                                             const float* __restrict__ rstdv,
                                             float* __restrict__ out,
                                             const float* __restrict__ L2,
                                             const float* __restrict__ L3,
                                             const float* __restrict__ Lm,
                                             const float* __restrict__ P,
                                             float* __restrict__ eout) {
  int bx = blockIdx.x;
  if (bx < ROWB) ln_bwd_body(bx, X, dG, gamma, meanv, rstdv, out);
  else eval_write_body(bx - ROWB, L2, L3, Lm, P, eout);
}

extern "C" void kernel_launch(void* const* d_in, const int* in_sizes, int n_in,
                              void* d_out, int out_size, void* d_ws, size_t ws_size,
                              hipStream_t stream) {
  (void)in_sizes; (void)n_in; (void)out_size;
  const float* X = (const float*)d_in[0];
  const float* EA = (const float*)d_in[1];
  const float* ln_g = (const float*)d_in[2];
  const float* ln_b = (const float*)d_in[3];
  const float* W_Q2 = (const float*)d_in[4];
  const float* W_K2 = (const float*)d_in[5];
  const float* W_Q3 = (const float*)d_in[6];
  const float* W_K3 = (const float*)d_in[7];
  const float* T_tau = (const float*)d_in[8];
  const float* W_Qm = (const float*)d_in[9];
  const float* W_Km = (const float*)d_in[10];
  const float* B_mem = (const float*)d_in[11];
  const float* We1 = (const float*)d_in[12];
  const float* be1 = (const float*)d_in[13];
  const float* We2 = (const float*)d_in[14];
  const float* be2 = (const float*)d_in[15];
  const float* l2s = (const float*)d_in[16];
  const float* l3s = (const float*)d_in[17];
  const float* lms = (const float*)d_in[18];
  const float* b2s = (const float*)d_in[19];
  const float* b3s = (const float*)d_in[20];
  const float* bms = (const float*)d_in[21];
  const int* c2 = (const int*)d_in[22];
  const int* u2 = (const int*)d_in[23];
  const int* c3 = (const int*)d_in[24];
  const int* u3 = (const int*)d_in[25];
  const int* v3 = (const int*)d_in[26];
  const int* ttau = (const int*)d_in[27];
  float* out = (float*)d_out;

  float* ws = (float*)d_ws;
  size_t off = 0;
  auto alloc = [&](size_t n) { float* p = ws + off; off += n; return p; };
  const size_t ND = (size_t)NN * DD;
  unsigned* Gb = (unsigned*)alloc(ND / 2);
  unsigned* QKall = (unsigned*)alloc((size_t)NN * UU);
  unsigned* dAll = (unsigned*)alloc((size_t)NN * UU);
  unsigned* dG = (unsigned*)alloc(ND / 2);
  ushort_t* Wt5 = (ushort_t*)alloc(640 * 128 / 2);
  ushort_t* Wcat = (ushort_t*)alloc(640 * 128 / 2);
  float* Km = alloc((size_t)KM * DD);
  float* a2 = alloc(EE);
  float* s2c = alloc(EE);
  float* s3c = alloc(TT);
  float* meanv = alloc(NN);
  float* rstdv = alloc(NN);
  float* L2 = alloc(NN);
  float* L3 = alloc(NN);
  float* Lm = alloc(NN);
  float* Pparams = alloc(16);
  int* cnt = (int*)alloc(4 * (size_t)NN);
  int* rowptr = (int*)alloc(4 * (size_t)(NN + 1));
  int* spart = (int*)alloc(4 * SCAN_NB);
  int* pos_c2 = (int*)alloc(EE);
  int* pos_u2 = (int*)alloc(EE);
  int* pos_c3 = (int*)alloc(TT);
  int* pos_u3 = (int*)alloc(TT);
  int* pos_v3 = (int*)alloc(TT);
  uint2* payc2 = (uint2*)alloc(2 * (size_t)EE);
  uint2* payu2 = (uint2*)alloc(2 * (size_t)EE);
  uint2* payc3 = (uint2*)alloc(2 * (size_t)TT);
  uint2* payuv = (uint2*)alloc(4 * (size_t)TT);
  if (off * sizeof(float) > ws_size) return;

  int* cnt_c2 = cnt, *cnt_u2 = cnt + NN, *cnt_c3 = cnt + 2 * NN, *cnt_uv = cnt + 3 * NN;
  int* rp_c2 = rowptr, *rp_u2 = rowptr + (NN + 1), *rp_c3 = rowptr + 2 * (NN + 1), *rp_uv = rowptr + 3 * (NN + 1);

  prep_k<<<ROWB + WCB + 2 + ZCB, 256, 0, stream>>>(
      X, ln_g, ln_b, Gb, meanv, rstdv,
      W_Q2, W_K2, W_Q3, W_K3, W_Qm, Wt5, Wcat,
      B_mem, W_Km, Km,
      l2s, l3s, lms, b2s, b3s, bms, Pparams, out + ND, cnt);

  fwd_k<<<HB2 + HBT + MB * 10 + EDGE_BLKS, 256, 0, stream>>>(
      (const ushort_t*)Gb, Wt5, (ushort_t*)QKall,
      EA, We1, be1, We2, be2, a2,
      c2, u2, c3, u3, v3,
      cnt_c2, cnt_u2, cnt_c3, cnt_uv,
      pos_c2, pos_u2, pos_c3, pos_u3, pos_v3);

  scan_p1<<<dim3(SCAN_NB, 4), 256, 0, stream>>>(cnt, spart);
  scan_p2<<<1, 256, 0, stream>>>(spart);
  scan_p3<<<dim3(SCAN_NB, 4), 256, 0, stream>>>(cnt, spart, rowptr);

  scat_k<<<HB2 + HBT, 256, 0, stream>>>(
      c2, u2, a2, pos_c2, pos_u2, rp_c2, rp_u2, payc2, payu2,
      c3, u3, v3, ttau, pos_c3, pos_u3, pos_v3, rp_c3, rp_uv, payc3, payuv);

  phase2_k<<<3 * ROWB, 256, 0, stream>>>(QKall, T_tau, Km, Pparams,
                                         payc2, rp_c2, payc3, rp_c3,
                                         s2c, L2, s3c, L3, Lm, dAll);
  phase3_k<<<2 * ROWB, 256, 0, stream>>>(QKall, T_tau, Pparams,
                                         s2c, L2, payu2, rp_u2,
                                         s3c, L3, payuv, rp_uv, dAll);

  mfma_bwd<<<dim3(MB, 2), 256, 0, stream>>>((const ushort_t*)dAll, Wcat, dG, NN);

  fin_k<<<ROWB + 196, 256, 0, stream>>>(X, dG, ln_g, meanv, rstdv, out,
                                        L2, L3, Lm, Pparams, out + ND);
}

// Round 8
// 723.263 us; speedup vs baseline: 1.3127x; 1.0580x over previous
//
#include <hip/hip_runtime.h>

#define NN 50000
#define DD 128
#define EE 800000
#define TT 400000
#define KM 32
#define UU 320  // uints per 640-col bf16 row
#define ROWB 12500           // NN/4
#define MB 782               // ceil(NN/64)
#define EDGE_BLKS 3125       // EE/256
#define HB2 391              // ceil(EE/2048)
#define HBT 196              // ceil(TT/2048)
#define WCB 320
#define ZCB 196              // cnt zero blocks
#define FWD_TOT 11532        // HB2+HBT+MB*10+EDGE_BLKS
#define SCAN_TILE 2048
#define SCAN_NB ((NN + SCAN_TILE - 1) / SCAN_TILE)  // 25

static constexpr float INV_SQRT_D = 0.08838834764831845f; // 1/sqrt(128)
static constexpr float INV_D = 1.f / 128.f;

typedef __attribute__((ext_vector_type(8))) short bf16x8;
typedef __attribute__((ext_vector_type(4))) float f32x4;
typedef unsigned short ushort_t;

__device__ __forceinline__ float softplus_f(float x) {
  return (x > 20.f) ? x : log1pf(__expf(x));
}

// exact rewrite of tanh-gelu: 0.5x(1+tanh(z)) == x * sigmoid(2z)
__device__ __forceinline__ float gelu_fast(float x) {
  float p = fmaf(0.044715f * x * x, x, x);
  float e = __expf(-1.5957691216057308f * p);
  return x * __builtin_amdgcn_rcpf(1.f + e);
}

__device__ __forceinline__ float wredsum(float v) {
#pragma unroll
  for (int m = 32; m; m >>= 1) v += __shfl_xor(v, m, 64);
  return v;
}

__device__ __forceinline__ float redsum16(float v) {
#pragma unroll
  for (int m = 1; m < 16; m <<= 1) v += __shfl_xor(v, m, 64);
  return v;
}

__device__ __forceinline__ float blo(unsigned w) { return __uint_as_float(w << 16); }
__device__ __forceinline__ float bhi(unsigned w) { return __uint_as_float(w & 0xffff0000u); }
__device__ __forceinline__ unsigned pack_bf16(float a, float b) {
  unsigned ua = __float_as_uint(a); ua += 0x7fff + ((ua >> 16) & 1);
  unsigned ub = __float_as_uint(b); ub += 0x7fff + ((ub >> 16) & 1);
  return (ua >> 16) | (ub & 0xffff0000u);
}
__device__ __forceinline__ ushort_t bf16_1(float x) {
  unsigned u = __float_as_uint(x); u += 0x7fff + ((u >> 16) & 1);
  return (ushort_t)(u >> 16);
}
__device__ __forceinline__ void unp8(uint4 w, float* f) {
  f[0] = blo(w.x); f[1] = bhi(w.x); f[2] = blo(w.y); f[3] = bhi(w.y);
  f[4] = blo(w.z); f[5] = bhi(w.z); f[6] = blo(w.w); f[7] = bhi(w.w);
}
__device__ __forceinline__ uint4 pk8(const float* f) {
  uint4 r;
  r.x = pack_bf16(f[0], f[1]); r.y = pack_bf16(f[2], f[3]);
  r.z = pack_bf16(f[4], f[5]); r.w = pack_bf16(f[6], f[7]);
  return r;
}

// ---------------- prep bodies ----------------
__device__ void ln_fwd_body(int bx, const float* __restrict__ X,
                            const float* __restrict__ gamma,
                            const float* __restrict__ beta,
                            unsigned* __restrict__ Gb,
                            float* __restrict__ meanv,
                            float* __restrict__ rstdv) {
  int row = bx * 4 + (threadIdx.x >> 6);
  if (row >= NN) return;
  int l = threadIdx.x & 63;
  float2 x2 = *(const float2*)(X + row * DD + 2 * l);
  float mu = wredsum(x2.x + x2.y) * (1.f / DD);
  float d0 = x2.x - mu, d1 = x2.y - mu;
  float var = wredsum(d0 * d0 + d1 * d1) * (1.f / DD);
  float rstd = rsqrtf(var + 1e-5f);
  float2 g2 = *(const float2*)(gamma + 2 * l);
  float2 b2 = *(const float2*)(beta + 2 * l);
  float o0 = d0 * rstd * g2.x + b2.x;
  float o1 = d1 * rstd * g2.y + b2.y;
  Gb[(size_t)row * 64 + l] = pack_bf16(o0, o1);
  if (l == 0) { meanv[row] = mu; rstdv[row] = rstd; }
}

__device__ void w_conv_body(int b, const float* W0, const float* W1, const float* W2,
                            const float* W3, const float* W4,
                            ushort_t* __restrict__ Wt,
                            ushort_t* __restrict__ Wc) {
  int idx = b * 256 + threadIdx.x;
  const float* Ws[5] = {W0, W1, W2, W3, W4};
  int n = idx >> 7, k = idx & 127;
  Wt[idx] = bf16_1(Ws[n >> 7][(size_t)k * 128 + (n & 127)]);
  int k2 = idx >> 7, n2 = idx & 127;
  Wc[(size_t)n2 * 640 + k2] = bf16_1(Ws[k2 >> 7][(size_t)n2 * 128 + (k2 & 127)]);
}

// lean Km GEMM: stage A (32x128) in LDS, stream W from global (1 block only)
__device__ void gemm_km_lean(const float* __restrict__ A,
                             const float* __restrict__ W,
                             float* __restrict__ C) {
  __shared__ float As[32][129];
  int tid = threadIdx.x;
  for (int idx = tid; idx < 32 * 128; idx += 256) As[idx >> 7][idx & 127] = A[idx];
  __syncthreads();
  int r = tid >> 3, c0 = (tid & 7) * 16;
  float acc[16];
#pragma unroll
  for (int q = 0; q < 16; q++) acc[q] = 0.f;
  for (int k = 0; k < 128; k++) {
    float av = As[r][k];
#pragma unroll
    for (int q = 0; q < 16; q++) acc[q] = fmaf(av, W[k * 128 + c0 + q], acc[q]);
  }
#pragma unroll
  for (int q = 0; q < 16; q++) C[r * 128 + c0 + q] = acc[q];
}

// fused prep: ln_fwd | w_conv | gemm_km | params+zero-scalar | cnt zero
__global__ __launch_bounds__(256) void prep_k(const float* __restrict__ X,
                                              const float* __restrict__ ln_g,
                                              const float* __restrict__ ln_b,
                                              unsigned* __restrict__ Gb,
                                              float* __restrict__ meanv,
                                              float* __restrict__ rstdv,
                                              const float* W0, const float* W1,
                                              const float* W2, const float* W3,
                                              const float* W4,
                                              ushort_t* __restrict__ Wt,
                                              ushort_t* __restrict__ Wc,
                                              const float* __restrict__ Bm,
                                              const float* __restrict__ Wkm,
                                              float* __restrict__ Km,
                                              const float* l2, const float* l3,
                                              const float* lm, const float* b2,
                                              const float* b3, const float* bm,
                                              float* __restrict__ P,
                                              float* __restrict__ eout,
                                              int* __restrict__ cnt) {
  int bx = blockIdx.x, tid = threadIdx.x;
  if (bx < ROWB) {
    ln_fwd_body(bx, X, ln_g, ln_b, Gb, meanv, rstdv);
  } else if (bx < ROWB + WCB) {
    w_conv_body(bx - ROWB, W0, W1, W2, W3, W4, Wt, Wc);
  } else if (bx == ROWB + WCB) {
    gemm_km_lean(Bm, Wkm, Km);
  } else if (bx == ROWB + WCB + 1) {
    if (tid == 0) {
      float B2 = fminf(softplus_f(b2[0]), 5.f);
      float B3 = fminf(softplus_f(b3[0]), 5.f);
      float Bm_ = fminf(softplus_f(bm[0]), 5.f);
      float S2 = softplus_f(l2[0]);
      float S3 = softplus_f(l3[0]);
      float Sm = softplus_f(lm[0]);
      P[0] = B2; P[1] = B3; P[2] = Bm_;
      P[3] = -S2 * INV_SQRT_D; P[4] = -S3 * INV_D; P[5] = -Sm * INV_SQRT_D;
      P[6] = -S2 / B2; P[7] = -S3 / B3; P[8] = -Sm / Bm_;
    }
    if (tid == 1) eout[0] = 0.f;
  } else {
    int i = (bx - (ROWB + WCB + 2)) * 1024 + tid * 4;
    if (i + 3 < 4 * NN) {
      *(int4*)&cnt[i] = (int4){0, 0, 0, 0};
    } else {
#pragma unroll
      for (int t = 0; t < 4; t++) if (i + t < 4 * NN) cnt[i + t] = 0;
    }
  }
}

// ---------------- fwd MFMA GEMM body (shared smem) ----------------
__device__ void mfma_fwd_body(int bxr, int by, const ushort_t* __restrict__ Gb,
                              const ushort_t* __restrict__ Wt,
                              ushort_t* __restrict__ QK, int M, char* smem) {
  ushort_t (*sB)[136] = (ushort_t (*)[136])smem;
  int tid = threadIdx.x;
  int nb = by * 64;
  for (int idx = tid; idx < 64 * 16; idx += 256) {
    int r = idx >> 4, c8 = idx & 15;
    *(bf16x8*)&sB[r][c8 * 8] = *(const bf16x8*)(Wt + (size_t)(nb + r) * 128 + c8 * 8);
  }
  __syncthreads();
  int w = tid >> 6, l = tid & 63, quad = l >> 4, j = l & 15;
  int row0 = bxr * 64 + w * 16;
  int arow = row0 + j; if (arow >= M) arow = M - 1;
  const bf16x8* ap = (const bf16x8*)(Gb + (size_t)arow * 128);
  f32x4 acc[4];
#pragma unroll
  for (int nt = 0; nt < 4; nt++) acc[nt] = (f32x4){0.f, 0.f, 0.f, 0.f};
#pragma unroll
  for (int kc = 0; kc < 4; kc++) {
    bf16x8 a = ap[kc * 4 + quad];
#pragma unroll
    for (int nt = 0; nt < 4; nt++) {
      bf16x8 b = *(const bf16x8*)&sB[nt * 16 + j][kc * 32 + quad * 8];
      acc[nt] = __builtin_amdgcn_mfma_f32_16x16x32_bf16(a, b, acc[nt], 0, 0, 0);
    }
  }
#pragma unroll
  for (int nt = 0; nt < 4; nt++)
#pragma unroll
    for (int r = 0; r < 4; r++) {
      int row = row0 + quad * 4 + r;
      if (row < M) QK[(size_t)row * 640 + nb + nt * 16 + j] = bf16_1(acc[nt][r]);
    }
}

// ---------------- edge MLP body (shared smem) ----------------
__device__ void edge_mlp_body(int bx, const float* __restrict__ EA,
                              const float* __restrict__ We1,
                              const float* __restrict__ be1,
                              const float* __restrict__ We2,
                              const float* __restrict__ be2,
                              float* __restrict__ a2, char* smem) {
  float* sW1 = (float*)smem;       // 2048 floats
  float* sb1 = sW1 + 2048;         // 128
  float* sW2 = sb1 + 128;          // 128  (total 9216+1024 bytes <= 17408)
  int tid = threadIdx.x;
  for (int i = tid; i < 2048; i += 256) sW1[i] = We1[i];
  if (tid < 128) { sb1[tid] = be1[tid]; sW2[tid] = We2[tid]; }
  __syncthreads();
  int w = tid >> 6, l = tid & 63;
  int m = l & 15, q = l >> 4;
  union u8 { bf16x8 v; ushort_t s[8]; };
  u8 bf[8];
  float bb[8], ww[8];
#pragma unroll
  for (int nt = 0; nt < 8; nt++) {
    int n = nt * 16 + m;
#pragma unroll
    for (int j = 0; j < 8; j++) {
      int k = q * 8 + j;
      bf[nt].s[j] = (k < 16) ? bf16_1(sW1[k * 128 + n]) : (ushort_t)0;
    }
    bb[nt] = sb1[n];
    ww[nt] = sW2[n];
  }
  float be2v = be2[0];
  for (int batch = 0; batch < 4; batch++) {
    int e0 = bx * 256 + batch * 64 + w * 16;
    u8 af;
    if (q < 2) {
      const float* ep = EA + (size_t)(e0 + m) * 16 + q * 8;
      float4 v0 = *(const float4*)ep;
      float4 v1 = *(const float4*)(ep + 4);
      af.s[0] = bf16_1(v0.x); af.s[1] = bf16_1(v0.y);
      af.s[2] = bf16_1(v0.z); af.s[3] = bf16_1(v0.w);
      af.s[4] = bf16_1(v1.x); af.s[5] = bf16_1(v1.y);
      af.s[6] = bf16_1(v1.z); af.s[7] = bf16_1(v1.w);
    } else {
#pragma unroll
      for (int j = 0; j < 8; j++) af.s[j] = 0;
    }
    float s0 = 0.f, s1 = 0.f, s2 = 0.f, s3 = 0.f;
#pragma unroll
    for (int nt = 0; nt < 8; nt++) {
      float bias = bb[nt];
      f32x4 cin = (f32x4){bias, bias, bias, bias};
      f32x4 acc = __builtin_amdgcn_mfma_f32_16x16x32_bf16(af.v, bf[nt].v, cin, 0, 0, 0);
      float w2v = ww[nt];
      s0 = fmaf(gelu_fast(acc[0]), w2v, s0);
      s1 = fmaf(gelu_fast(acc[1]), w2v, s1);
      s2 = fmaf(gelu_fast(acc[2]), w2v, s2);
      s3 = fmaf(gelu_fast(acc[3]), w2v, s3);
    }
    s0 = redsum16(s0); s1 = redsum16(s1); s2 = redsum16(s2); s3 = redsum16(s3);
    if (m == 0) {
      int eb = e0 + q * 4;
      a2[eb + 0] = s0 + be2v;
      a2[eb + 1] = s1 + be2v;
      a2[eb + 2] = s2 + be2v;
      a2[eb + 3] = s3 + be2v;
    }
  }
}

// ---------------- histogram bodies (8-deep ILP, position capture) ----------------
__device__ void hist2_body(int bx, const int* __restrict__ a,
                           const int* __restrict__ b,
                           int* __restrict__ ca, int* __restrict__ cb,
                           int* __restrict__ pos_a, int* __restrict__ pos_b, int n) {
  int base = bx * 2048 + threadIdx.x;
  if (base + 1792 < n) {
    int av[8], bv[8], pa[8], pb[8];
#pragma unroll
    for (int k = 0; k < 8; k++) { int e = base + k * 256; av[k] = a[e]; bv[k] = b[e]; }
#pragma unroll
    for (int k = 0; k < 8; k++) pa[k] = atomicAdd(&ca[av[k]], 1);
#pragma unroll
    for (int k = 0; k < 8; k++) pb[k] = atomicAdd(&cb[bv[k]], 1);
#pragma unroll
    for (int k = 0; k < 8; k++) pos_a[base + k * 256] = pa[k];
#pragma unroll
    for (int k = 0; k < 8; k++) pos_b[base + k * 256] = pb[k];
  } else {
#pragma unroll
    for (int k = 0; k < 8; k++) {
      int e = base + k * 256;
      if (e < n) {
        pos_a[e] = atomicAdd(&ca[a[e]], 1);
        pos_b[e] = atomicAdd(&cb[b[e]], 1);
      }
    }
  }
}

__device__ void hist_t3_body(int bx, const int* __restrict__ c,
                             const int* __restrict__ u,
                             const int* __restrict__ v,
                             int* __restrict__ cc, int* __restrict__ cuv,
                             int* __restrict__ pos_c, int* __restrict__ pos_u,
                             int* __restrict__ pos_v, int n) {
  int base = bx * 2048 + threadIdx.x;
  if (base + 1792 < n) {
    int cv[8], uv[8], vv[8], pc[8], pu[8], pv[8];
#pragma unroll
    for (int k = 0; k < 8; k++) { int t = base + k * 256; cv[k] = c[t]; uv[k] = u[t]; vv[k] = v[t]; }
#pragma unroll
    for (int k = 0; k < 8; k++) pc[k] = atomicAdd(&cc[cv[k]], 1);
#pragma unroll
    for (int k = 0; k < 8; k++) pu[k] = atomicAdd(&cuv[uv[k]], 1);
#pragma unroll
    for (int k = 0; k < 8; k++) pv[k] = atomicAdd(&cuv[vv[k]], 1);
#pragma unroll
    for (int k = 0; k < 8; k++) pos_c[base + k * 256] = pc[k];
#pragma unroll
    for (int k = 0; k < 8; k++) pos_u[base + k * 256] = pu[k];
#pragma unroll
    for (int k = 0; k < 8; k++) pos_v[base + k * 256] = pv[k];
  } else {
#pragma unroll
    for (int k = 0; k < 8; k++) {
      int t = base + k * 256;
      if (t < n) {
        pos_c[t] = atomicAdd(&cc[c[t]], 1);
        pos_u[t] = atomicAdd(&cuv[u[t]], 1);
        pos_v[t] = atomicAdd(&cuv[v[t]], 1);
      }
    }
  }
}

// fused fwd: hist | mfma_fwd | edge_mlp, block order scrambled so every resident
// generation mixes latency-bound, MFMA-bound and VALU-bound blocks.
__global__ __launch_bounds__(256) void fwd_k(const ushort_t* __restrict__ Gb,
                                             const ushort_t* __restrict__ Wt,
                                             ushort_t* __restrict__ QK,
                                             const float* __restrict__ EA,
                                             const float* __restrict__ We1,
                                             const float* __restrict__ be1,
                                             const float* __restrict__ We2,
                                             const float* __restrict__ be2,
                                             float* __restrict__ a2,
                                             const int* __restrict__ c2,
                                             const int* __restrict__ u2,
                                             const int* __restrict__ c3,
                                             const int* __restrict__ u3,
                                             const int* __restrict__ v3,
                                             int* __restrict__ cnt_c2,
                                             int* __restrict__ cnt_u2,
                                             int* __restrict__ cnt_c3,
                                             int* __restrict__ cnt_uv,
                                             int* __restrict__ pos_c2,
                                             int* __restrict__ pos_u2,
                                             int* __restrict__ pos_c3,
                                             int* __restrict__ pos_u3,
                                             int* __restrict__ pos_v3) {
  __shared__ char smem[64 * 136 * 2];  // 17408 B, union across bodies
  int bx = (int)(((unsigned long long)blockIdx.x * 7919ull) % (unsigned long long)FWD_TOT);
  if (bx < HB2) {
    hist2_body(bx, c2, u2, cnt_c2, cnt_u2, pos_c2, pos_u2, EE);
  } else if (bx < HB2 + HBT) {
    hist_t3_body(bx - HB2, c3, u3, v3, cnt_c3, cnt_uv, pos_c3, pos_u3, pos_v3, TT);
  } else if (bx < HB2 + HBT + MB * 10) {
    int b = bx - HB2 - HBT;
    mfma_fwd_body(b / 10, b % 10, Gb, Wt, QK, NN, smem);
  } else {
    edge_mlp_body(bx - HB2 - HBT - MB * 10, EA, We1, be1, We2, be2, a2, smem);
  }
}

// ---------------- bwd MFMA GEMM: dG[M,128](bf16) = dAll[M,640](bf16) @ Wc^T ----------------
__global__ __launch_bounds__(256) void mfma_bwd(const ushort_t* __restrict__ dAll,
                                                const ushort_t* __restrict__ Wc,
                                                unsigned* __restrict__ dG, int M) {
  __shared__ ushort_t sB[64][40];
  int tid = threadIdx.x;
  int nb = blockIdx.y * 64;
  int w = tid >> 6, l = tid & 63, quad = l >> 4, j = l & 15;
  int row0 = blockIdx.x * 64 + w * 16;
  int arow = row0 + j; if (arow >= M) arow = M - 1;
  const ushort_t* arp = dAll + (size_t)arow * 640;
  f32x4 acc[4];
#pragma unroll
  for (int nt = 0; nt < 4; nt++) acc[nt] = (f32x4){0.f, 0.f, 0.f, 0.f};
  int sr = tid >> 2, sc = tid & 3;
  for (int kc = 0; kc < 20; kc++) {
    __syncthreads();
    *(bf16x8*)&sB[sr][sc * 8] = *(const bf16x8*)(Wc + (size_t)(nb + sr) * 640 + kc * 32 + sc * 8);
    __syncthreads();
    bf16x8 a = *(const bf16x8*)(arp + kc * 32 + quad * 8);
#pragma unroll
    for (int nt = 0; nt < 4; nt++) {
      bf16x8 b = *(const bf16x8*)&sB[nt * 16 + j][quad * 8];
      acc[nt] = __builtin_amdgcn_mfma_f32_16x16x32_bf16(a, b, acc[nt], 0, 0, 0);
    }
  }
#pragma unroll
  for (int nt = 0; nt < 4; nt++)
#pragma unroll
    for (int r = 0; r < 4; r++) {
      int row = row0 + quad * 4 + r;
      if (row < M) ((ushort_t*)dG)[(size_t)row * 128 + nb + nt * 16 + j] = bf16_1(acc[nt][r]);
    }
}

// ---------------- parallel 3-phase scan over 4 count arrays ----------------
__global__ __launch_bounds__(256) void scan_p1(const int* __restrict__ cnt,
                                               int* __restrict__ part) {
  int arr = blockIdx.y, b = blockIdx.x;
  const int* c = cnt + (size_t)arr * NN;
  int gi = b * SCAN_TILE + threadIdx.x * 8;
  int s = 0;
#pragma unroll
  for (int t = 0; t < 8; t++) s += (gi + t < NN) ? c[gi + t] : 0;
#pragma unroll
  for (int m = 32; m; m >>= 1) s += __shfl_xor(s, m, 64);
  __shared__ int wt[4];
  int lane = threadIdx.x & 63, wid = threadIdx.x >> 6;
  if (lane == 0) wt[wid] = s;
  __syncthreads();
  if (threadIdx.x == 0) part[arr * SCAN_NB + b] = wt[0] + wt[1] + wt[2] + wt[3];
}

__global__ __launch_bounds__(256) void scan_p2(int* __restrict__ part) {
  int w = threadIdx.x >> 6, l = threadIdx.x & 63;
  int v = (l < SCAN_NB) ? part[w * SCAN_NB + l] : 0;
  int x = v;
#pragma unroll
  for (int d = 1; d < 64; d <<= 1) {
    int y = __shfl_up(x, d, 64);
    if (l >= d) x += y;
  }
  if (l < SCAN_NB) part[w * SCAN_NB + l] = x - v;
}

__global__ __launch_bounds__(256) void scan_p3(const int* __restrict__ cnt,
                                               const int* __restrict__ part,
                                               int* __restrict__ rowptr) {
  int arr = blockIdx.y, b = blockIdx.x;
  const int* c = cnt + (size_t)arr * NN;
  int* rp = rowptr + (size_t)arr * (NN + 1);
  int tid = threadIdx.x;
  int gi = b * SCAN_TILE + tid * 8;
  int vals[8];
#pragma unroll
  for (int t = 0; t < 8; t++) vals[t] = (gi + t < NN) ? c[gi + t] : 0;
  int tsum = 0;
#pragma unroll
  for (int t = 0; t < 8; t++) tsum += vals[t];
  int lane = tid & 63, wid = tid >> 6;
  int x = tsum;
#pragma unroll
  for (int d = 1; d < 64; d <<= 1) {
    int y = __shfl_up(x, d, 64);
    if (lane >= d) x += y;
  }
  __shared__ int wt[4];
  if (lane == 63) wt[wid] = x;
  __syncthreads();
  int wadd = 0;
  for (int w = 0; w < wid; w++) wadd += wt[w];
  int running = part[arr * SCAN_NB + b] + wadd + x - tsum;
#pragma unroll
  for (int t = 0; t < 8; t++) {
    if (gi + t < NN) rp[gi + t] = running;
    running += vals[t];
  }
  if (b == SCAN_NB - 1 && tid == 255) rp[NN] = running;
}

// ---------------- atomic-free packed scatter bodies (8-deep ILP) ----------------
__device__ void scat2_body(int bx, const int* __restrict__ c2,
                           const int* __restrict__ u2,
                           const float* __restrict__ a2,
                           const int* __restrict__ posc,
                           const int* __restrict__ posu,
                           const int* __restrict__ rpc,
                           const int* __restrict__ rpu,
                           uint2* __restrict__ payc,
                           uint2* __restrict__ payu, int n) {
  int base = bx * 2048 + threadIdx.x;
  if (base + 1792 < n) {
    int c[8], u[8]; float a[8]; int pc[8], pu[8];
#pragma unroll
    for (int k = 0; k < 8; k++) {
      int e = base + k * 256;
      c[k] = c2[e]; u[k] = u2[e]; a[k] = a2[e]; pc[k] = posc[e]; pu[k] = posu[e];
    }
    int p[8], q[8];
#pragma unroll
    for (int k = 0; k < 8; k++) { p[k] = rpc[c[k]] + pc[k]; q[k] = rpu[u[k]] + pu[k]; }
#pragma unroll
    for (int k = 0; k < 8; k++) {
      uint2 t; t.x = (unsigned)u[k]; t.y = __float_as_uint(a[k]);
      payc[p[k]] = t;
    }
#pragma unroll
    for (int k = 0; k < 8; k++) {
      uint2 t; t.x = (unsigned)p[k]; t.y = (unsigned)c[k];
      payu[q[k]] = t;
    }
  } else {
#pragma unroll
    for (int k = 0; k < 8; k++) {
      int e = base + k * 256;
      if (e < n) {
        int cc = c2[e], uu = u2[e];
        int pp = rpc[cc] + posc[e];
        int qq = rpu[uu] + posu[e];
        uint2 t; t.x = (unsigned)uu; t.y = __float_as_uint(a2[e]);
        payc[pp] = t;
        uint2 t2; t2.x = (unsigned)pp; t2.y = (unsigned)cc;
        payu[qq] = t2;
      }
    }
  }
}

__device__ void scat_t3_body(int bx, const int* __restrict__ c3,
                             const int* __restrict__ u3,
                             const int* __restrict__ v3,
                             const int* __restrict__ ttau,
                             const int* __restrict__ posc,
                             const int* __restrict__ posu,
                             const int* __restrict__ posv,
                             const int* __restrict__ rpc,
                             const int* __restrict__ rpuv,
                             uint2* __restrict__ payc,
                             uint2* __restrict__ payuv, int n) {
  int base = bx * 2048 + threadIdx.x;
  if (base + 1792 < n) {
    int c[8], u[8], v[8], ta[8], p[8], q1[8], q2[8];
#pragma unroll
    for (int k = 0; k < 8; k++) {
      int t = base + k * 256;
      c[k] = c3[t]; u[k] = u3[t]; v[k] = v3[t]; ta[k] = ttau[t] & 1;
    }
#pragma unroll
    for (int k = 0; k < 8; k++) {
      int t = base + k * 256;
      p[k] = rpc[c[k]] + posc[t];
      q1[k] = rpuv[u[k]] + posu[t];
      q2[k] = rpuv[v[k]] + posv[t];
    }
#pragma unroll
    for (int k = 0; k < 8; k++) {
      uint2 a; a.x = ((unsigned)u[k] << 16) | (unsigned)v[k]; a.y = (unsigned)ta[k];
      payc[p[k]] = a;
    }
#pragma unroll
    for (int k = 0; k < 8; k++) {
      unsigned sp = ((unsigned)p[k] << 1) | (unsigned)ta[k];
      uint2 b1; b1.x = ((unsigned)v[k] << 16) | (unsigned)c[k]; b1.y = sp;
      payuv[q1[k]] = b1;
      uint2 b2; b2.x = ((unsigned)u[k] << 16) | (unsigned)c[k]; b2.y = sp;
      payuv[q2[k]] = b2;
    }
  } else {
#pragma unroll
    for (int k = 0; k < 8; k++) {
      int t = base + k * 256;
      if (t < n) {
        int c = c3[t], u = u3[t], v = v3[t], ta = ttau[t] & 1;
        int p = rpc[c] + posc[t];
        int q1 = rpuv[u] + posu[t];
        int q2 = rpuv[v] + posv[t];
        unsigned sp = ((unsigned)p << 1) | (unsigned)ta;
        uint2 a; a.x = ((unsigned)u << 16) | (unsigned)v; a.y = (unsigned)ta;
        payc[p] = a;
        uint2 b1; b1.x = ((unsigned)v << 16) | (unsigned)c; b1.y = sp;
        payuv[q1] = b1;
        uint2 b2; b2.x = ((unsigned)u << 16) | (unsigned)c; b2.y = sp;
        payuv[q2] = b2;
      }
    }
  }
}

// fused scatter, block-interleaved 2:1
__global__ __launch_bounds__(256) void scat_k(const int* __restrict__ c2,
                                              const int* __restrict__ u2,
                                              const float* __restrict__ a2,
                                              const int* __restrict__ pos_c2,
                                              const int* __restrict__ pos_u2,
                                              const int* __restrict__ rp_c2,
                                              const int* __restrict__ rp_u2,
                                              uint2* __restrict__ payc2,
                                              uint2* __restrict__ payu2,
                                              const int* __restrict__ c3,
                                              const int* __restrict__ u3,
                                              const int* __restrict__ v3,
                                              const int* __restrict__ ttau,
                                              const int* __restrict__ pos_c3,
                                              const int* __restrict__ pos_u3,
                                              const int* __restrict__ pos_v3,
                                              const int* __restrict__ rp_c3,
                                              const int* __restrict__ rp_uv,
                                              uint2* __restrict__ payc3,
                                              uint2* __restrict__ payuv) {
  int b3 = blockIdx.x / 3, r = blockIdx.x % 3;
  if (r < 2) {
    int b = b3 * 2 + r;
    if (b < HB2) scat2_body(b, c2, u2, a2, pos_c2, pos_u2, rp_c2, rp_u2, payc2, payu2, EE);
  } else {
    scat_t3_body(b3, c3, u3, v3, ttau, pos_c3, pos_u3, pos_v3,
                 rp_c3, rp_uv, payc3, payuv, TT);
  }
}

// ---------------- fused e2 fwd + dQ2 (pair-processing, 6 gathers in flight) ----------------
__device__ void e2_body(int bx, const unsigned* __restrict__ QK,
                        const float* __restrict__ P,
                        const uint2* __restrict__ pay,
                        const int* __restrict__ rp,
                        float* __restrict__ s2c,
                        float* __restrict__ L2,
                        unsigned* __restrict__ dAll) {
  int row = bx * 4 + (threadIdx.x >> 6);
  int l = threadIdx.x & 63, g = l >> 4, j = l & 15;
  float b2s = P[0] * INV_SQRT_D, cw2 = P[3];
  float q[8];
  unp8(*(const uint4*)(QK + (size_t)row * UU + j * 4), q);
  int s = rp[row], e = rp[row + 1];
  float m = -3.0e38f, z = 0.f;
  float acc[8] = {0.f, 0.f, 0.f, 0.f, 0.f, 0.f, 0.f, 0.f};
  int i0 = s + g;
  uint4 kA1 = {0,0,0,0}, kA2 = {0,0,0,0}, kB1 = {0,0,0,0}, kB2 = {0,0,0,0};
  float aA1 = 0.f, aA2 = 0.f, aB1 = 0.f, aB2 = 0.f;
  if (i0 < e)      { uint2 w = pay[i0];      aA1 = __uint_as_float(w.y); kA1 = *(const uint4*)(QK + (size_t)w.x * UU + 64 + j * 4); }
  if (i0 + 4 < e)  { uint2 w = pay[i0 + 4];  aA2 = __uint_as_float(w.y); kA2 = *(const uint4*)(QK + (size_t)w.x * UU + 64 + j * 4); }
  if (i0 + 8 < e)  { uint2 w = pay[i0 + 8];  aB1 = __uint_as_float(w.y); kB1 = *(const uint4*)(QK + (size_t)w.x * UU + 64 + j * 4); }
  if (i0 + 12 < e) { uint2 w = pay[i0 + 12]; aB2 = __uint_as_float(w.y); kB2 = *(const uint4*)(QK + (size_t)w.x * UU + 64 + j * 4); }
  for (int i = i0; i < e; i += 8) {
    uint4 kC1 = {0,0,0,0}, kC2 = {0,0,0,0}; float aC1 = 0.f, aC2 = 0.f;
    if (i + 16 < e) { uint2 w = pay[i + 16]; aC1 = __uint_as_float(w.y); kC1 = *(const uint4*)(QK + (size_t)w.x * UU + 64 + j * 4); }
    if (i + 20 < e) { uint2 w = pay[i + 20]; aC2 = __uint_as_float(w.y); kC2 = *(const uint4*)(QK + (size_t)w.x * UU + 64 + j * 4); }
    {
      float k[8]; unp8(kA1, k);
      float d = 0.f;
#pragma unroll
      for (int t = 0; t < 8; t++) d = fmaf(q[t], k[t], d);
      d = redsum16(d);
      float sv = b2s * d + aA1;
      if (j == 0) s2c[i] = sv;
      if (sv <= m) {
        float p = __expf(sv - m);
        z += p;
#pragma unroll
        for (int t = 0; t < 8; t++) acc[t] = fmaf(p, k[t], acc[t]);
      } else {
        float r = __expf(m - sv);
        z = fmaf(z, r, 1.f);
#pragma unroll
        for (int t = 0; t < 8; t++) acc[t] = fmaf(acc[t], r, k[t]);
        m = sv;
      }
    }
    if (i + 4 < e) {
      float k[8]; unp8(kA2, k);
      float d = 0.f;
#pragma unroll
      for (int t = 0; t < 8; t++) d = fmaf(q[t], k[t], d);
      d = redsum16(d);
      float sv = b2s * d + aA2;
      if (j == 0) s2c[i + 4] = sv;
      if (sv <= m) {
        float p = __expf(sv - m);
        z += p;
#pragma unroll
        for (int t = 0; t < 8; t++) acc[t] = fmaf(p, k[t], acc[t]);
      } else {
        float r = __expf(m - sv);
        z = fmaf(z, r, 1.f);
#pragma unroll
        for (int t = 0; t < 8; t++) acc[t] = fmaf(acc[t], r, k[t]);
        m = sv;
      }
    }
    kA1 = kB1; aA1 = aB1; kA2 = kB2; aA2 = aB2;
    kB1 = kC1; aB1 = aC1; kB2 = kC2; aB2 = aC2;
  }
  float mx = fmaxf(m, __shfl_xor(m, 16, 64));
  mx = fmaxf(mx, __shfl_xor(mx, 32, 64));
  float r = (z > 0.f) ? __expf(m - mx) : 0.f;
  float zz = z * r;
  zz += __shfl_xor(zz, 16, 64);
  zz += __shfl_xor(zz, 32, 64);
#pragma unroll
  for (int t = 0; t < 8; t++) {
    float v = acc[t] * r;
    v += __shfl_xor(v, 16, 64);
    v += __shfl_xor(v, 32, 64);
    acc[t] = v;
  }
  if (l == 0) L2[row] = (zz > 0.f) ? (mx + __logf(zz)) : 0.f;
  if (g == 0) {
    float coef = (zz > 0.f) ? cw2 / zz : 0.f;
    float o[8];
#pragma unroll
    for (int t = 0; t < 8; t++) o[t] = coef * acc[t];
    *(uint4*)(dAll + (size_t)row * UU + 0 + j * 4) = pk8(o);
  }
}

// ---------------- fused t3 fwd + dQ3 (3-deep pipeline; padded T in LDS) ----------------
__device__ void t3_body(int bx, const unsigned* __restrict__ QK,
                        const float* __restrict__ P,
                        const uint2* __restrict__ pay,
                        const int* __restrict__ rp,
                        float* __restrict__ s3c,
                        float* __restrict__ L3,
                        unsigned* __restrict__ dAll,
                        const float* __restrict__ sT) {
  int tid = threadIdx.x;
  int row = bx * 4 + (tid >> 6);
  int l = tid & 63, g = l >> 4, j = l & 15;
  float b3s = P[1] * INV_D, cw3 = P[4];
  float q[8];
  unp8(*(const uint4*)(QK + (size_t)row * UU + 128 + j * 4), q);
  int s = rp[row], e = rp[row + 1];
  float m = -3.0e38f, z = 0.f;
  float acc[8] = {0.f, 0.f, 0.f, 0.f, 0.f, 0.f, 0.f, 0.f};
  int i0 = s + g;
  uint4 kuA = {0,0,0,0}, kvA = {0,0,0,0};
  uint4 kuB = {0,0,0,0}, kvB = {0,0,0,0};
  int taA = 0, taB = 0;
  if (i0 < e) {
    uint2 w = pay[i0]; int u = w.x >> 16, v = w.x & 0xffff; taA = (int)w.y;
    kuA = *(const uint4*)(QK + (size_t)u * UU + 192 + j * 4);
    kvA = *(const uint4*)(QK + (size_t)v * UU + 192 + j * 4);
  }
  if (i0 + 4 < e) {
    uint2 w = pay[i0 + 4]; int u = w.x >> 16, v = w.x & 0xffff; taB = (int)w.y;
    kuB = *(const uint4*)(QK + (size_t)u * UU + 192 + j * 4);
    kvB = *(const uint4*)(QK + (size_t)v * UU + 192 + j * 4);
  }
  for (int i = i0; i < e; i += 4) {
    uint4 kuC = {0,0,0,0}, kvC = {0,0,0,0}; int taC = 0;
    if (i + 8 < e) {
      uint2 w = pay[i + 8]; int u = w.x >> 16, v = w.x & 0xffff; taC = (int)w.y;
      kuC = *(const uint4*)(QK + (size_t)u * UU + 192 + j * 4);
      kvC = *(const uint4*)(QK + (size_t)v * UU + 192 + j * 4);
    }
    float ku[8], kv[8]; unp8(kuA, ku); unp8(kvA, kv);
    const float* tv = &sT[taA * 144 + j * 9];
    float et[8], d = 0.f;
#pragma unroll
    for (int t = 0; t < 8; t++) { et[t] = ku[t] * kv[t] * tv[t]; d = fmaf(q[t], et[t], d); }
    d = redsum16(d);
    float sv = b3s * d;
    if (j == 0) s3c[i] = sv;
    if (sv <= m) {
      float p = __expf(sv - m);
      z += p;
#pragma unroll
      for (int t = 0; t < 8; t++) acc[t] = fmaf(p, et[t], acc[t]);
    } else {
      float r = __expf(m - sv);
      z = fmaf(z, r, 1.f);
#pragma unroll
      for (int t = 0; t < 8; t++) acc[t] = fmaf(acc[t], r, et[t]);
      m = sv;
    }
    kuA = kuB; kvA = kvB; taA = taB;
    kuB = kuC; kvB = kvC; taB = taC;
  }
  float mx = fmaxf(m, __shfl_xor(m, 16, 64));
  mx = fmaxf(mx, __shfl_xor(mx, 32, 64));
  float r = (z > 0.f) ? __expf(m - mx) : 0.f;
  float zz = z * r;
  zz += __shfl_xor(zz, 16, 64);
  zz += __shfl_xor(zz, 32, 64);
#pragma unroll
  for (int t = 0; t < 8; t++) {
    float v = acc[t] * r;
    v += __shfl_xor(v, 16, 64);
    v += __shfl_xor(v, 32, 64);
    acc[t] = v;
  }
  if (l == 0) L3[row] = (zz > 0.f) ? (mx + __logf(zz)) : 0.f;
  if (g == 0) {
    float coef = (zz > 0.f) ? cw3 / zz : 0.f;
    float o[8];
#pragma unroll
    for (int t = 0; t < 8; t++) o[t] = coef * acc[t];
    *(uint4*)(dAll + (size_t)row * UU + 128 + j * 4) = pk8(o);
  }
}

// ---------------- memory-bank energy (padded Km in LDS) ----------------
__device__ void em_body(int bx, const unsigned* __restrict__ QK,
                        const float* __restrict__ P,
                        unsigned* __restrict__ dAll,
                        float* __restrict__ Lm,
                        const float* __restrict__ sKm) {
  int tid = threadIdx.x;
  int row = bx * 4 + (tid >> 6);
  int l = tid & 63, g = l >> 4, j = l & 15;
  float bms = P[2] * INV_SQRT_D, cwm = P[5];
  float q[8];
  unp8(*(const uint4*)(QK + (size_t)row * UU + 256 + j * 4), q);
  float dk[8];
#pragma unroll
  for (int kk = 0; kk < 8; kk++) {
    int k = g * 8 + kk;
    const float* kr = &sKm[k * 144 + j * 9];
    float d = 0.f;
#pragma unroll
    for (int t = 0; t < 8; t++) d = fmaf(q[t], kr[t], d);
    dk[kk] = redsum16(d) * bms;
  }
  float m = dk[0];
#pragma unroll
  for (int kk = 1; kk < 8; kk++) m = fmaxf(m, dk[kk]);
  float mx = fmaxf(m, __shfl_xor(m, 16, 64));
  mx = fmaxf(mx, __shfl_xor(mx, 32, 64));
  float p[8], z = 0.f;
#pragma unroll
  for (int kk = 0; kk < 8; kk++) { p[kk] = __expf(dk[kk] - mx); z += p[kk]; }
  float zz = z;
  zz += __shfl_xor(zz, 16, 64);
  zz += __shfl_xor(zz, 32, 64);
  if (l == 0) Lm[row] = mx + __logf(zz);
  float coef = cwm / zz;
  float acc[8] = {0.f, 0.f, 0.f, 0.f, 0.f, 0.f, 0.f, 0.f};
#pragma unroll
  for (int kk = 0; kk < 8; kk++) {
    int k = g * 8 + kk;
    const float* kr = &sKm[k * 144 + j * 9];
    float pc_ = p[kk] * coef;
#pragma unroll
    for (int t = 0; t < 8; t++) acc[t] = fmaf(pc_, kr[t], acc[t]);
  }
#pragma unroll
  for (int t = 0; t < 8; t++) {
    float v = acc[t];
    v += __shfl_xor(v, 16, 64);
    v += __shfl_xor(v, 32, 64);
    acc[t] = v;
  }
  if (g == 0) *(uint4*)(dAll + (size_t)row * UU + 256 + j * 4) = pk8(acc);
}

// fused phase2: e2 | t3 | em, block-interleaved to smooth tails
__global__ __launch_bounds__(256) void phase2_k(const unsigned* __restrict__ QK,
                                                const float* __restrict__ Tt,
                                                const float* __restrict__ Km,
                                                const float* __restrict__ P,
                                                const uint2* __restrict__ payc2,
                                                const int* __restrict__ rp_c2,
                                                const uint2* __restrict__ payc3,
                                                const int* __restrict__ rp_c3,
                                                float* __restrict__ s2c,
                                                float* __restrict__ L2,
                                                float* __restrict__ s3c,
                                                float* __restrict__ L3,
                                                float* __restrict__ Lm,
                                                unsigned* __restrict__ dAll) {
  __shared__ float smem[32 * 144];
  int bx = blockIdx.x;
  int body = bx % 3, b = bx / 3;
  int tid = threadIdx.x;
  if (body == 0) {
    e2_body(b, QK, P, payc2, rp_c2, s2c, L2, dAll);
  } else if (body == 1) {
    {
      int ta = tid >> 7, d = tid & 127;
      smem[ta * 144 + (d >> 3) * 9 + (d & 7)] = Tt[tid];
    }
    __syncthreads();
    t3_body(b, QK, P, payc3, rp_c3, s3c, L3, dAll, smem);
  } else {
    for (int i = tid; i < KM * DD; i += 256) {
      int k = i >> 7, d = i & 127;
      smem[k * 144 + (d >> 3) * 9 + (d & 7)] = Km[i];
    }
    __syncthreads();
    em_body(b, QK, P, dAll, Lm, smem);
  }
}

// ---------------- dK2 gather (pair-processing, 6 gathers in flight) ----------------
__device__ void dk2_body(int bx, const unsigned* __restrict__ QK,
                         const float* __restrict__ s2c,
                         const float* __restrict__ L2,
                         const float* __restrict__ P,
                         const uint2* __restrict__ pay,
                         const int* __restrict__ rp,
                         unsigned* __restrict__ dAll) {
  int row = bx * 4 + (threadIdx.x >> 6);
  int l = threadIdx.x & 63, g = l >> 4, j = l & 15;
  float cw2 = P[3];
  int s = rp[row], e = rp[row + 1];
  float acc[8] = {0.f, 0.f, 0.f, 0.f, 0.f, 0.f, 0.f, 0.f};
  int i0 = s + g;
  uint4 qA1 = {0,0,0,0}, qA2 = {0,0,0,0}, qB1 = {0,0,0,0}, qB2 = {0,0,0,0};
  float scA1 = 0.f, lcA1 = 0.f, scA2 = 0.f, lcA2 = 0.f;
  float scB1 = 0.f, lcB1 = 0.f, scB2 = 0.f, lcB2 = 0.f;
  if (i0 < e)      { uint2 w = pay[i0];      scA1 = s2c[w.x]; lcA1 = L2[w.y]; qA1 = *(const uint4*)(QK + (size_t)w.y * UU + 0 + j * 4); }
  if (i0 + 4 < e)  { uint2 w = pay[i0 + 4];  scA2 = s2c[w.x]; lcA2 = L2[w.y]; qA2 = *(const uint4*)(QK + (size_t)w.y * UU + 0 + j * 4); }
  if (i0 + 8 < e)  { uint2 w = pay[i0 + 8];  scB1 = s2c[w.x]; lcB1 = L2[w.y]; qB1 = *(const uint4*)(QK + (size_t)w.y * UU + 0 + j * 4); }
  if (i0 + 12 < e) { uint2 w = pay[i0 + 12]; scB2 = s2c[w.x]; lcB2 = L2[w.y]; qB2 = *(const uint4*)(QK + (size_t)w.y * UU + 0 + j * 4); }
  for (int i = i0; i < e; i += 8) {
    uint4 qC1 = {0,0,0,0}, qC2 = {0,0,0,0};
    float scC1 = 0.f, lcC1 = 0.f, scC2 = 0.f, lcC2 = 0.f;
    if (i + 16 < e) { uint2 w = pay[i + 16]; scC1 = s2c[w.x]; lcC1 = L2[w.y]; qC1 = *(const uint4*)(QK + (size_t)w.y * UU + 0 + j * 4); }
    if (i + 20 < e) { uint2 w = pay[i + 20]; scC2 = s2c[w.x]; lcC2 = L2[w.y]; qC2 = *(const uint4*)(QK + (size_t)w.y * UU + 0 + j * 4); }
    {
      float w1 = cw2 * __expf(scA1 - lcA1);
      float qv[8]; unp8(qA1, qv);
#pragma unroll
      for (int t = 0; t < 8; t++) acc[t] = fmaf(w1, qv[t], acc[t]);
    }
    if (i + 4 < e) {
      float w2 = cw2 * __expf(scA2 - lcA2);
      float qv[8]; unp8(qA2, qv);
#pragma unroll
      for (int t = 0; t < 8; t++) acc[t] = fmaf(w2, qv[t], acc[t]);
    }
    qA1 = qB1; scA1 = scB1; lcA1 = lcB1; qA2 = qB2; scA2 = scB2; lcA2 = lcB2;
    qB1 = qC1; scB1 = scC1; lcB1 = lcC1; qB2 = qC2; scB2 = scC2; lcB2 = lcC2;
  }
#pragma unroll
  for (int t = 0; t < 8; t++) {
    float v = acc[t];
    v += __shfl_xor(v, 16, 64);
    v += __shfl_xor(v, 32, 64);
    acc[t] = v;
  }
  if (g == 0) *(uint4*)(dAll + (size_t)row * UU + 64 + j * 4) = pk8(acc);
}

// ---------------- dK3 gather (3-deep pipeline; padded T in LDS) ----------------
__device__ void dk3_body(int bx, const unsigned* __restrict__ QK,
                         const float* __restrict__ s3c,
                         const float* __restrict__ L3,
                         const float* __restrict__ P,
                         const uint2* __restrict__ pay,
                         const int* __restrict__ rp,
                         unsigned* __restrict__ dAll,
                         const float* __restrict__ sT) {
  int tid = threadIdx.x;
  int row = bx * 4 + (tid >> 6);
  int l = tid & 63, g = l >> 4, j = l & 15;
  float cw3 = P[4];
  int s = rp[row], e = rp[row + 1];
  float acc[8] = {0.f, 0.f, 0.f, 0.f, 0.f, 0.f, 0.f, 0.f};
  int i0 = s + g;
  uint4 qA = {0,0,0,0}, kA = {0,0,0,0};
  uint4 qB = {0,0,0,0}, kB = {0,0,0,0};
  int taA = 0, taB = 0;
  float scA = 0.f, lcA = 0.f, scB = 0.f, lcB = 0.f;
  if (i0 < e) {
    uint2 w = pay[i0]; int o = w.x >> 16, c = w.x & 0xffff; unsigned sp = w.y;
    taA = (int)(sp & 1); scA = s3c[sp >> 1]; lcA = L3[c];
    qA = *(const uint4*)(QK + (size_t)c * UU + 128 + j * 4);
    kA = *(const uint4*)(QK + (size_t)o * UU + 192 + j * 4);
  }
  if (i0 + 4 < e) {
    uint2 w = pay[i0 + 4]; int o = w.x >> 16, c = w.x & 0xffff; unsigned sp = w.y;
    taB = (int)(sp & 1); scB = s3c[sp >> 1]; lcB = L3[c];
    qB = *(const uint4*)(QK + (size_t)c * UU + 128 + j * 4);
    kB = *(const uint4*)(QK + (size_t)o * UU + 192 + j * 4);
  }
  for (int i = i0; i < e; i += 4) {
    uint4 qC = {0,0,0,0}, kC = {0,0,0,0}; int taC = 0;
    float scC = 0.f, lcC = 0.f;
    if (i + 8 < e) {
      uint2 w = pay[i + 8]; int o = w.x >> 16, c = w.x & 0xffff; unsigned sp = w.y;
      taC = (int)(sp & 1); scC = s3c[sp >> 1]; lcC = L3[c];
      qC = *(const uint4*)(QK + (size_t)c * UU + 128 + j * 4);
      kC = *(const uint4*)(QK + (size_t)o * UU + 192 + j * 4);
    }
    float w = cw3 * __expf(scA - lcA);
    float qv[8], ko[8]; unp8(qA, qv); unp8(kA, ko);
    const float* tv = &sT[taA * 144 + j * 9];
#pragma unroll
    for (int t = 0; t < 8; t++) acc[t] = fmaf(w * tv[t], qv[t] * ko[t], acc[t]);
    qA = qB; kA = kB; taA = taB; scA = scB; lcA = lcB;
    qB = qC; kB = kC; taB = taC; scB = scC; lcB = lcC;
  }
#pragma unroll
  for (int t = 0; t < 8; t++) {
    float v = acc[t];
    v += __shfl_xor(v, 16, 64);
    v += __shfl_xor(v, 32, 64);
    acc[t] = v;
  }
  if (g == 0) *(uint4*)(dAll + (size_t)row * UU + 192 + j * 4) = pk8(acc);
}

// ---------------- final energy scalar body ----------------
__device__ void eval_write_body(int bx, const float* __restrict__ L2,
                                const float* __restrict__ L3,
                                const float* __restrict__ Lm,
                                const float* __restrict__ P,
                                float* __restrict__ out) {
  int i = bx * 256 + threadIdx.x;
  float a2 = 0.f, a3 = 0.f, am = 0.f;
  if (i < NN) { a2 = L2[i]; a3 = L3[i]; am = Lm[i]; }
  a2 = wredsum(a2); a3 = wredsum(a3); am = wredsum(am);
  __shared__ float r2[4], r3[4], rm[4];
  int wv = threadIdx.x >> 6, l = threadIdx.x & 63;
  if (l == 0) { r2[wv] = a2; r3[wv] = a3; rm[wv] = am; }
  __syncthreads();
  if (threadIdx.x == 0) {
    float S2 = r2[0] + r2[1] + r2[2] + r2[3];
    float S3 = r3[0] + r3[1] + r3[2] + r3[3];
    float Sm = rm[0] + rm[1] + rm[2] + rm[3];
    atomicAdd(out, P[6] * S2 + P[7] * S3 + P[8] * Sm);
  }
}

// fused phase3: dk2 | dk3 interleaved, plus eval_write (inputs ready after phase2)
__global__ __launch_bounds__(256) void phase3_k(const unsigned* __restrict__ QK,
                                                const float* __restrict__ Tt,
                                                const float* __restrict__ P,
                                                const float* __restrict__ s2c,
                                                const float* __restrict__ L2,
                                                const uint2* __restrict__ payu2,
                                                const int* __restrict__ rp_u2,
                                                const float* __restrict__ s3c,
                                                const float* __restrict__ L3,
                                                const uint2* __restrict__ payuv,
                                                const int* __restrict__ rp_uv,
                                                unsigned* __restrict__ dAll,
                                                const float* __restrict__ Lm,
                                                float* __restrict__ eout) {
  __shared__ float smem[2 * 144];
  int bx = blockIdx.x;
  int tid = threadIdx.x;
  if (bx < 2 * ROWB) {
    int body = bx & 1, b = bx >> 1;
    if (body == 0) {
      dk2_body(b, QK, s2c, L2, P, payu2, rp_u2, dAll);
    } else {
      {
        int ta = tid >> 7, d = tid & 127;
        smem[ta * 144 + (d >> 3) * 9 + (d & 7)] = Tt[tid];
      }
      __syncthreads();
      dk3_body(b, QK, s3c, L3, P, payuv, rp_uv, dAll, smem);
    }
  } else {
    eval_write_body(bx - 2 * ROWB, L2, L3, Lm, P, eout);
  }
}

// ---------------- LN backward + clips + update ----------------
__global__ __launch_bounds__(256) void fin_k(const float* __restrict__ X,
                                             const unsigned* __restrict__ dG,
                                             const float* __restrict__ gamma,
                                             const float* __restrict__ meanv,
                                             const float* __restrict__ rstdv,
                                             float* __restrict__ out) {
  int row = blockIdx.x * 4 + (threadIdx.x >> 6);
  if (row >= NN) return;
  int l = threadIdx.x & 63;
  float mu = meanv[row], rstd = rstdv[row];
  float2 x2 = *(const float2*)(X + row * DD + 2 * l);
  unsigned gw = dG[(size_t)row * 64 + l];
  float2 ga = *(const float2*)(gamma + 2 * l);
  float xh0 = (x2.x - mu) * rstd, xh1 = (x2.y - mu) * rstd;
  float dh0 = blo(gw) * ga.x, dh1 = bhi(gw) * ga.y;
  float sa = wredsum(dh0 + dh1) * (1.f / DD);
  float sb = wredsum(dh0 * xh0 + dh1 * xh1) * (1.f / DD);
  float dx0 = rstd * (dh0 - sa - xh0 * sb);
  float dx1 = rstd * (dh1 - sa - xh1 * sb);
  float gn = fmaxf(sqrtf(wredsum(dx0 * dx0 + dx1 * dx1)), 1e-6f);
  float sc = fminf(1.f / gn, 1.f);
  dx0 *= sc; dx1 *= sc;
  float xn0 = x2.x - 0.1f * 0.9999f * dx0;
  float xn1 = x2.y - 0.1f * 0.9999f * dx1;
  float sn = fmaxf(sqrtf(wredsum(xn0 * xn0 + xn1 * xn1)), 1e-6f);
  float sc2 = fminf(10.f / sn, 1.f);
  float2 o; o.x = xn0 * sc2; o.y = xn1 * sc2;
  *(float2*)(out + row * DD + 2 * l) = o;
}

extern "C" void kernel_launch(void* const* d_in, const int* in_sizes, int n_in,
                              void* d_out, int out_size, void* d_ws, size_t ws_size,
                              hipStream_t stream) {
  (void)in_sizes; (void)n_in; (void)out_size;
  const float* X = (const float*)d_in[0];
  const float* EA = (const float*)d_in[1];
  const float* ln_g = (const float*)d_in[2];
  const float* ln_b = (const float*)d_in[3];
  const float* W_Q2 = (const float*)d_in[4];
  const float* W_K2 = (const float*)d_in[5];
  const float* W_Q3 = (const float*)d_in[6];
  const float* W_K3 = (const float*)d_in[7];
  const float* T_tau = (const float*)d_in[8];
  const float* W_Qm = (const float*)d_in[9];
  const float* W_Km = (const float*)d_in[10];
  const float* B_mem = (const float*)d_in[11];
  const float* We1 = (const float*)d_in[12];
  const float* be1 = (const float*)d_in[13];
  const float* We2 = (const float*)d_in[14];
  const float* be2 = (const float*)d_in[15];
  const float* l2s = (const float*)d_in[16];
  const float* l3s = (const float*)d_in[17];
  const float* lms = (const float*)d_in[18];
  const float* b2s = (const float*)d_in[19];
  const float* b3s = (const float*)d_in[20];
  const float* bms = (const float*)d_in[21];
  const int* c2 = (const int*)d_in[22];
  const int* u2 = (const int*)d_in[23];
  const int* c3 = (const int*)d_in[24];
  const int* u3 = (const int*)d_in[25];
  const int* v3 = (const int*)d_in[26];
  const int* ttau = (const int*)d_in[27];
  float* out = (float*)d_out;

  float* ws = (float*)d_ws;
  size_t off = 0;
  auto alloc = [&](size_t n) { float* p = ws + off; off += n; return p; };
  const size_t ND = (size_t)NN * DD;
  unsigned* Gb = (unsigned*)alloc(ND / 2);
  unsigned* QKall = (unsigned*)alloc((size_t)NN * UU);
  unsigned* dAll = (unsigned*)alloc((size_t)NN * UU);
  unsigned* dG = (unsigned*)alloc(ND / 2);
  ushort_t* Wt5 = (ushort_t*)alloc(640 * 128 / 2);
  ushort_t* Wcat = (ushort_t*)alloc(640 * 128 / 2);
  float* Km = alloc((size_t)KM * DD);
  float* a2 = alloc(EE);
  float* s2c = alloc(EE);
  float* s3c = alloc(TT);
  float* meanv = alloc(NN);
  float* rstdv = alloc(NN);
  float* L2 = alloc(NN);
  float* L3 = alloc(NN);
  float* Lm = alloc(NN);
  float* Pparams = alloc(16);
  int* cnt = (int*)alloc(4 * (size_t)NN);
  int* rowptr = (int*)alloc(4 * (size_t)(NN + 1));
  int* spart = (int*)alloc(4 * SCAN_NB);
  int* pos_c2 = (int*)alloc(EE);
  int* pos_u2 = (int*)alloc(EE);
  int* pos_c3 = (int*)alloc(TT);
  int* pos_u3 = (int*)alloc(TT);
  int* pos_v3 = (int*)alloc(TT);
  uint2* payc2 = (uint2*)alloc(2 * (size_t)EE);
  uint2* payu2 = (uint2*)alloc(2 * (size_t)EE);
  uint2* payc3 = (uint2*)alloc(2 * (size_t)TT);
  uint2* payuv = (uint2*)alloc(4 * (size_t)TT);
  if (off * sizeof(float) > ws_size) return;

  int* cnt_c2 = cnt, *cnt_u2 = cnt + NN, *cnt_c3 = cnt + 2 * NN, *cnt_uv = cnt + 3 * NN;
  int* rp_c2 = rowptr, *rp_u2 = rowptr + (NN + 1), *rp_c3 = rowptr + 2 * (NN + 1), *rp_uv = rowptr + 3 * (NN + 1);

  prep_k<<<ROWB + WCB + 2 + ZCB, 256, 0, stream>>>(
      X, ln_g, ln_b, Gb, meanv, rstdv,
      W_Q2, W_K2, W_Q3, W_K3, W_Qm, Wt5, Wcat,
      B_mem, W_Km, Km,
      l2s, l3s, lms, b2s, b3s, bms, Pparams, out + ND, cnt);

  fwd_k<<<FWD_TOT, 256, 0, stream>>>(
      (const ushort_t*)Gb, Wt5, (ushort_t*)QKall,
      EA, We1, be1, We2, be2, a2,
      c2, u2, c3, u3, v3,
      cnt_c2, cnt_u2, cnt_c3, cnt_uv,
      pos_c2, pos_u2, pos_c3, pos_u3, pos_v3);

  scan_p1<<<dim3(SCAN_NB, 4), 256, 0, stream>>>(cnt, spart);
  scan_p2<<<1, 256, 0, stream>>>(spart);
  scan_p3<<<dim3(SCAN_NB, 4), 256, 0, stream>>>(cnt, spart, rowptr);

  scat_k<<<3 * HBT, 256, 0, stream>>>(
      c2, u2, a2, pos_c2, pos_u2, rp_c2, rp_u2, payc2, payu2,
      c3, u3, v3, ttau, pos_c3, pos_u3, pos_v3, rp_c3, rp_uv, payc3, payuv);

  phase2_k<<<3 * ROWB, 256, 0, stream>>>(QKall, T_tau, Km, Pparams,
                                         payc2, rp_c2, payc3, rp_c3,
                                         s2c, L2, s3c, L3, Lm, dAll);
  phase3_k<<<2 * ROWB + 196, 256, 0, stream>>>(QKall, T_tau, Pparams,
                                               s2c, L2, payu2, rp_u2,
                                               s3c, L3, payuv, rp_uv, dAll,
                                               Lm, out + ND);

  mfma_bwd<<<dim3(MB, 2), 256, 0, stream>>>((const ushort_t*)dAll, Wcat, dG, NN);

  fin_k<<<ROWB, 256, 0, stream>>>(X, dG, ln_g, meanv, rstdv, out);
}